// Round 1
// baseline (271.469 us; speedup 1.0000x reference)
//
#include <hip/hip_runtime.h>
#include <hip/hip_bf16.h>
#include <cstdint>
#include <cstddef>

typedef __attribute__((ext_vector_type(4))) float f32x4;
typedef __attribute__((ext_vector_type(8))) short bf16x8;
typedef __attribute__((ext_vector_type(8))) unsigned short us8;

#define MFMA16(a, b, c) __builtin_amdgcn_mfma_f32_16x16x32_bf16(a, b, c, 0, 0, 0)

__device__ inline unsigned short f2bf(float f) {
    unsigned int u = __float_as_uint(f);
    u += 0x7fffu + ((u >> 16) & 1u);
    return (unsigned short)(u >> 16);
}

__device__ inline void gload_lds16(const void* g, void* l) {
    __builtin_amdgcn_global_load_lds(
        (const __attribute__((address_space(1))) void*)g,
        (__attribute__((address_space(3))) void*)l, 16, 0, 0);
}

// ---------------------------------------------------------------- converts
__global__ __launch_bounds__(256) void convert_bf16(const float* __restrict__ src,
                                                    unsigned short* __restrict__ dst,
                                                    int n) {
    int i = (blockIdx.x * 256 + threadIdx.x) * 4;
    if (i >= n) return;
    float4 v = *(const float4*)(src + i);
    ushort4 o;
    o.x = f2bf(v.x); o.y = f2bf(v.y); o.z = f2bf(v.z); o.w = f2bf(v.w);
    *(ushort4*)(dst + i) = o;
}

// ---------------------------------------------------------------- GEMM  C[M,N] = A[M,K] * B[N,K]^T
__global__ __launch_bounds__(256) void gemm_bt(const unsigned short* __restrict__ A,
                                               const unsigned short* __restrict__ B,
                                               float* __restrict__ C,
                                               int M, int N, int K) {
    __shared__ unsigned short As[128 * 32];
    __shared__ unsigned short Bs[128 * 32];
    const int tid = threadIdx.x;
    const int lane = tid & 63, wave = tid >> 6;
    const int wr = wave >> 1, wc = wave & 1;
    const int bm = blockIdx.y, bn = blockIdx.x;
    const int l15 = lane & 15, l4 = lane >> 4;
    f32x4 acc[4][4] = {};
    const int nK = K >> 5;
    for (int kt = 0; kt < nK; ++kt) {
        __syncthreads();  // previous iter's LDS reads complete
        for (int i = 0; i < 2; ++i) {
            int e = (i * 256 + tid) * 8;   // element index in 128x32 tile
            int r = e >> 5, c = e & 31;
            gload_lds16(A + (size_t)(bm * 128 + r) * K + kt * 32 + c, As + e);
            gload_lds16(B + (size_t)(bn * 128 + r) * K + kt * 32 + c, Bs + e);
        }
        __syncthreads();  // drains vmcnt -> LDS tiles ready
        bf16x8 af[4], bf[4];
        for (int m = 0; m < 4; ++m)
            af[m] = *(const bf16x8*)&As[(wr * 64 + m * 16 + l15) * 32 + l4 * 8];
        for (int n = 0; n < 4; ++n)
            bf[n] = *(const bf16x8*)&Bs[(wc * 64 + n * 16 + l15) * 32 + l4 * 8];
        for (int m = 0; m < 4; ++m)
            for (int n = 0; n < 4; ++n)
                acc[m][n] = MFMA16(af[m], bf[n], acc[m][n]);
    }
    for (int m = 0; m < 4; ++m)
        for (int n = 0; n < 4; ++n)
            for (int j = 0; j < 4; ++j) {
                int row = bm * 128 + wr * 64 + m * 16 + l4 * 4 + j;
                int col = bn * 128 + wc * 64 + n * 16 + l15;
                C[(size_t)row * N + col] = acc[m][n][j];
            }
}

// ---------------------------------------------------------------- RMSNorm + RoPE + repack
// qkv f32 [2048][3072]; heads 0..15 -> Q, 16..19 -> K, 20..23 -> V
__global__ __launch_bounds__(64) void norm_rope(const float* __restrict__ qkv,
                                                const float* __restrict__ qw,
                                                const float* __restrict__ kw,
                                                unsigned short* __restrict__ Qb,
                                                unsigned short* __restrict__ Kb,
                                                unsigned short* __restrict__ Vb) {
    const int row = blockIdx.x;   // 0..2047 (pos)
    const int head = blockIdx.y;  // 0..23
    const int t = threadIdx.x;    // 0..63
    const float* src = qkv + (size_t)row * 3072 + head * 128;
    float x1 = src[t], x2 = src[t + 64];
    if (head < 20) {
        float ss = x1 * x1 + x2 * x2;
        for (int m = 32; m; m >>= 1) ss += __shfl_xor(ss, m);
        float r = rsqrtf(ss * (1.0f / 128.0f) + 1e-6f);
        const float* w = (head < 16) ? qw : kw;
        float y1 = x1 * r * w[t], y2 = x2 * r * w[t + 64];
        // inv_freq = 10000^(-2t/128)
        float inv_freq = expf((float)t * (-2.0f / 128.0f) * 9.210340371976184f);
        float ang = (float)row * inv_freq;
        float s, c;
        sincosf(ang, &s, &c);
        x1 = y1 * c - y2 * s;
        x2 = y1 * s + y2 * c;
    }
    unsigned short* dst;
    if (head < 16)      dst = Qb + ((size_t)head * 2048 + row) * 128;
    else if (head < 20) dst = Kb + ((size_t)(head - 16) * 2048 + row) * 128;
    else                dst = Vb + ((size_t)(head - 20) * 2048 + row) * 128;
    dst[t] = f2bf(x1);
    dst[t + 64] = f2bf(x2);
}

// ---------------------------------------------------------------- flash attention (windowed causal GQA)
// Qb [16][2048][128], Kb/Vb [4][2048][128] bf16 ; Ob [2048][16*128] bf16
__global__ __launch_bounds__(256) void attn_fwd(const unsigned short* __restrict__ Qb,
                                                const unsigned short* __restrict__ Kb,
                                                const unsigned short* __restrict__ Vb,
                                                unsigned short* __restrict__ Ob) {
    const int qt = blockIdx.x;  // 0..31 (64-row q tiles)
    const int h = blockIdx.y;   // 0..15
    const int kvh = h >> 2;
    const int q0 = qt * 64;
    __shared__ unsigned short Ks[64 * 128];
    __shared__ unsigned short Vt[128 * 64];   // transposed: Vt[d][c]
    __shared__ unsigned short Ps[4][16 * 64]; // per-wave P buffer
    const int tid = threadIdx.x;
    const int lane = tid & 63, wave = tid >> 6;
    const int l15 = lane & 15, l4 = lane >> 4;

    bf16x8 qf[4];
    {
        const unsigned short* qrow =
            Qb + ((size_t)h * 2048 + q0 + wave * 16 + l15) * 128 + l4 * 8;
        for (int kk = 0; kk < 4; ++kk) qf[kk] = *(const bf16x8*)(qrow + kk * 32);
    }
    f32x4 o[8] = {};
    float m_run[4], l_run[4];
    for (int j = 0; j < 4; ++j) { m_run[j] = -1e30f; l_run[j] = 0.0f; }
    const float scale = 0.08838834764831843f;  // 1/sqrt(128)
    const int kt_lo = (qt >= 16) ? (qt - 16) : 0;

    for (int kt = kt_lo; kt <= qt; ++kt) {
        __syncthreads();  // previous iter's LDS reads complete
        // stage K tile [64][128] via global->LDS DMA
        for (int i = 0; i < 4; ++i) {
            int e = (i * 256 + tid) * 8;
            gload_lds16(Kb + ((size_t)kvh * 2048 + kt * 64 + (e >> 7)) * 128 + (e & 127),
                        Ks + e);
        }
        // stage V transposed (register path, scalar LDS writes)
        for (int i = 0; i < 4; ++i) {
            int e = (i * 256 + tid) * 8;
            int vr = e >> 7, vd = e & 127;
            us8 vv = *(const us8*)(Vb + ((size_t)kvh * 2048 + kt * 64 + vr) * 128 + vd);
            for (int jj = 0; jj < 8; ++jj) Vt[(vd + jj) * 64 + vr] = vv[jj];
        }
        __syncthreads();

        // S = Q K^T : wave's 16 rows x 64 keys
        f32x4 s[4] = {};
        for (int nn = 0; nn < 4; ++nn)
            for (int kk = 0; kk < 4; ++kk) {
                bf16x8 kf = *(const bf16x8*)&Ks[(nn * 16 + l15) * 128 + kk * 32 + l4 * 8];
                s[nn] = MFMA16(qf[kk], kf, s[nn]);
            }

        // mask + online softmax
        float p[4][4], corr[4];
        for (int j = 0; j < 4; ++j) {
            const int qr = q0 + wave * 16 + l4 * 4 + j;
            float mx = -1e30f;
            for (int nn = 0; nn < 4; ++nn) {
                int kc = kt * 64 + nn * 16 + l15;
                float sv = s[nn][j] * scale;
                bool ok = (qr >= kc) && (qr - kc < 1024);
                sv = ok ? sv : -1e30f;
                p[nn][j] = sv;
                mx = fmaxf(mx, sv);
            }
            for (int mk = 8; mk; mk >>= 1) mx = fmaxf(mx, __shfl_xor(mx, mk));
            float mnew = fmaxf(m_run[j], mx);
            corr[j] = __expf(m_run[j] - mnew);
            float rs = 0.0f;
            for (int nn = 0; nn < 4; ++nn) {
                float pv = __expf(p[nn][j] - mnew);
                p[nn][j] = pv;
                rs += pv;
            }
            for (int mk = 8; mk; mk >>= 1) rs += __shfl_xor(rs, mk);
            l_run[j] = l_run[j] * corr[j] + rs;
            m_run[j] = mnew;
        }
        for (int dd = 0; dd < 8; ++dd)
            for (int j = 0; j < 4; ++j) o[dd][j] *= corr[j];

        // P -> LDS (bf16), per-wave private buffer
        for (int j = 0; j < 4; ++j)
            for (int nn = 0; nn < 4; ++nn)
                Ps[wave][(l4 * 4 + j) * 64 + nn * 16 + l15] = f2bf(p[nn][j]);

        bf16x8 pa[2];
        for (int kk2 = 0; kk2 < 2; ++kk2)
            pa[kk2] = *(const bf16x8*)&Ps[wave][l15 * 64 + kk2 * 32 + l4 * 8];

        // O += P V
        for (int dd = 0; dd < 8; ++dd)
            for (int kk2 = 0; kk2 < 2; ++kk2) {
                bf16x8 vf = *(const bf16x8*)&Vt[(dd * 16 + l15) * 64 + kk2 * 32 + l4 * 8];
                o[dd] = MFMA16(pa[kk2], vf, o[dd]);
            }
    }

    // epilogue: normalize and store
    for (int j = 0; j < 4; ++j) {
        float inv = 1.0f / l_run[j];
        int row = q0 + wave * 16 + l4 * 4 + j;
        unsigned short* orow = Ob + (size_t)row * 2048 + h * 128;
        for (int dd = 0; dd < 8; ++dd) orow[dd * 16 + l15] = f2bf(o[dd][j] * inv);
    }
}

// ---------------------------------------------------------------- launch
extern "C" void kernel_launch(void* const* d_in, const int* in_sizes, int n_in,
                              void* d_out, int out_size, void* d_ws, size_t ws_size,
                              hipStream_t stream) {
    const float* x  = (const float*)d_in[0];
    const float* wq = (const float*)d_in[1];
    const float* wk = (const float*)d_in[2];
    const float* wv = (const float*)d_in[3];
    const float* wo = (const float*)d_in[4];
    const float* qw = (const float*)d_in[5];
    const float* kw = (const float*)d_in[6];
    float* out = (float*)d_out;

    char* ws = (char*)d_ws;
    unsigned short* xb   = (unsigned short*)(ws + 0);          //  8 MB  x bf16 [2048][2048]
    unsigned short* wqkv = (unsigned short*)(ws + 8388608);    // 12 MB  [3072][2048]
    unsigned short* wob  = (unsigned short*)(ws + 20971520);   //  8 MB  [2048][2048]
    float*          qkv  = (float*)(ws + 29360128);            // 24 MB  [2048][3072]
    unsigned short* Qb   = (unsigned short*)(ws + 54525952);   //  8 MB  [16][2048][128]
    unsigned short* Kb   = (unsigned short*)(ws + 62914560);   //  2 MB  [4][2048][128]
    unsigned short* Vb   = (unsigned short*)(ws + 65011712);   //  2 MB  [4][2048][128]
    unsigned short* Ob   = (unsigned short*)(ws + 67108864);   //  8 MB  [2048][2048]

    convert_bf16<<<dim3(4096), dim3(256), 0, stream>>>(x, xb, 2048 * 2048);
    convert_bf16<<<dim3(4096), dim3(256), 0, stream>>>(wq, wqkv, 2048 * 2048);
    convert_bf16<<<dim3(1024), dim3(256), 0, stream>>>(wk, wqkv + 2048 * 2048, 512 * 2048);
    convert_bf16<<<dim3(1024), dim3(256), 0, stream>>>(wv, wqkv + 2560 * 2048, 512 * 2048);
    convert_bf16<<<dim3(4096), dim3(256), 0, stream>>>(wo, wob, 2048 * 2048);

    gemm_bt<<<dim3(24, 16), dim3(256), 0, stream>>>(xb, wqkv, qkv, 2048, 3072, 2048);
    norm_rope<<<dim3(2048, 24), dim3(64), 0, stream>>>(qkv, qw, kw, Qb, Kb, Vb);
    attn_fwd<<<dim3(32, 16), dim3(256), 0, stream>>>(Qb, Kb, Vb, Ob);
    gemm_bt<<<dim3(16, 16), dim3(256), 0, stream>>>(Ob, wob, out, 2048, 2048, 2048);
}

// Round 2
// 191.308 us; speedup vs baseline: 1.4190x; 1.4190x over previous
//
#include <hip/hip_runtime.h>
#include <hip/hip_bf16.h>
#include <cstdint>
#include <cstddef>

typedef __attribute__((ext_vector_type(4))) float f32x4;
typedef __attribute__((ext_vector_type(8))) short bf16x8;
typedef __attribute__((ext_vector_type(8))) unsigned short us8;

#define MFMA16(a, b, c) __builtin_amdgcn_mfma_f32_16x16x32_bf16(a, b, c, 0, 0, 0)

__device__ inline unsigned short f2bf(float f) {
    unsigned int u = __float_as_uint(f);
    u += 0x7fffu + ((u >> 16) & 1u);
    return (unsigned short)(u >> 16);
}

__device__ inline void gload_lds16(const void* g, void* l) {
    __builtin_amdgcn_global_load_lds(
        (const __attribute__((address_space(1))) void*)g,
        (__attribute__((address_space(3))) void*)l, 16, 0, 0);
}

// ---------------------------------------------------------------- converts
__global__ __launch_bounds__(256) void convert_bf16(const float* __restrict__ src,
                                                    unsigned short* __restrict__ dst,
                                                    int n) {
    int i = (blockIdx.x * 256 + threadIdx.x) * 4;
    if (i >= n) return;
    float4 v = *(const float4*)(src + i);
    ushort4 o;
    o.x = f2bf(v.x); o.y = f2bf(v.y); o.z = f2bf(v.z); o.w = f2bf(v.w);
    *(ushort4*)(dst + i) = o;
}

// ---------------------------------------------------------------- GEMM  C[M,N] = A[M,K] * B[N,K]^T
__global__ __launch_bounds__(256) void gemm_bt(const unsigned short* __restrict__ A,
                                               const unsigned short* __restrict__ B,
                                               float* __restrict__ C,
                                               int M, int N, int K) {
    __shared__ unsigned short As[128 * 32];
    __shared__ unsigned short Bs[128 * 32];
    const int tid = threadIdx.x;
    const int lane = tid & 63, wave = tid >> 6;
    const int wr = wave >> 1, wc = wave & 1;
    const int bm = blockIdx.y, bn = blockIdx.x;
    const int l15 = lane & 15, l4 = lane >> 4;
    f32x4 acc[4][4] = {};
    const int nK = K >> 5;
    for (int kt = 0; kt < nK; ++kt) {
        __syncthreads();  // previous iter's LDS reads complete
        for (int i = 0; i < 2; ++i) {
            int e = (i * 256 + tid) * 8;   // element index in 128x32 tile
            int r = e >> 5, c = e & 31;
            gload_lds16(A + (size_t)(bm * 128 + r) * K + kt * 32 + c, As + e);
            gload_lds16(B + (size_t)(bn * 128 + r) * K + kt * 32 + c, Bs + e);
        }
        __syncthreads();  // drains vmcnt -> LDS tiles ready
        bf16x8 af[4], bf[4];
        for (int m = 0; m < 4; ++m)
            af[m] = *(const bf16x8*)&As[(wr * 64 + m * 16 + l15) * 32 + l4 * 8];
        for (int n = 0; n < 4; ++n)
            bf[n] = *(const bf16x8*)&Bs[(wc * 64 + n * 16 + l15) * 32 + l4 * 8];
        for (int m = 0; m < 4; ++m)
            for (int n = 0; n < 4; ++n)
                acc[m][n] = MFMA16(af[m], bf[n], acc[m][n]);
    }
    for (int m = 0; m < 4; ++m)
        for (int n = 0; n < 4; ++n)
            for (int j = 0; j < 4; ++j) {
                int row = bm * 128 + wr * 64 + m * 16 + l4 * 4 + j;
                int col = bn * 128 + wc * 64 + n * 16 + l15;
                C[(size_t)row * N + col] = acc[m][n][j];
            }
}

// ---------------------------------------------------------------- RMSNorm + RoPE + repack
// qkv f32 [2048][3072]; heads 0..15 -> Q, 16..19 -> K, 20..23 -> V
__global__ __launch_bounds__(64) void norm_rope(const float* __restrict__ qkv,
                                                const float* __restrict__ qw,
                                                const float* __restrict__ kw,
                                                unsigned short* __restrict__ Qb,
                                                unsigned short* __restrict__ Kb,
                                                unsigned short* __restrict__ Vb) {
    const int row = blockIdx.x;   // 0..2047 (pos)
    const int head = blockIdx.y;  // 0..23
    const int t = threadIdx.x;    // 0..63
    const float* src = qkv + (size_t)row * 3072 + head * 128;
    float x1 = src[t], x2 = src[t + 64];
    if (head < 20) {
        float ss = x1 * x1 + x2 * x2;
        for (int m = 32; m; m >>= 1) ss += __shfl_xor(ss, m);
        float r = rsqrtf(ss * (1.0f / 128.0f) + 1e-6f);
        const float* w = (head < 16) ? qw : kw;
        float y1 = x1 * r * w[t], y2 = x2 * r * w[t + 64];
        float inv_freq = expf((float)t * (-2.0f / 128.0f) * 9.210340371976184f);
        float ang = (float)row * inv_freq;
        float s, c;
        sincosf(ang, &s, &c);
        x1 = y1 * c - y2 * s;
        x2 = y1 * s + y2 * c;
    }
    unsigned short* dst;
    if (head < 16)      dst = Qb + ((size_t)head * 2048 + row) * 128;
    else if (head < 20) dst = Kb + ((size_t)(head - 16) * 2048 + row) * 128;
    else                dst = Vb + ((size_t)(head - 20) * 2048 + row) * 128;
    dst[t] = f2bf(x1);
    dst[t + 64] = f2bf(x2);
}

// ---------------------------------------------------------------- V transpose: Vb [4][2048][128] -> VbT [4][128][2048]
__global__ __launch_bounds__(256) void transpose_v(const unsigned short* __restrict__ Vb,
                                                   unsigned short* __restrict__ VbT) {
    const int kt = blockIdx.x;  // 0..31 (64-row k tile)
    const int h  = blockIdx.y;  // 0..3
    __shared__ unsigned short T[64 * 130];
    const int tid = threadIdx.x;
    for (int i = 0; i < 4; ++i) {
        int s = i * 256 + tid;
        int r = s >> 4, c = (s & 15) * 8;
        us8 v = *(const us8*)(Vb + ((size_t)h * 2048 + kt * 64 + r) * 128 + c);
        for (int j = 0; j < 8; ++j) T[r * 130 + c + j] = v[j];
    }
    __syncthreads();
    for (int i = 0; i < 4; ++i) {
        int s = i * 256 + tid;
        int d = s >> 3, ck = (s & 7) * 8;
        us8 v;
        for (int j = 0; j < 8; ++j) v[j] = T[(ck + j) * 130 + d];
        *(us8*)(VbT + (size_t)h * 128 * 2048 + (size_t)d * 2048 + kt * 64 + ck) = v;
    }
}

// ---------------------------------------------------------------- flash attention (windowed causal GQA)
// Qb [16][2048][128], Kb [4][2048][128], VbT [4][128][2048] bf16 ; Ob [2048][16*128] bf16
__global__ __launch_bounds__(256) void attn_fwd(const unsigned short* __restrict__ Qb,
                                                const unsigned short* __restrict__ Kb,
                                                const unsigned short* __restrict__ VbT,
                                                unsigned short* __restrict__ Ob) {
    const int qt = blockIdx.x;  // 0..31 (64-row q tiles)
    const int h = blockIdx.y;   // 0..15
    const int kvh = h >> 2;
    const int q0 = qt * 64;
    // XOR-swizzled tiles (swizzle: col_byte ^= (row&7)<<4; inverse-swizzled global src)
    __shared__ unsigned short Ks[2][64 * 128];   // K rows x d, swizzled
    __shared__ unsigned short Vs[2][128 * 64];   // V^T: d rows x k, swizzled
    __shared__ unsigned short Ps[4][16 * 72];    // per-wave P, padded stride 72
    const int tid = threadIdx.x;
    const int lane = tid & 63, wave = tid >> 6;
    const int l15 = lane & 15, l4 = lane >> 4;

    bf16x8 qf[4];
    {
        const unsigned short* qrow =
            Qb + ((size_t)h * 2048 + q0 + wave * 16 + l15) * 128 + l4 * 8;
        for (int kk = 0; kk < 4; ++kk) qf[kk] = *(const bf16x8*)(qrow + kk * 32);
    }
    f32x4 o[8] = {};
    float m_run[4], l_run[4];
    for (int j = 0; j < 4; ++j) { m_run[j] = -1e30f; l_run[j] = 0.0f; }
    const float scale = 0.08838834764831843f;  // 1/sqrt(128)
    const int kt_lo = (qt >= 16) ? (qt - 16) : 0;

    const unsigned short* Kh = Kb + (size_t)kvh * 2048 * 128;
    const unsigned short* Vh = VbT + (size_t)kvh * 128 * 2048;

    // prologue: stage first tile into buffer 0
    {
        const int kt = kt_lo;
        for (int i = 0; i < 4; ++i) {
            int s = i * 256 + tid;
            int r = s >> 4;
            int cb = ((s & 15) * 16) ^ ((r & 7) << 4);
            gload_lds16(Kh + (size_t)(kt * 64 + r) * 128 + (cb >> 1), &Ks[0][s * 8]);
        }
        for (int i = 0; i < 4; ++i) {
            int s = i * 256 + tid;
            int d = s >> 3;
            int cb = ((s & 7) * 16) ^ ((d & 7) << 4);
            gload_lds16(Vh + (size_t)d * 2048 + kt * 64 + (cb >> 1), &Vs[0][s * 8]);
        }
    }

    int cur = 0;
    for (int kt = kt_lo; kt <= qt; ++kt) {
        __syncthreads();  // drains vmcnt -> tile `cur` ready; prev reads of cur^1 done

        // prefetch next tile into cur^1 (flies under this tile's compute)
        if (kt < qt) {
            const int kn = kt + 1;
            for (int i = 0; i < 4; ++i) {
                int s = i * 256 + tid;
                int r = s >> 4;
                int cb = ((s & 15) * 16) ^ ((r & 7) << 4);
                gload_lds16(Kh + (size_t)(kn * 64 + r) * 128 + (cb >> 1), &Ks[cur ^ 1][s * 8]);
            }
            for (int i = 0; i < 4; ++i) {
                int s = i * 256 + tid;
                int d = s >> 3;
                int cb = ((s & 7) * 16) ^ ((d & 7) << 4);
                gload_lds16(Vh + (size_t)d * 2048 + kn * 64 + (cb >> 1), &Vs[cur ^ 1][s * 8]);
            }
        }

        // S = Q K^T : wave's 16 rows x 64 keys (swizzled Ks reads)
        f32x4 s[4] = {};
        for (int nn = 0; nn < 4; ++nn)
            for (int kk = 0; kk < 4; ++kk) {
                int r = nn * 16 + l15;
                int cb = (kk * 64 + l4 * 16) ^ ((r & 7) << 4);
                bf16x8 kf = *(const bf16x8*)((const char*)&Ks[cur][0] + r * 256 + cb);
                s[nn] = MFMA16(qf[kk], kf, s[nn]);
            }

        // mask + online softmax
        float p[4][4], corr[4];
        for (int j = 0; j < 4; ++j) {
            const int qr = q0 + wave * 16 + l4 * 4 + j;
            float mx = -1e30f;
            for (int nn = 0; nn < 4; ++nn) {
                int kc = kt * 64 + nn * 16 + l15;
                float sv = s[nn][j] * scale;
                bool ok = (qr >= kc) && (qr - kc < 1024);
                sv = ok ? sv : -1e30f;
                p[nn][j] = sv;
                mx = fmaxf(mx, sv);
            }
            for (int mk = 8; mk; mk >>= 1) mx = fmaxf(mx, __shfl_xor(mx, mk));
            float mnew = fmaxf(m_run[j], mx);
            corr[j] = __expf(m_run[j] - mnew);
            float rs = 0.0f;
            for (int nn = 0; nn < 4; ++nn) {
                float pv = __expf(p[nn][j] - mnew);
                p[nn][j] = pv;
                rs += pv;
            }
            for (int mk = 8; mk; mk >>= 1) rs += __shfl_xor(rs, mk);
            l_run[j] = l_run[j] * corr[j] + rs;
            m_run[j] = mnew;
        }
        for (int dd = 0; dd < 8; ++dd)
            for (int j = 0; j < 4; ++j) o[dd][j] *= corr[j];

        // P -> LDS (bf16), per-wave buffer, padded stride 72
        for (int j = 0; j < 4; ++j)
            for (int nn = 0; nn < 4; ++nn)
                Ps[wave][(l4 * 4 + j) * 72 + nn * 16 + l15] = f2bf(p[nn][j]);

        bf16x8 pa[2];
        for (int kk2 = 0; kk2 < 2; ++kk2)
            pa[kk2] = *(const bf16x8*)&Ps[wave][l15 * 72 + kk2 * 32 + l4 * 8];

        // O += P V  (swizzled Vs reads)
        for (int dd = 0; dd < 8; ++dd)
            for (int kk2 = 0; kk2 < 2; ++kk2) {
                int d = dd * 16 + l15;
                int cb = (kk2 * 64 + l4 * 16) ^ ((d & 7) << 4);
                bf16x8 vf = *(const bf16x8*)((const char*)&Vs[cur][0] + d * 128 + cb);
                o[dd] = MFMA16(pa[kk2], vf, o[dd]);
            }
        cur ^= 1;
    }

    // epilogue: normalize and store
    for (int j = 0; j < 4; ++j) {
        float inv = 1.0f / l_run[j];
        int row = q0 + wave * 16 + l4 * 4 + j;
        unsigned short* orow = Ob + (size_t)row * 2048 + h * 128;
        for (int dd = 0; dd < 8; ++dd) orow[dd * 16 + l15] = f2bf(o[dd][j] * inv);
    }
}

// ---------------------------------------------------------------- launch
extern "C" void kernel_launch(void* const* d_in, const int* in_sizes, int n_in,
                              void* d_out, int out_size, void* d_ws, size_t ws_size,
                              hipStream_t stream) {
    const float* x  = (const float*)d_in[0];
    const float* wq = (const float*)d_in[1];
    const float* wk = (const float*)d_in[2];
    const float* wv = (const float*)d_in[3];
    const float* wo = (const float*)d_in[4];
    const float* qw = (const float*)d_in[5];
    const float* kw = (const float*)d_in[6];
    float* out = (float*)d_out;

    char* ws = (char*)d_ws;
    unsigned short* xb   = (unsigned short*)(ws + 0);          //  8 MB  x bf16 [2048][2048]
    unsigned short* wqkv = (unsigned short*)(ws + 8388608);    // 12 MB  [3072][2048]
    unsigned short* wob  = (unsigned short*)(ws + 20971520);   //  8 MB  [2048][2048]
    float*          qkv  = (float*)(ws + 29360128);            // 24 MB  [2048][3072]
    unsigned short* Qb   = (unsigned short*)(ws + 54525952);   //  8 MB  [16][2048][128]
    unsigned short* Kb   = (unsigned short*)(ws + 62914560);   //  2 MB  [4][2048][128]
    unsigned short* Vb   = (unsigned short*)(ws + 65011712);   //  2 MB  [4][2048][128]
    unsigned short* Ob   = (unsigned short*)(ws + 67108864);   //  8 MB  [2048][2048]
    // VbT aliases the (dead after norm_rope) qkv region
    unsigned short* VbT  = (unsigned short*)(ws + 29360128);   //  2 MB  [4][128][2048]

    convert_bf16<<<dim3(4096), dim3(256), 0, stream>>>(x, xb, 2048 * 2048);
    convert_bf16<<<dim3(4096), dim3(256), 0, stream>>>(wq, wqkv, 2048 * 2048);
    convert_bf16<<<dim3(1024), dim3(256), 0, stream>>>(wk, wqkv + 2048 * 2048, 512 * 2048);
    convert_bf16<<<dim3(1024), dim3(256), 0, stream>>>(wv, wqkv + 2560 * 2048, 512 * 2048);
    convert_bf16<<<dim3(4096), dim3(256), 0, stream>>>(wo, wob, 2048 * 2048);

    gemm_bt<<<dim3(24, 16), dim3(256), 0, stream>>>(xb, wqkv, qkv, 2048, 3072, 2048);
    norm_rope<<<dim3(2048, 24), dim3(64), 0, stream>>>(qkv, qw, kw, Qb, Kb, Vb);
    transpose_v<<<dim3(32, 4), dim3(256), 0, stream>>>(Vb, VbT);
    attn_fwd<<<dim3(32, 16), dim3(256), 0, stream>>>(Qb, Kb, VbT, Ob);
    gemm_bt<<<dim3(16, 16), dim3(256), 0, stream>>>(Ob, wob, out, 2048, 2048, 2048);
}

// Round 3
// 181.269 us; speedup vs baseline: 1.4976x; 1.0554x over previous
//
#include <hip/hip_runtime.h>
#include <hip/hip_bf16.h>
#include <cstdint>
#include <cstddef>

typedef __attribute__((ext_vector_type(4))) float f32x4;
typedef __attribute__((ext_vector_type(8))) short bf16x8;
typedef __attribute__((ext_vector_type(8))) unsigned short us8;

#define MFMA16(a, b, c) __builtin_amdgcn_mfma_f32_16x16x32_bf16(a, b, c, 0, 0, 0)

__device__ inline unsigned short f2bf(float f) {
    unsigned int u = __float_as_uint(f);
    u += 0x7fffu + ((u >> 16) & 1u);
    return (unsigned short)(u >> 16);
}

__device__ inline void gload_lds16(const void* g, void* l) {
    __builtin_amdgcn_global_load_lds(
        (const __attribute__((address_space(1))) void*)g,
        (__attribute__((address_space(3))) void*)l, 16, 0, 0);
}

// ---------------------------------------------------------------- converts
__global__ __launch_bounds__(256) void convert_bf16(const float* __restrict__ src,
                                                    unsigned short* __restrict__ dst,
                                                    int n) {
    int i = (blockIdx.x * 256 + threadIdx.x) * 4;
    if (i >= n) return;
    float4 v = *(const float4*)(src + i);
    ushort4 o;
    o.x = f2bf(v.x); o.y = f2bf(v.y); o.z = f2bf(v.z); o.w = f2bf(v.w);
    *(ushort4*)(dst + i) = o;
}

// ---------------------------------------------------------------- GEMM  C[M,N] = A[M,K] * B[N,K]^T
// single-barrier double-buffered 2-phase; XCD-bijective block swizzle
__global__ __launch_bounds__(256) void gemm_bt(const unsigned short* __restrict__ A,
                                               const unsigned short* __restrict__ B,
                                               float* __restrict__ C,
                                               int M, int N, int K) {
    __shared__ unsigned short As[2][128 * 32];
    __shared__ unsigned short Bs[2][128 * 32];
    const int tid = threadIdx.x;
    const int lane = tid & 63, wave = tid >> 6;
    const int wr = wave >> 1, wc = wave & 1;
    // bijective XCD swizzle (m204): consecutive wgid cluster on one XCD
    const int gx = gridDim.x;
    const int nwg = gx * gridDim.y;
    const int bid0 = blockIdx.y * gx + blockIdx.x;
    const int q8 = nwg >> 3, r8 = nwg & 7;
    const int xcd = bid0 & 7, sub = bid0 >> 3;
    const int wgid = ((xcd < r8) ? xcd * (q8 + 1) : r8 * (q8 + 1) + (xcd - r8) * q8) + sub;
    const int bm = wgid / gx, bn = wgid % gx;
    const int l15 = lane & 15, l4 = lane >> 4;
    f32x4 acc[4][4] = {};
    const int nK = K >> 5;

    // prologue: stage K-tile 0 into buffer 0
    for (int i = 0; i < 2; ++i) {
        int e = (i * 256 + tid) * 8;
        int r = e >> 5, c = e & 31;
        gload_lds16(A + (size_t)(bm * 128 + r) * K + c, &As[0][e]);
        gload_lds16(B + (size_t)(bn * 128 + r) * K + c, &Bs[0][e]);
    }
    int cur = 0;
    for (int kt = 0; kt < nK; ++kt) {
        __syncthreads();  // vmcnt(0)+barrier: buf[cur] staged, prior reads of buf^1 done
        if (kt + 1 < nK) {  // prefetch next tile; flies under this tile's compute
            for (int i = 0; i < 2; ++i) {
                int e = (i * 256 + tid) * 8;
                int r = e >> 5, c = e & 31;
                gload_lds16(A + (size_t)(bm * 128 + r) * K + (kt + 1) * 32 + c, &As[cur ^ 1][e]);
                gload_lds16(B + (size_t)(bn * 128 + r) * K + (kt + 1) * 32 + c, &Bs[cur ^ 1][e]);
            }
        }
        bf16x8 af[4], bfr[4];
        for (int m = 0; m < 4; ++m)
            af[m] = *(const bf16x8*)&As[cur][(wr * 64 + m * 16 + l15) * 32 + l4 * 8];
        for (int n = 0; n < 4; ++n)
            bfr[n] = *(const bf16x8*)&Bs[cur][(wc * 64 + n * 16 + l15) * 32 + l4 * 8];
        for (int m = 0; m < 4; ++m)
            for (int n = 0; n < 4; ++n)
                acc[m][n] = MFMA16(af[m], bfr[n], acc[m][n]);
        cur ^= 1;
    }
    for (int m = 0; m < 4; ++m)
        for (int n = 0; n < 4; ++n)
            for (int j = 0; j < 4; ++j) {
                int row = bm * 128 + wr * 64 + m * 16 + l4 * 4 + j;
                int col = bn * 128 + wc * 64 + n * 16 + l15;
                C[(size_t)row * N + col] = acc[m][n][j];
            }
}

// ---------------------------------------------------------------- RoPE table (one-time)
__global__ __launch_bounds__(64) void rope_table(float2* __restrict__ tbl) {
    int row = blockIdx.x, t = threadIdx.x;
    float inv_freq = exp2f((float)t * (-2.0f / 128.0f) * 13.287712379549449f);  // log2(10000)
    float s, c;
    sincosf((float)row * inv_freq, &s, &c);
    tbl[row * 64 + t] = make_float2(c, s);
}

// ---------------------------------------------------------------- RMSNorm + RoPE + repack
// qkv f32 [2048][3072]; heads 0..15 -> Q, 16..19 -> K, 20..23 -> V
__global__ __launch_bounds__(256) void norm_rope(const float* __restrict__ qkv,
                                                 const float* __restrict__ qw,
                                                 const float* __restrict__ kw,
                                                 const float2* __restrict__ tbl,
                                                 unsigned short* __restrict__ Qb,
                                                 unsigned short* __restrict__ Kb,
                                                 unsigned short* __restrict__ Vb) {
    const int row = blockIdx.x;                          // 0..2047
    const int head = blockIdx.y * 4 + (threadIdx.x >> 6); // 0..23
    const int t = threadIdx.x & 63;
    const float* src = qkv + (size_t)row * 3072 + head * 128;
    float x1 = src[t], x2 = src[t + 64];
    if (head < 20) {
        float ss = x1 * x1 + x2 * x2;
        for (int m = 32; m; m >>= 1) ss += __shfl_xor(ss, m);
        float r = rsqrtf(ss * (1.0f / 128.0f) + 1e-6f);
        const float* w = (head < 16) ? qw : kw;
        float y1 = x1 * r * w[t], y2 = x2 * r * w[t + 64];
        float2 cs = tbl[row * 64 + t];
        x1 = y1 * cs.x - y2 * cs.y;
        x2 = y1 * cs.y + y2 * cs.x;
    }
    unsigned short* dst;
    if (head < 16)      dst = Qb + ((size_t)head * 2048 + row) * 128;
    else if (head < 20) dst = Kb + ((size_t)(head - 16) * 2048 + row) * 128;
    else                dst = Vb + ((size_t)(head - 20) * 2048 + row) * 128;
    dst[t] = f2bf(x1);
    dst[t + 64] = f2bf(x2);
}

// ---------------------------------------------------------------- V transpose: Vb [4][2048][128] -> VbT [4][128][2048]
__global__ __launch_bounds__(256) void transpose_v(const unsigned short* __restrict__ Vb,
                                                   unsigned short* __restrict__ VbT) {
    const int kt = blockIdx.x;  // 0..31
    const int h  = blockIdx.y;  // 0..3
    __shared__ unsigned short T[64 * 130];
    const int tid = threadIdx.x;
    for (int i = 0; i < 4; ++i) {
        int s = i * 256 + tid;
        int r = s >> 4, c = (s & 15) * 8;
        us8 v = *(const us8*)(Vb + ((size_t)h * 2048 + kt * 64 + r) * 128 + c);
        for (int j = 0; j < 8; ++j) T[r * 130 + c + j] = v[j];
    }
    __syncthreads();
    for (int i = 0; i < 4; ++i) {
        int s = i * 256 + tid;
        int d = s >> 3, ck = (s & 7) * 8;
        us8 v;
        for (int j = 0; j < 8; ++j) v[j] = T[(ck + j) * 130 + d];
        *(us8*)(VbT + (size_t)h * 128 * 2048 + (size_t)d * 2048 + kt * 64 + ck) = v;
    }
}

// ---------------------------------------------------------------- flash attention (windowed causal GQA)
// Qb [16][2048][128], Kb [4][2048][128], VbT [4][128][2048] bf16 ; Ob [2048][16*128] bf16
__global__ __launch_bounds__(256) void attn_fwd(const unsigned short* __restrict__ Qb,
                                                const unsigned short* __restrict__ Kb,
                                                const unsigned short* __restrict__ VbT,
                                                unsigned short* __restrict__ Ob) {
    const int qt = blockIdx.x;  // 0..31
    const int h = blockIdx.y;   // 0..15
    const int kvh = h >> 2;
    const int q0 = qt * 64;
    __shared__ unsigned short Ks[2][64 * 128];   // swizzled: cbyte ^= (row&7)<<4
    __shared__ unsigned short Vs[2][128 * 64];   // V^T swizzled
    __shared__ unsigned short Ps[4][16 * 72];
    const int tid = threadIdx.x;
    const int lane = tid & 63, wave = tid >> 6;
    const int l15 = lane & 15, l4 = lane >> 4;

    bf16x8 qf[4];
    {
        const unsigned short* qrow =
            Qb + ((size_t)h * 2048 + q0 + wave * 16 + l15) * 128 + l4 * 8;
        for (int kk = 0; kk < 4; ++kk) qf[kk] = *(const bf16x8*)(qrow + kk * 32);
    }
    f32x4 o[8] = {};
    float m_run[4], l_run[4];
    for (int j = 0; j < 4; ++j) { m_run[j] = -1e30f; l_run[j] = 0.0f; }
    const float scale = 0.08838834764831843f;
    const int kt_lo = (qt >= 16) ? (qt - 16) : 0;

    const unsigned short* Kh = Kb + (size_t)kvh * 2048 * 128;
    const unsigned short* Vh = VbT + (size_t)kvh * 128 * 2048;

    {   // prologue: stage first tile into buffer 0
        const int kt = kt_lo;
        for (int i = 0; i < 4; ++i) {
            int s = i * 256 + tid;
            int r = s >> 4;
            int cb = ((s & 15) * 16) ^ ((r & 7) << 4);
            gload_lds16(Kh + (size_t)(kt * 64 + r) * 128 + (cb >> 1), &Ks[0][s * 8]);
        }
        for (int i = 0; i < 4; ++i) {
            int s = i * 256 + tid;
            int d = s >> 3;
            int cb = ((s & 7) * 16) ^ ((d & 7) << 4);
            gload_lds16(Vh + (size_t)d * 2048 + kt * 64 + (cb >> 1), &Vs[0][s * 8]);
        }
    }

    int cur = 0;
    for (int kt = kt_lo; kt <= qt; ++kt) {
        __syncthreads();  // vmcnt(0)+barrier: tile cur staged; prev reads done

        if (kt < qt) {  // prefetch next tile
            const int kn = kt + 1;
            for (int i = 0; i < 4; ++i) {
                int s = i * 256 + tid;
                int r = s >> 4;
                int cb = ((s & 15) * 16) ^ ((r & 7) << 4);
                gload_lds16(Kh + (size_t)(kn * 64 + r) * 128 + (cb >> 1), &Ks[cur ^ 1][s * 8]);
            }
            for (int i = 0; i < 4; ++i) {
                int s = i * 256 + tid;
                int d = s >> 3;
                int cb = ((s & 7) * 16) ^ ((d & 7) << 4);
                gload_lds16(Vh + (size_t)d * 2048 + kn * 64 + (cb >> 1), &Vs[cur ^ 1][s * 8]);
            }
        }

        // S = Q K^T
        f32x4 s[4] = {};
        __builtin_amdgcn_s_setprio(1);
        for (int nn = 0; nn < 4; ++nn)
            for (int kk = 0; kk < 4; ++kk) {
                int r = nn * 16 + l15;
                int cb = (kk * 64 + l4 * 16) ^ ((r & 7) << 4);
                bf16x8 kf = *(const bf16x8*)((const char*)&Ks[cur][0] + r * 256 + cb);
                s[nn] = MFMA16(qf[kk], kf, s[nn]);
            }
        __builtin_amdgcn_s_setprio(0);

        // mask + online softmax
        float p[4][4], corr[4];
        for (int j = 0; j < 4; ++j) {
            const int qr = q0 + wave * 16 + l4 * 4 + j;
            float mx = -1e30f;
            for (int nn = 0; nn < 4; ++nn) {
                int kc = kt * 64 + nn * 16 + l15;
                float sv = s[nn][j] * scale;
                bool ok = (qr >= kc) && (qr - kc < 1024);
                sv = ok ? sv : -1e30f;
                p[nn][j] = sv;
                mx = fmaxf(mx, sv);
            }
            for (int mk = 8; mk; mk >>= 1) mx = fmaxf(mx, __shfl_xor(mx, mk));
            float mnew = fmaxf(m_run[j], mx);
            corr[j] = __expf(m_run[j] - mnew);
            float rs = 0.0f;
            for (int nn = 0; nn < 4; ++nn) {
                float pv = __expf(p[nn][j] - mnew);
                p[nn][j] = pv;
                rs += pv;
            }
            for (int mk = 8; mk; mk >>= 1) rs += __shfl_xor(rs, mk);
            l_run[j] = l_run[j] * corr[j] + rs;
            m_run[j] = mnew;
        }
        for (int dd = 0; dd < 8; ++dd)
            for (int j = 0; j < 4; ++j) o[dd][j] *= corr[j];

        // P -> LDS (bf16)
        for (int j = 0; j < 4; ++j)
            for (int nn = 0; nn < 4; ++nn)
                Ps[wave][(l4 * 4 + j) * 72 + nn * 16 + l15] = f2bf(p[nn][j]);

        bf16x8 pa[2];
        for (int kk2 = 0; kk2 < 2; ++kk2)
            pa[kk2] = *(const bf16x8*)&Ps[wave][l15 * 72 + kk2 * 32 + l4 * 8];

        // O += P V
        __builtin_amdgcn_s_setprio(1);
        for (int dd = 0; dd < 8; ++dd)
            for (int kk2 = 0; kk2 < 2; ++kk2) {
                int d = dd * 16 + l15;
                int cb = (kk2 * 64 + l4 * 16) ^ ((d & 7) << 4);
                bf16x8 vf = *(const bf16x8*)((const char*)&Vs[cur][0] + d * 128 + cb);
                o[dd] = MFMA16(pa[kk2], vf, o[dd]);
            }
        __builtin_amdgcn_s_setprio(0);
        cur ^= 1;
    }

    for (int j = 0; j < 4; ++j) {
        float inv = 1.0f / l_run[j];
        int row = q0 + wave * 16 + l4 * 4 + j;
        unsigned short* orow = Ob + (size_t)row * 2048 + h * 128;
        for (int dd = 0; dd < 8; ++dd) orow[dd * 16 + l15] = f2bf(o[dd][j] * inv);
    }
}

// ---------------------------------------------------------------- launch
extern "C" void kernel_launch(void* const* d_in, const int* in_sizes, int n_in,
                              void* d_out, int out_size, void* d_ws, size_t ws_size,
                              hipStream_t stream) {
    const float* x  = (const float*)d_in[0];
    const float* wq = (const float*)d_in[1];
    const float* wk = (const float*)d_in[2];
    const float* wv = (const float*)d_in[3];
    const float* wo = (const float*)d_in[4];
    const float* qw = (const float*)d_in[5];
    const float* kw = (const float*)d_in[6];
    float* out = (float*)d_out;

    char* ws = (char*)d_ws;
    unsigned short* xb   = (unsigned short*)(ws + 0);          //  8 MB  x bf16 [2048][2048]
    unsigned short* wqkv = (unsigned short*)(ws + 8388608);    // 12 MB  [3072][2048]
    unsigned short* wob  = (unsigned short*)(ws + 20971520);   //  8 MB  [2048][2048]
    float*          qkv  = (float*)(ws + 29360128);            // 24 MB  [2048][3072]
    unsigned short* Qb   = (unsigned short*)(ws + 54525952);   //  8 MB  [16][2048][128]
    unsigned short* Kb   = (unsigned short*)(ws + 62914560);   //  2 MB  [4][2048][128]
    unsigned short* Vb   = (unsigned short*)(ws + 65011712);   //  2 MB  [4][2048][128]
    unsigned short* Ob   = (unsigned short*)(ws + 67108864);   //  8 MB  [2048][2048]
    unsigned short* VbT  = (unsigned short*)(ws + 29360128);   //  2 MB  aliases dead qkv
    float2*         tbl  = (float2*)(ws + 0);                  //  1 MB  aliases dead xb

    convert_bf16<<<dim3(4096), dim3(256), 0, stream>>>(x, xb, 2048 * 2048);
    convert_bf16<<<dim3(4096), dim3(256), 0, stream>>>(wq, wqkv, 2048 * 2048);
    convert_bf16<<<dim3(1024), dim3(256), 0, stream>>>(wk, wqkv + 2048 * 2048, 512 * 2048);
    convert_bf16<<<dim3(1024), dim3(256), 0, stream>>>(wv, wqkv + 2560 * 2048, 512 * 2048);
    convert_bf16<<<dim3(4096), dim3(256), 0, stream>>>(wo, wob, 2048 * 2048);

    gemm_bt<<<dim3(24, 16), dim3(256), 0, stream>>>(xb, wqkv, qkv, 2048, 3072, 2048);
    rope_table<<<dim3(2048), dim3(64), 0, stream>>>(tbl);  // xb dead now
    norm_rope<<<dim3(2048, 6), dim3(256), 0, stream>>>(qkv, qw, kw, tbl, Qb, Kb, Vb);
    transpose_v<<<dim3(32, 4), dim3(256), 0, stream>>>(Vb, VbT);
    attn_fwd<<<dim3(32, 16), dim3(256), 0, stream>>>(Qb, Kb, VbT, Ob);
    gemm_bt<<<dim3(16, 16), dim3(256), 0, stream>>>(Ob, wob, out, 2048, 2048, 2048);
}

// Round 4
// 169.083 us; speedup vs baseline: 1.6055x; 1.0721x over previous
//
#include <hip/hip_runtime.h>
#include <hip/hip_bf16.h>
#include <cstdint>
#include <cstddef>

typedef __attribute__((ext_vector_type(4))) float f32x4;
typedef __attribute__((ext_vector_type(8))) short bf16x8;
typedef __attribute__((ext_vector_type(8))) unsigned short us8;

#define MFMA16(a, b, c) __builtin_amdgcn_mfma_f32_16x16x32_bf16(a, b, c, 0, 0, 0)

__device__ inline unsigned short f2bf(float f) {
    unsigned int u = __float_as_uint(f);
    u += 0x7fffu + ((u >> 16) & 1u);
    return (unsigned short)(u >> 16);
}
__device__ inline float bf2f(unsigned short u) {
    return __uint_as_float((unsigned int)u << 16);
}

__device__ inline void gload_lds16(const void* g, void* l) {
    __builtin_amdgcn_global_load_lds(
        (const __attribute__((address_space(1))) void*)g,
        (__attribute__((address_space(3))) void*)l, 16, 0, 0);
}

// ---------------------------------------------------------------- converts
__global__ __launch_bounds__(256) void convert_bf16(const float* __restrict__ src,
                                                    unsigned short* __restrict__ dst,
                                                    int n) {
    int i = (blockIdx.x * 256 + threadIdx.x) * 4;
    if (i >= n) return;
    float4 v = *(const float4*)(src + i);
    ushort4 o;
    o.x = f2bf(v.x); o.y = f2bf(v.y); o.z = f2bf(v.z); o.w = f2bf(v.w);
    *(ushort4*)(dst + i) = o;
}

// ---------------------------------------------------------------- RoPE table (one-time)
__global__ __launch_bounds__(64) void rope_table(float2* __restrict__ tbl) {
    int row = blockIdx.x, t = threadIdx.x;
    float inv_freq = exp2f((float)t * (-2.0f / 128.0f) * 13.287712379549449f);  // log2(10000)
    float s, c;
    sincosf((float)row * inv_freq, &s, &c);
    tbl[row * 64 + t] = make_float2(c, s);
}

// ---------------------------------------------------------------- GEMM  C[M,N] = A[M,K]*B[N,K]^T  (f32 out)
__global__ __launch_bounds__(256) void gemm_bt(const unsigned short* __restrict__ A,
                                               const unsigned short* __restrict__ B,
                                               float* __restrict__ C,
                                               int M, int N, int K) {
    __shared__ unsigned short As[2][128 * 32];
    __shared__ unsigned short Bs[2][128 * 32];
    const int tid = threadIdx.x;
    const int lane = tid & 63, wave = tid >> 6;
    const int wr = wave >> 1, wc = wave & 1;
    const int gx = gridDim.x;
    const int nwg = gx * gridDim.y;
    const int bid0 = blockIdx.y * gx + blockIdx.x;
    const int q8 = nwg >> 3, r8 = nwg & 7;
    const int xcd = bid0 & 7, sub = bid0 >> 3;
    const int wgid = ((xcd < r8) ? xcd * (q8 + 1) : r8 * (q8 + 1) + (xcd - r8) * q8) + sub;
    const int bm = wgid / gx, bn = wgid % gx;
    const int l15 = lane & 15, l4 = lane >> 4;
    f32x4 acc[4][4] = {};
    const int nK = K >> 5;

    for (int i = 0; i < 2; ++i) {
        int e = (i * 256 + tid) * 8;
        int r = e >> 5, c = e & 31;
        gload_lds16(A + (size_t)(bm * 128 + r) * K + c, &As[0][e]);
        gload_lds16(B + (size_t)(bn * 128 + r) * K + c, &Bs[0][e]);
    }
    int cur = 0;
    for (int kt = 0; kt < nK; ++kt) {
        __syncthreads();
        if (kt + 1 < nK) {
            for (int i = 0; i < 2; ++i) {
                int e = (i * 256 + tid) * 8;
                int r = e >> 5, c = e & 31;
                gload_lds16(A + (size_t)(bm * 128 + r) * K + (kt + 1) * 32 + c, &As[cur ^ 1][e]);
                gload_lds16(B + (size_t)(bn * 128 + r) * K + (kt + 1) * 32 + c, &Bs[cur ^ 1][e]);
            }
        }
        bf16x8 af[4], bfr[4];
        for (int m = 0; m < 4; ++m)
            af[m] = *(const bf16x8*)&As[cur][(wr * 64 + m * 16 + l15) * 32 + l4 * 8];
        for (int n = 0; n < 4; ++n)
            bfr[n] = *(const bf16x8*)&Bs[cur][(wc * 64 + n * 16 + l15) * 32 + l4 * 8];
        for (int m = 0; m < 4; ++m)
            for (int n = 0; n < 4; ++n)
                acc[m][n] = MFMA16(af[m], bfr[n], acc[m][n]);
        cur ^= 1;
    }
    for (int m = 0; m < 4; ++m)
        for (int n = 0; n < 4; ++n)
            for (int j = 0; j < 4; ++j) {
                int row = bm * 128 + wr * 64 + m * 16 + l4 * 4 + j;
                int col = bn * 128 + wc * 64 + n * 16 + l15;
                C[(size_t)row * N + col] = acc[m][n][j];
            }
}

// ---------------------------------------------------------------- QKV GEMM with fused RMSNorm+RoPE epilogue
// A=xb[2048][2048], B=wqkv[3072][2048]; block bn = head (0..23); M=2048,N=3072,K=2048
__global__ __launch_bounds__(256) void gemm_qkv(const unsigned short* __restrict__ A,
                                                const unsigned short* __restrict__ B,
                                                const float* __restrict__ qw,
                                                const float* __restrict__ kw,
                                                const float2* __restrict__ tbl,
                                                unsigned short* __restrict__ Qb,
                                                unsigned short* __restrict__ Kb,
                                                unsigned short* __restrict__ Vb) {
    constexpr int K = 2048;
    __shared__ __align__(16) char sm[35840];           // union: {As,Bs dbuf 32KB} | {ybuf 34.8KB + ssbuf 1KB}
    unsigned short* As = (unsigned short*)sm;          // [2][4096]
    unsigned short* Bs = As + 8192;                    // [2][4096]
    const int tid = threadIdx.x;
    const int lane = tid & 63, wave = tid >> 6;
    const int wr = wave >> 1, wc = wave & 1;
    const int gx = gridDim.x;                          // 24
    const int nwg = gx * gridDim.y;
    const int bid0 = blockIdx.y * gx + blockIdx.x;
    const int q8 = nwg >> 3, r8 = nwg & 7;
    const int xcd = bid0 & 7, sub = bid0 >> 3;
    const int wgid = ((xcd < r8) ? xcd * (q8 + 1) : r8 * (q8 + 1) + (xcd - r8) * q8) + sub;
    const int bm = wgid / gx, bn = wgid % gx;
    const int l15 = lane & 15, l4 = lane >> 4;
    f32x4 acc[4][4] = {};
    constexpr int nK = K >> 5;

    for (int i = 0; i < 2; ++i) {
        int e = (i * 256 + tid) * 8;
        int r = e >> 5, c = e & 31;
        gload_lds16(A + (size_t)(bm * 128 + r) * K + c, &As[e]);
        gload_lds16(B + (size_t)(bn * 128 + r) * K + c, &Bs[e]);
    }
    int cur = 0;
    for (int kt = 0; kt < nK; ++kt) {
        __syncthreads();
        if (kt + 1 < nK) {
            for (int i = 0; i < 2; ++i) {
                int e = (i * 256 + tid) * 8;
                int r = e >> 5, c = e & 31;
                gload_lds16(A + (size_t)(bm * 128 + r) * K + (kt + 1) * 32 + c, &As[(cur ^ 1) * 4096 + e]);
                gload_lds16(B + (size_t)(bn * 128 + r) * K + (kt + 1) * 32 + c, &Bs[(cur ^ 1) * 4096 + e]);
            }
        }
        bf16x8 af[4], bfr[4];
        for (int m = 0; m < 4; ++m)
            af[m] = *(const bf16x8*)&As[cur * 4096 + (wr * 64 + m * 16 + l15) * 32 + l4 * 8];
        for (int n = 0; n < 4; ++n)
            bfr[n] = *(const bf16x8*)&Bs[cur * 4096 + (wc * 64 + n * 16 + l15) * 32 + l4 * 8];
        for (int m = 0; m < 4; ++m)
            for (int n = 0; n < 4; ++n)
                acc[m][n] = MFMA16(af[m], bfr[n], acc[m][n]);
        cur ^= 1;
    }

    // ---------------- fused epilogue ----------------
    const int head = bn;
    __syncthreads();  // all waves done with As/Bs; union region reusable
    if (head >= 20) {  // V: plain bf16 write
        unsigned short* dst = Vb + (size_t)(head - 20) * 2048 * 128;
        for (int m = 0; m < 4; ++m)
            for (int j = 0; j < 4; ++j) {
                int row = bm * 128 + wr * 64 + m * 16 + l4 * 4 + j;
                for (int n = 0; n < 4; ++n)
                    dst[(size_t)row * 128 + wc * 64 + n * 16 + l15] = f2bf(acc[m][n][j]);
            }
        return;
    }
    unsigned short* ybuf = (unsigned short*)sm;        // [128][136] bf16
    float* ssbuf = (float*)(sm + 34816);               // [2][128]
    // row sum-of-squares (this wave's 64 cols) -> cross-wave via LDS
    for (int m = 0; m < 4; ++m)
        for (int j = 0; j < 4; ++j) {
            float ss = 0.0f;
            for (int n = 0; n < 4; ++n) ss += acc[m][n][j] * acc[m][n][j];
            for (int mk = 8; mk; mk >>= 1) ss += __shfl_xor(ss, mk);
            if (l15 == 0) ssbuf[wc * 128 + wr * 64 + m * 16 + l4 * 4 + j] = ss;
        }
    __syncthreads();
    const float* w = (head < 16) ? qw : kw;
    float wv4[4];
    for (int n = 0; n < 4; ++n) wv4[n] = w[wc * 64 + n * 16 + l15];
    float rr[4][4];
    for (int m = 0; m < 4; ++m)
        for (int j = 0; j < 4; ++j) {
            int lrow = wr * 64 + m * 16 + l4 * 4 + j;
            float tot = ssbuf[lrow] + ssbuf[128 + lrow];
            rr[m][j] = rsqrtf(tot * (1.0f / 128.0f) + 1e-6f);
        }
    // normalized y -> LDS (bf16) for the RoPE pair exchange
    for (int m = 0; m < 4; ++m)
        for (int j = 0; j < 4; ++j) {
            int lrow = wr * 64 + m * 16 + l4 * 4 + j;
            for (int n = 0; n < 4; ++n)
                ybuf[lrow * 136 + wc * 64 + n * 16 + l15] = f2bf(acc[m][n][j] * rr[m][j] * wv4[n]);
        }
    __syncthreads();
    unsigned short* dstbase = (head < 16) ? Qb + (size_t)head * 2048 * 128
                                          : Kb + (size_t)(head - 16) * 2048 * 128;
    for (int m = 0; m < 4; ++m)
        for (int j = 0; j < 4; ++j) {
            int lrow = wr * 64 + m * 16 + l4 * 4 + j;
            int grow = bm * 128 + lrow;
            for (int n = 0; n < 4; ++n) {
                int col = wc * 64 + n * 16 + l15;
                float2 cs = tbl[grow * 64 + (col & 63)];
                float own = bf2f(ybuf[lrow * 136 + col]);
                float par = bf2f(ybuf[lrow * 136 + (col ^ 64)]);
                float outv = (wc == 0) ? own * cs.x - par * cs.y
                                       : par * cs.y + own * cs.x;
                dstbase[(size_t)grow * 128 + col] = f2bf(outv);
            }
        }
}

// ---------------------------------------------------------------- V transpose: Vb [4][2048][128] -> VbT [4][128][2048]
__global__ __launch_bounds__(256) void transpose_v(const unsigned short* __restrict__ Vb,
                                                   unsigned short* __restrict__ VbT) {
    const int kt = blockIdx.x;  // 0..31
    const int h  = blockIdx.y;  // 0..3
    __shared__ unsigned short T[64 * 130];
    const int tid = threadIdx.x;
    for (int i = 0; i < 4; ++i) {
        int s = i * 256 + tid;
        int r = s >> 4, c = (s & 15) * 8;
        us8 v = *(const us8*)(Vb + ((size_t)h * 2048 + kt * 64 + r) * 128 + c);
        for (int j = 0; j < 8; ++j) T[r * 130 + c + j] = v[j];
    }
    __syncthreads();
    for (int i = 0; i < 4; ++i) {
        int s = i * 256 + tid;
        int d = s >> 3, ck = (s & 7) * 8;
        us8 v;
        for (int j = 0; j < 8; ++j) v[j] = T[(ck + j) * 130 + d];
        *(us8*)(VbT + (size_t)h * 128 * 2048 + (size_t)d * 2048 + kt * 64 + ck) = v;
    }
}

// ---------------------------------------------------------------- flash attention (windowed causal GQA)
__global__ __launch_bounds__(256) void attn_fwd(const unsigned short* __restrict__ Qb,
                                                const unsigned short* __restrict__ Kb,
                                                const unsigned short* __restrict__ VbT,
                                                unsigned short* __restrict__ Ob) {
    const int qt = blockIdx.x;  // 0..31
    const int h = blockIdx.y;   // 0..15
    const int kvh = h >> 2;
    const int q0 = qt * 64;
    __shared__ unsigned short Ks[2][64 * 128];   // swizzled: cbyte ^= (row&7)<<4
    __shared__ unsigned short Vs[2][128 * 64];   // V^T swizzled
    __shared__ unsigned short Ps[4][16 * 72];
    const int tid = threadIdx.x;
    const int lane = tid & 63, wave = tid >> 6;
    const int l15 = lane & 15, l4 = lane >> 4;

    bf16x8 qf[4];
    {
        const unsigned short* qrow =
            Qb + ((size_t)h * 2048 + q0 + wave * 16 + l15) * 128 + l4 * 8;
        for (int kk = 0; kk < 4; ++kk) qf[kk] = *(const bf16x8*)(qrow + kk * 32);
    }
    f32x4 o[8] = {};
    float m2[4], lp[4];
    for (int j = 0; j < 4; ++j) { m2[j] = -1e30f; lp[j] = 0.0f; }
    const float SCALE2 = 0.08838834764831843f * 1.4426950408889634f;  // scale*log2(e)
    const int kt_lo = (qt >= 16) ? (qt - 16) : 0;

    const unsigned short* Kh = Kb + (size_t)kvh * 2048 * 128;
    const unsigned short* Vh = VbT + (size_t)kvh * 128 * 2048;

    {   // prologue: stage first tile into buffer 0
        const int kt = kt_lo;
        for (int i = 0; i < 4; ++i) {
            int s = i * 256 + tid;
            int r = s >> 4;
            int cb = ((s & 15) * 16) ^ ((r & 7) << 4);
            gload_lds16(Kh + (size_t)(kt * 64 + r) * 128 + (cb >> 1), &Ks[0][s * 8]);
        }
        for (int i = 0; i < 4; ++i) {
            int s = i * 256 + tid;
            int d = s >> 3;
            int cb = ((s & 7) * 16) ^ ((d & 7) << 4);
            gload_lds16(Vh + (size_t)d * 2048 + kt * 64 + (cb >> 1), &Vs[0][s * 8]);
        }
    }

    int cur = 0;
    for (int kt = kt_lo; kt <= qt; ++kt) {
        __syncthreads();  // vmcnt(0)+barrier: tile cur staged; prev reads done

        if (kt < qt) {  // prefetch next tile
            const int kn = kt + 1;
            for (int i = 0; i < 4; ++i) {
                int s = i * 256 + tid;
                int r = s >> 4;
                int cb = ((s & 15) * 16) ^ ((r & 7) << 4);
                gload_lds16(Kh + (size_t)(kn * 64 + r) * 128 + (cb >> 1), &Ks[cur ^ 1][s * 8]);
            }
            for (int i = 0; i < 4; ++i) {
                int s = i * 256 + tid;
                int d = s >> 3;
                int cb = ((s & 7) * 16) ^ ((d & 7) << 4);
                gload_lds16(Vh + (size_t)d * 2048 + kn * 64 + (cb >> 1), &Vs[cur ^ 1][s * 8]);
            }
        }

        // S = Q K^T
        f32x4 s[4] = {};
        __builtin_amdgcn_s_setprio(1);
        for (int nn = 0; nn < 4; ++nn)
            for (int kk = 0; kk < 4; ++kk) {
                int r = nn * 16 + l15;
                int cb = (kk * 64 + l4 * 16) ^ ((r & 7) << 4);
                bf16x8 kf = *(const bf16x8*)((const char*)&Ks[cur][0] + r * 256 + cb);
                s[nn] = MFMA16(qf[kk], kf, s[nn]);
            }
        __builtin_amdgcn_s_setprio(0);

        // scale into log2 domain; mask only boundary tiles (uniform branch)
        float p[4][4];
        const bool masked = (kt == qt) || (qt >= 16 && kt == kt_lo);
        if (masked) {
            for (int nn = 0; nn < 4; ++nn) {
                int kc = kt * 64 + nn * 16 + l15;
                for (int j = 0; j < 4; ++j) {
                    int qr = q0 + wave * 16 + l4 * 4 + j;
                    float sv = s[nn][j] * SCALE2;
                    bool ok = (qr >= kc) && (qr - kc < 1024);
                    p[nn][j] = ok ? sv : -1e30f;
                }
            }
        } else {
            for (int nn = 0; nn < 4; ++nn)
                for (int j = 0; j < 4; ++j) p[nn][j] = s[nn][j] * SCALE2;
        }

        // online softmax with deferred max (THR=11 in log2 domain)
        float mx4[4];
        bool flag = true;
        for (int j = 0; j < 4; ++j) {
            float mx = fmaxf(fmaxf(p[0][j], p[1][j]), fmaxf(p[2][j], p[3][j]));
            for (int mk = 8; mk; mk >>= 1) mx = fmaxf(mx, __shfl_xor(mx, mk));
            mx4[j] = mx;
            flag = flag && (mx <= m2[j] + 11.0f);
        }
        if (!__all(flag)) {
            for (int j = 0; j < 4; ++j) {
                float mnew = fmaxf(m2[j], mx4[j]);
                float corr = exp2f(m2[j] - mnew);
                m2[j] = mnew;
                lp[j] *= corr;
                for (int dd = 0; dd < 8; ++dd) o[dd][j] *= corr;
            }
        }
        for (int j = 0; j < 4; ++j) {
            float rs = 0.0f;
            for (int nn = 0; nn < 4; ++nn) {
                float pv = exp2f(p[nn][j] - m2[j]);
                p[nn][j] = pv;
                rs += pv;
            }
            lp[j] += rs;  // per-lane partial; reduced in epilogue
        }

        // P -> LDS (bf16)
        for (int j = 0; j < 4; ++j)
            for (int nn = 0; nn < 4; ++nn)
                Ps[wave][(l4 * 4 + j) * 72 + nn * 16 + l15] = f2bf(p[nn][j]);

        bf16x8 pa[2];
        for (int kk2 = 0; kk2 < 2; ++kk2)
            pa[kk2] = *(const bf16x8*)&Ps[wave][l15 * 72 + kk2 * 32 + l4 * 8];

        // O += P V
        __builtin_amdgcn_s_setprio(1);
        for (int dd = 0; dd < 8; ++dd)
            for (int kk2 = 0; kk2 < 2; ++kk2) {
                int d = dd * 16 + l15;
                int cb = (kk2 * 64 + l4 * 16) ^ ((d & 7) << 4);
                bf16x8 vf = *(const bf16x8*)((const char*)&Vs[cur][0] + d * 128 + cb);
                o[dd] = MFMA16(pa[kk2], vf, o[dd]);
            }
        __builtin_amdgcn_s_setprio(0);
        cur ^= 1;
    }

    // epilogue: reduce l partials, normalize, store
    for (int j = 0; j < 4; ++j) {
        float lt = lp[j];
        for (int mk = 8; mk; mk >>= 1) lt += __shfl_xor(lt, mk);
        float inv = 1.0f / lt;
        int row = q0 + wave * 16 + l4 * 4 + j;
        unsigned short* orow = Ob + (size_t)row * 2048 + h * 128;
        for (int dd = 0; dd < 8; ++dd) orow[dd * 16 + l15] = f2bf(o[dd][j] * inv);
    }
}

// ---------------------------------------------------------------- launch
extern "C" void kernel_launch(void* const* d_in, const int* in_sizes, int n_in,
                              void* d_out, int out_size, void* d_ws, size_t ws_size,
                              hipStream_t stream) {
    const float* x  = (const float*)d_in[0];
    const float* wq = (const float*)d_in[1];
    const float* wk = (const float*)d_in[2];
    const float* wv = (const float*)d_in[3];
    const float* wo = (const float*)d_in[4];
    const float* qw = (const float*)d_in[5];
    const float* kw = (const float*)d_in[6];
    float* out = (float*)d_out;

    char* ws = (char*)d_ws;
    unsigned short* xb   = (unsigned short*)(ws + 0);          //  8 MB  x bf16 [2048][2048]
    unsigned short* wqkv = (unsigned short*)(ws + 8388608);    // 12 MB  [3072][2048]
    unsigned short* wob  = (unsigned short*)(ws + 20971520);   //  8 MB  [2048][2048]
    unsigned short* Qb   = (unsigned short*)(ws + 29360128);   //  8 MB  [16][2048][128]
    unsigned short* Kb   = (unsigned short*)(ws + 37748736);   //  2 MB  [4][2048][128]
    unsigned short* Vb   = (unsigned short*)(ws + 39845888);   //  2 MB  [4][2048][128]
    unsigned short* VbT  = (unsigned short*)(ws + 41943040);   //  2 MB  [4][128][2048]
    unsigned short* Ob   = (unsigned short*)(ws + 44040192);   //  8 MB  [2048][2048]
    float2*         tbl  = (float2*)(ws + 52428800);           //  1 MB  [2048][64]

    convert_bf16<<<dim3(4096), dim3(256), 0, stream>>>(x, xb, 2048 * 2048);
    convert_bf16<<<dim3(4096), dim3(256), 0, stream>>>(wq, wqkv, 2048 * 2048);
    convert_bf16<<<dim3(1024), dim3(256), 0, stream>>>(wk, wqkv + 2048 * 2048, 512 * 2048);
    convert_bf16<<<dim3(1024), dim3(256), 0, stream>>>(wv, wqkv + 2560 * 2048, 512 * 2048);
    convert_bf16<<<dim3(4096), dim3(256), 0, stream>>>(wo, wob, 2048 * 2048);
    rope_table<<<dim3(2048), dim3(64), 0, stream>>>(tbl);

    gemm_qkv<<<dim3(24, 16), dim3(256), 0, stream>>>(xb, wqkv, qw, kw, tbl, Qb, Kb, Vb);
    transpose_v<<<dim3(32, 4), dim3(256), 0, stream>>>(Vb, VbT);
    attn_fwd<<<dim3(32, 16), dim3(256), 0, stream>>>(Qb, Kb, VbT, Ob);
    gemm_bt<<<dim3(16, 16), dim3(256), 0, stream>>>(Ob, wob, out, 2048, 2048, 2048);
}

// Round 5
// 160.227 us; speedup vs baseline: 1.6943x; 1.0553x over previous
//
#include <hip/hip_runtime.h>
#include <hip/hip_bf16.h>
#include <cstdint>
#include <cstddef>

typedef __attribute__((ext_vector_type(4))) float f32x4;
typedef __attribute__((ext_vector_type(8))) short bf16x8;
typedef __attribute__((ext_vector_type(8))) unsigned short us8;

#define MFMA16(a, b, c) __builtin_amdgcn_mfma_f32_16x16x32_bf16(a, b, c, 0, 0, 0)

__device__ inline unsigned short f2bf(float f) {
    unsigned int u = __float_as_uint(f);
    u += 0x7fffu + ((u >> 16) & 1u);
    return (unsigned short)(u >> 16);
}
__device__ inline float bf2f(unsigned short u) {
    return __uint_as_float((unsigned int)u << 16);
}

__device__ inline void gload_lds16(const void* g, void* l) {
    __builtin_amdgcn_global_load_lds(
        (const __attribute__((address_space(1))) void*)g,
        (__attribute__((address_space(3))) void*)l, 16, 0, 0);
}

// counted-vmcnt barrier: tile-t loads certified done per-wave, tile-t+1's 4 stay in flight
__device__ inline void bar_vm4() {
    asm volatile("s_waitcnt vmcnt(4)" ::: "memory");
    __builtin_amdgcn_s_barrier();
    asm volatile("" ::: "memory");
}
__device__ inline void bar_vm0() {
    asm volatile("s_waitcnt vmcnt(0)" ::: "memory");
    __builtin_amdgcn_s_barrier();
    asm volatile("" ::: "memory");
}

// ---------------------------------------------------------------- fused prep: 5 f32->bf16 converts + RoPE table
__global__ __launch_bounds__(256) void prep_all(const float* __restrict__ x,
                                                const float* __restrict__ wq,
                                                const float* __restrict__ wk,
                                                const float* __restrict__ wv,
                                                const float* __restrict__ wo,
                                                unsigned short* __restrict__ xb,
                                                unsigned short* __restrict__ wqkv,
                                                unsigned short* __restrict__ wob,
                                                float2* __restrict__ tbl) {
    const int b = blockIdx.x;
    if (b < 14336) {  // converts; every block entirely within one region
        const float* src; unsigned short* dst; int off4;
        if (b < 4096)       { src = x;  dst = xb;                off4 = b; }
        else if (b < 8192)  { src = wq; dst = wqkv;              off4 = b - 4096; }
        else if (b < 9216)  { src = wk; dst = wqkv + 2048 * 2048; off4 = b - 8192; }
        else if (b < 10240) { src = wv; dst = wqkv + 2560 * 2048; off4 = b - 9216; }
        else                { src = wo; dst = wob;               off4 = b - 10240; }
        int i = (off4 * 256 + threadIdx.x) * 4;
        float4 v = *(const float4*)(src + i);
        ushort4 o;
        o.x = f2bf(v.x); o.y = f2bf(v.y); o.z = f2bf(v.z); o.w = f2bf(v.w);
        *(ushort4*)(dst + i) = o;
    } else {          // rope table: 512 blocks -> 2048 rows x 64
        int idx = (b - 14336) * 256 + threadIdx.x;
        int row = idx >> 6, t = idx & 63;
        float inv_freq = exp2f((float)t * (-2.0f / 128.0f) * 13.287712379549449f);
        float s, c;
        sincosf((float)row * inv_freq, &s, &c);
        tbl[idx] = make_float2(c, s);
    }
}

// ---------------------------------------------------------------- GEMM  C[M,N] = A[M,K]*B[N,K]^T  (f32 out)
// 3-buffer depth-2 prefetch, counted-vmcnt barriers, XCD-bijective swizzle
__global__ __launch_bounds__(256) void gemm_bt(const unsigned short* __restrict__ A,
                                               const unsigned short* __restrict__ B,
                                               float* __restrict__ C,
                                               int M, int N, int K) {
    __shared__ unsigned short As[3][4096];
    __shared__ unsigned short Bs[3][4096];
    const int tid = threadIdx.x;
    const int lane = tid & 63, wave = tid >> 6;
    const int wr = wave >> 1, wc = wave & 1;
    const int gx = gridDim.x;
    const int nwg = gx * gridDim.y;
    const int bid0 = blockIdx.y * gx + blockIdx.x;
    const int q8 = nwg >> 3, r8 = nwg & 7;
    const int xcd = bid0 & 7, sub = bid0 >> 3;
    const int wgid = ((xcd < r8) ? xcd * (q8 + 1) : r8 * (q8 + 1) + (xcd - r8) * q8) + sub;
    const int bm = wgid / gx, bn = wgid % gx;
    const int l15 = lane & 15, l4 = lane >> 4;
    f32x4 acc[4][4] = {};
    const int nK = K >> 5;

    // per-thread staging addresses (hoisted)
    const int rsub = tid >> 2;           // 0..63
    const int csub = (tid & 3) * 8;      // 0/8/16/24
    const unsigned short* pa0 = A + (size_t)(bm * 128 + rsub) * K + csub;
    const unsigned short* pa1 = pa0 + (size_t)64 * K;
    const unsigned short* pb0 = B + (size_t)(bn * 128 + rsub) * K + csub;
    const unsigned short* pb1 = pb0 + (size_t)64 * K;
    const int e0 = tid * 8, e1 = 2048 + tid * 8;

#define STAGE_G(koff, bb)                        \
    do {                                         \
        gload_lds16(pa0 + (koff), &As[bb][e0]);  \
        gload_lds16(pa1 + (koff), &As[bb][e1]);  \
        gload_lds16(pb0 + (koff), &Bs[bb][e0]);  \
        gload_lds16(pb1 + (koff), &Bs[bb][e1]);  \
    } while (0)

    STAGE_G(0, 0);
    STAGE_G(32, 1);
    int bc = 0, bs = 2;
    for (int kt = 0; kt < nK; ++kt) {
        if (kt + 1 < nK) bar_vm4(); else bar_vm0();
        if (kt + 2 < nK) STAGE_G((kt + 2) * 32, bs);
        const unsigned short* as_ = As[bc];
        const unsigned short* bs_ = Bs[bc];
        bf16x8 af[4], bfr[4];
        for (int m = 0; m < 4; ++m)
            af[m] = *(const bf16x8*)&as_[(wr * 64 + m * 16 + l15) * 32 + l4 * 8];
        for (int n = 0; n < 4; ++n)
            bfr[n] = *(const bf16x8*)&bs_[(wc * 64 + n * 16 + l15) * 32 + l4 * 8];
        for (int m = 0; m < 4; ++m)
            for (int n = 0; n < 4; ++n)
                acc[m][n] = MFMA16(af[m], bfr[n], acc[m][n]);
        if (++bc == 3) bc = 0;
        if (++bs == 3) bs = 0;
    }
#undef STAGE_G
    for (int m = 0; m < 4; ++m)
        for (int n = 0; n < 4; ++n)
            for (int j = 0; j < 4; ++j) {
                int row = bm * 128 + wr * 64 + m * 16 + l4 * 4 + j;
                int col = bn * 128 + wc * 64 + n * 16 + l15;
                C[(size_t)row * N + col] = acc[m][n][j];
            }
}

// ---------------------------------------------------------------- QKV GEMM with fused RMSNorm+RoPE epilogue
__global__ __launch_bounds__(256) void gemm_qkv(const unsigned short* __restrict__ A,
                                                const unsigned short* __restrict__ B,
                                                const float* __restrict__ qw,
                                                const float* __restrict__ kw,
                                                const float2* __restrict__ tbl,
                                                unsigned short* __restrict__ Qb,
                                                unsigned short* __restrict__ Kb,
                                                unsigned short* __restrict__ Vb) {
    constexpr int K = 2048;
    constexpr int nK = K >> 5;  // 64
    __shared__ __align__(16) char sm[49152];       // union: 3x(As+Bs) dbuf | {ybuf+ssbuf}
    unsigned short* AsB = (unsigned short*)sm;     // As[b] = AsB + b*4096
    unsigned short* BsB = AsB + 12288;             // Bs[b] = BsB + b*4096
    const int tid = threadIdx.x;
    const int lane = tid & 63, wave = tid >> 6;
    const int wr = wave >> 1, wc = wave & 1;
    const int gx = gridDim.x;                      // 24
    const int nwg = gx * gridDim.y;
    const int bid0 = blockIdx.y * gx + blockIdx.x;
    const int q8 = nwg >> 3, r8 = nwg & 7;
    const int xcd = bid0 & 7, sub = bid0 >> 3;
    const int wgid = ((xcd < r8) ? xcd * (q8 + 1) : r8 * (q8 + 1) + (xcd - r8) * q8) + sub;
    const int bm = wgid / gx, bn = wgid % gx;
    const int l15 = lane & 15, l4 = lane >> 4;
    f32x4 acc[4][4] = {};

    const int rsub = tid >> 2;
    const int csub = (tid & 3) * 8;
    const unsigned short* pa0 = A + (size_t)(bm * 128 + rsub) * K + csub;
    const unsigned short* pa1 = pa0 + (size_t)64 * K;
    const unsigned short* pb0 = B + (size_t)(bn * 128 + rsub) * K + csub;
    const unsigned short* pb1 = pb0 + (size_t)64 * K;
    const int e0 = tid * 8, e1 = 2048 + tid * 8;

#define STAGE_Q(koff, bb)                                   \
    do {                                                    \
        gload_lds16(pa0 + (koff), AsB + (bb) * 4096 + e0);  \
        gload_lds16(pa1 + (koff), AsB + (bb) * 4096 + e1);  \
        gload_lds16(pb0 + (koff), BsB + (bb) * 4096 + e0);  \
        gload_lds16(pb1 + (koff), BsB + (bb) * 4096 + e1);  \
    } while (0)

    STAGE_Q(0, 0);
    STAGE_Q(32, 1);
    int bc = 0, bs = 2;
    for (int kt = 0; kt < nK; ++kt) {
        if (kt + 1 < nK) bar_vm4(); else bar_vm0();
        if (kt + 2 < nK) STAGE_Q((kt + 2) * 32, bs);
        const unsigned short* as_ = AsB + bc * 4096;
        const unsigned short* bs_ = BsB + bc * 4096;
        bf16x8 af[4], bfr[4];
        for (int m = 0; m < 4; ++m)
            af[m] = *(const bf16x8*)&as_[(wr * 64 + m * 16 + l15) * 32 + l4 * 8];
        for (int n = 0; n < 4; ++n)
            bfr[n] = *(const bf16x8*)&bs_[(wc * 64 + n * 16 + l15) * 32 + l4 * 8];
        for (int m = 0; m < 4; ++m)
            for (int n = 0; n < 4; ++n)
                acc[m][n] = MFMA16(af[m], bfr[n], acc[m][n]);
        if (++bc == 3) bc = 0;
        if (++bs == 3) bs = 0;
    }
#undef STAGE_Q

    // ---------------- fused epilogue ----------------
    const int head = bn;
    __syncthreads();
    if (head >= 20) {  // V: plain bf16 write
        unsigned short* dst = Vb + (size_t)(head - 20) * 2048 * 128;
        for (int m = 0; m < 4; ++m)
            for (int j = 0; j < 4; ++j) {
                int row = bm * 128 + wr * 64 + m * 16 + l4 * 4 + j;
                for (int n = 0; n < 4; ++n)
                    dst[(size_t)row * 128 + wc * 64 + n * 16 + l15] = f2bf(acc[m][n][j]);
            }
        return;
    }
    unsigned short* ybuf = (unsigned short*)sm;        // [128][136] bf16
    float* ssbuf = (float*)(sm + 34816);               // [2][128]
    for (int m = 0; m < 4; ++m)
        for (int j = 0; j < 4; ++j) {
            float ss = 0.0f;
            for (int n = 0; n < 4; ++n) ss += acc[m][n][j] * acc[m][n][j];
            for (int mk = 8; mk; mk >>= 1) ss += __shfl_xor(ss, mk);
            if (l15 == 0) ssbuf[wc * 128 + wr * 64 + m * 16 + l4 * 4 + j] = ss;
        }
    __syncthreads();
    const float* w = (head < 16) ? qw : kw;
    float wv4[4];
    for (int n = 0; n < 4; ++n) wv4[n] = w[wc * 64 + n * 16 + l15];
    float rr[4][4];
    for (int m = 0; m < 4; ++m)
        for (int j = 0; j < 4; ++j) {
            int lrow = wr * 64 + m * 16 + l4 * 4 + j;
            float tot = ssbuf[lrow] + ssbuf[128 + lrow];
            rr[m][j] = rsqrtf(tot * (1.0f / 128.0f) + 1e-6f);
        }
    for (int m = 0; m < 4; ++m)
        for (int j = 0; j < 4; ++j) {
            int lrow = wr * 64 + m * 16 + l4 * 4 + j;
            for (int n = 0; n < 4; ++n)
                ybuf[lrow * 136 + wc * 64 + n * 16 + l15] = f2bf(acc[m][n][j] * rr[m][j] * wv4[n]);
        }
    __syncthreads();
    unsigned short* dstbase = (head < 16) ? Qb + (size_t)head * 2048 * 128
                                          : Kb + (size_t)(head - 16) * 2048 * 128;
    for (int m = 0; m < 4; ++m)
        for (int j = 0; j < 4; ++j) {
            int lrow = wr * 64 + m * 16 + l4 * 4 + j;
            int grow = bm * 128 + lrow;
            for (int n = 0; n < 4; ++n) {
                int col = wc * 64 + n * 16 + l15;
                float2 cs = tbl[grow * 64 + (col & 63)];
                float own = bf2f(ybuf[lrow * 136 + col]);
                float par = bf2f(ybuf[lrow * 136 + (col ^ 64)]);
                float outv = (wc == 0) ? own * cs.x - par * cs.y
                                       : par * cs.y + own * cs.x;
                dstbase[(size_t)grow * 128 + col] = f2bf(outv);
            }
        }
}

// ---------------------------------------------------------------- V transpose: Vb [4][2048][128] -> VbT [4][128][2048]
__global__ __launch_bounds__(256) void transpose_v(const unsigned short* __restrict__ Vb,
                                                   unsigned short* __restrict__ VbT) {
    const int kt = blockIdx.x;  // 0..31
    const int h  = blockIdx.y;  // 0..3
    __shared__ unsigned short T[64 * 130];
    const int tid = threadIdx.x;
    for (int i = 0; i < 4; ++i) {
        int s = i * 256 + tid;
        int r = s >> 4, c = (s & 15) * 8;
        us8 v = *(const us8*)(Vb + ((size_t)h * 2048 + kt * 64 + r) * 128 + c);
        for (int j = 0; j < 8; ++j) T[r * 130 + c + j] = v[j];
    }
    __syncthreads();
    for (int i = 0; i < 4; ++i) {
        int s = i * 256 + tid;
        int d = s >> 3, ck = (s & 7) * 8;
        us8 v;
        for (int j = 0; j < 8; ++j) v[j] = T[(ck + j) * 130 + d];
        *(us8*)(VbT + (size_t)h * 128 * 2048 + (size_t)d * 2048 + kt * 64 + ck) = v;
    }
}

// ---------------------------------------------------------------- flash attention (windowed causal GQA)
__global__ __launch_bounds__(256) void attn_fwd(const unsigned short* __restrict__ Qb,
                                                const unsigned short* __restrict__ Kb,
                                                const unsigned short* __restrict__ VbT,
                                                unsigned short* __restrict__ Ob) {
    const int qt = blockIdx.x;  // 0..31
    const int h = blockIdx.y;   // 0..15
    const int kvh = h >> 2;
    const int q0 = qt * 64;
    __shared__ unsigned short Ks[2][64 * 128];   // swizzled: cbyte ^= (row&7)<<4
    __shared__ unsigned short Vs[2][128 * 64];   // V^T swizzled
    __shared__ unsigned short Ps[4][16 * 72];
    const int tid = threadIdx.x;
    const int lane = tid & 63, wave = tid >> 6;
    const int l15 = lane & 15, l4 = lane >> 4;

    bf16x8 qf[4];
    {
        const unsigned short* qrow =
            Qb + ((size_t)h * 2048 + q0 + wave * 16 + l15) * 128 + l4 * 8;
        for (int kk = 0; kk < 4; ++kk) qf[kk] = *(const bf16x8*)(qrow + kk * 32);
    }
    f32x4 o[8] = {};
    float m2[4], lp[4];
    for (int j = 0; j < 4; ++j) { m2[j] = -1e30f; lp[j] = 0.0f; }
    const float SCALE2 = 0.08838834764831843f * 1.4426950408889634f;  // scale*log2(e)
    const int kt_lo = (qt >= 16) ? (qt - 16) : 0;

    const unsigned short* Kh = Kb + (size_t)kvh * 2048 * 128;
    const unsigned short* Vh = VbT + (size_t)kvh * 128 * 2048;

    {   // prologue
        const int kt = kt_lo;
        for (int i = 0; i < 4; ++i) {
            int s = i * 256 + tid;
            int r = s >> 4;
            int cb = ((s & 15) * 16) ^ ((r & 7) << 4);
            gload_lds16(Kh + (size_t)(kt * 64 + r) * 128 + (cb >> 1), &Ks[0][s * 8]);
        }
        for (int i = 0; i < 4; ++i) {
            int s = i * 256 + tid;
            int d = s >> 3;
            int cb = ((s & 7) * 16) ^ ((d & 7) << 4);
            gload_lds16(Vh + (size_t)d * 2048 + kt * 64 + (cb >> 1), &Vs[0][s * 8]);
        }
    }

    int cur = 0;
    for (int kt = kt_lo; kt <= qt; ++kt) {
        __syncthreads();

        if (kt < qt) {  // prefetch next tile
            const int kn = kt + 1;
            for (int i = 0; i < 4; ++i) {
                int s = i * 256 + tid;
                int r = s >> 4;
                int cb = ((s & 15) * 16) ^ ((r & 7) << 4);
                gload_lds16(Kh + (size_t)(kn * 64 + r) * 128 + (cb >> 1), &Ks[cur ^ 1][s * 8]);
            }
            for (int i = 0; i < 4; ++i) {
                int s = i * 256 + tid;
                int d = s >> 3;
                int cb = ((s & 7) * 16) ^ ((d & 7) << 4);
                gload_lds16(Vh + (size_t)d * 2048 + kt * 64 + 64 + (cb >> 1) - 64 + 64, &Vs[cur ^ 1][s * 8]);
            }
        }

        // S = Q K^T
        f32x4 s[4] = {};
        __builtin_amdgcn_s_setprio(1);
        for (int nn = 0; nn < 4; ++nn)
            for (int kk = 0; kk < 4; ++kk) {
                int r = nn * 16 + l15;
                int cb = (kk * 64 + l4 * 16) ^ ((r & 7) << 4);
                bf16x8 kf = *(const bf16x8*)((const char*)&Ks[cur][0] + r * 256 + cb);
                s[nn] = MFMA16(qf[kk], kf, s[nn]);
            }
        __builtin_amdgcn_s_setprio(0);

        float p[4][4];
        const bool masked = (kt == qt) || (qt >= 16 && kt == kt_lo);
        if (masked) {
            for (int nn = 0; nn < 4; ++nn) {
                int kc = kt * 64 + nn * 16 + l15;
                for (int j = 0; j < 4; ++j) {
                    int qr = q0 + wave * 16 + l4 * 4 + j;
                    float sv = s[nn][j] * SCALE2;
                    bool ok = (qr >= kc) && (qr - kc < 1024);
                    p[nn][j] = ok ? sv : -1e30f;
                }
            }
        } else {
            for (int nn = 0; nn < 4; ++nn)
                for (int j = 0; j < 4; ++j) p[nn][j] = s[nn][j] * SCALE2;
        }

        float mx4[4];
        bool flag = true;
        for (int j = 0; j < 4; ++j) {
            float mx = fmaxf(fmaxf(p[0][j], p[1][j]), fmaxf(p[2][j], p[3][j]));
            for (int mk = 8; mk; mk >>= 1) mx = fmaxf(mx, __shfl_xor(mx, mk));
            mx4[j] = mx;
            flag = flag && (mx <= m2[j] + 11.0f);
        }
        if (!__all(flag)) {
            for (int j = 0; j < 4; ++j) {
                float mnew = fmaxf(m2[j], mx4[j]);
                float corr = exp2f(m2[j] - mnew);
                m2[j] = mnew;
                lp[j] *= corr;
                for (int dd = 0; dd < 8; ++dd) o[dd][j] *= corr;
            }
        }
        for (int j = 0; j < 4; ++j) {
            float rs = 0.0f;
            for (int nn = 0; nn < 4; ++nn) {
                float pv = exp2f(p[nn][j] - m2[j]);
                p[nn][j] = pv;
                rs += pv;
            }
            lp[j] += rs;
        }

        for (int j = 0; j < 4; ++j)
            for (int nn = 0; nn < 4; ++nn)
                Ps[wave][(l4 * 4 + j) * 72 + nn * 16 + l15] = f2bf(p[nn][j]);

        bf16x8 pa[2];
        for (int kk2 = 0; kk2 < 2; ++kk2)
            pa[kk2] = *(const bf16x8*)&Ps[wave][l15 * 72 + kk2 * 32 + l4 * 8];

        __builtin_amdgcn_s_setprio(1);
        for (int dd = 0; dd < 8; ++dd)
            for (int kk2 = 0; kk2 < 2; ++kk2) {
                int d = dd * 16 + l15;
                int cb = (kk2 * 64 + l4 * 16) ^ ((d & 7) << 4);
                bf16x8 vf = *(const bf16x8*)((const char*)&Vs[cur][0] + d * 128 + cb);
                o[dd] = MFMA16(pa[kk2], vf, o[dd]);
            }
        __builtin_amdgcn_s_setprio(0);
        cur ^= 1;
    }

    for (int j = 0; j < 4; ++j) {
        float lt = lp[j];
        for (int mk = 8; mk; mk >>= 1) lt += __shfl_xor(lt, mk);
        float inv = 1.0f / lt;
        int row = q0 + wave * 16 + l4 * 4 + j;
        unsigned short* orow = Ob + (size_t)row * 2048 + h * 128;
        for (int dd = 0; dd < 8; ++dd) orow[dd * 16 + l15] = f2bf(o[dd][j] * inv);
    }
}

// ---------------------------------------------------------------- launch
extern "C" void kernel_launch(void* const* d_in, const int* in_sizes, int n_in,
                              void* d_out, int out_size, void* d_ws, size_t ws_size,
                              hipStream_t stream) {
    const float* x  = (const float*)d_in[0];
    const float* wq = (const float*)d_in[1];
    const float* wk = (const float*)d_in[2];
    const float* wv = (const float*)d_in[3];
    const float* wo = (const float*)d_in[4];
    const float* qw = (const float*)d_in[5];
    const float* kw = (const float*)d_in[6];
    float* out = (float*)d_out;

    char* ws = (char*)d_ws;
    unsigned short* xb   = (unsigned short*)(ws + 0);          //  8 MB
    unsigned short* wqkv = (unsigned short*)(ws + 8388608);    // 12 MB
    unsigned short* wob  = (unsigned short*)(ws + 20971520);   //  8 MB
    unsigned short* Qb   = (unsigned short*)(ws + 29360128);   //  8 MB
    unsigned short* Kb   = (unsigned short*)(ws + 37748736);   //  2 MB
    unsigned short* Vb   = (unsigned short*)(ws + 39845888);   //  2 MB
    unsigned short* VbT  = (unsigned short*)(ws + 41943040);   //  2 MB
    unsigned short* Ob   = (unsigned short*)(ws + 44040192);   //  8 MB
    float2*         tbl  = (float2*)(ws + 52428800);           //  1 MB

    prep_all<<<dim3(14848), dim3(256), 0, stream>>>(x, wq, wk, wv, wo, xb, wqkv, wob, tbl);
    gemm_qkv<<<dim3(24, 16), dim3(256), 0, stream>>>(xb, wqkv, qw, kw, tbl, Qb, Kb, Vb);
    transpose_v<<<dim3(32, 4), dim3(256), 0, stream>>>(Vb, VbT);
    attn_fwd<<<dim3(32, 16), dim3(256), 0, stream>>>(Qb, Kb, VbT, Ob);
    gemm_bt<<<dim3(16, 16), dim3(256), 0, stream>>>(Ob, wob, out, 2048, 2048, 2048);
}

// Round 6
// 159.780 us; speedup vs baseline: 1.6990x; 1.0028x over previous
//
#include <hip/hip_runtime.h>
#include <hip/hip_bf16.h>
#include <cstdint>
#include <cstddef>

typedef __attribute__((ext_vector_type(4))) float f32x4;
typedef __attribute__((ext_vector_type(8))) short bf16x8;
typedef __attribute__((ext_vector_type(8))) unsigned short us8;

#define MFMA16(a, b, c) __builtin_amdgcn_mfma_f32_16x16x32_bf16(a, b, c, 0, 0, 0)

__device__ inline unsigned short f2bf(float f) {
    unsigned int u = __float_as_uint(f);
    u += 0x7fffu + ((u >> 16) & 1u);
    return (unsigned short)(u >> 16);
}
__device__ inline float bf2f(unsigned short u) {
    return __uint_as_float((unsigned int)u << 16);
}

__device__ inline void gload_lds16(const void* g, void* l) {
    __builtin_amdgcn_global_load_lds(
        (const __attribute__((address_space(1))) void*)g,
        (__attribute__((address_space(3))) void*)l, 16, 0, 0);
}

// counted-vmcnt barriers
__device__ inline void bar_vm3() {
    asm volatile("s_waitcnt vmcnt(3)" ::: "memory");
    __builtin_amdgcn_s_barrier();
    asm volatile("" ::: "memory");
}
__device__ inline void bar_vm0() {
    asm volatile("s_waitcnt vmcnt(0)" ::: "memory");
    __builtin_amdgcn_s_barrier();
    asm volatile("" ::: "memory");
}

// ---------------------------------------------------------------- fused prep: 5 f32->bf16 converts + RoPE table
__global__ __launch_bounds__(256) void prep_all(const float* __restrict__ x,
                                                const float* __restrict__ wq,
                                                const float* __restrict__ wk,
                                                const float* __restrict__ wv,
                                                const float* __restrict__ wo,
                                                unsigned short* __restrict__ xb,
                                                unsigned short* __restrict__ wqkv,
                                                unsigned short* __restrict__ wob,
                                                float2* __restrict__ tbl) {
    const int b = blockIdx.x;
    if (b < 14336) {
        const float* src; unsigned short* dst; int off4;
        if (b < 4096)       { src = x;  dst = xb;                 off4 = b; }
        else if (b < 8192)  { src = wq; dst = wqkv;               off4 = b - 4096; }
        else if (b < 9216)  { src = wk; dst = wqkv + 2048 * 2048; off4 = b - 8192; }
        else if (b < 10240) { src = wv; dst = wqkv + 2560 * 2048; off4 = b - 9216; }
        else                { src = wo; dst = wob;                off4 = b - 10240; }
        int i = (off4 * 256 + threadIdx.x) * 4;
        float4 v = *(const float4*)(src + i);
        ushort4 o;
        o.x = f2bf(v.x); o.y = f2bf(v.y); o.z = f2bf(v.z); o.w = f2bf(v.w);
        *(ushort4*)(dst + i) = o;
    } else {
        int idx = (b - 14336) * 256 + threadIdx.x;
        int row = idx >> 6, t = idx & 63;
        float inv_freq = exp2f((float)t * (-2.0f / 128.0f) * 13.287712379549449f);
        float s, c;
        sincosf((float)row * inv_freq, &s, &c);
        tbl[idx] = make_float2(c, s);
    }
}

// ---------------------------------------------------------------- 8-wave GEMM core helpers
// block tile 128x256, 8 waves (2M x 4N), per-wave 64x64 (16 MFMA : 8 ds_read)
// staging per tile: A 128x32 (1 load/thr), B 256x32 (2 loads/thr); 3 buffers, depth-2, vmcnt(3)

// ---------------------------------------------------------------- out-projection GEMM (split-K partials, f32 out)
__global__ __launch_bounds__(512) void gemm8_out(const unsigned short* __restrict__ A,
                                                 const unsigned short* __restrict__ B,
                                                 float* __restrict__ Cp,
                                                 int M, int N, int Kfull, int kspan) {
    __shared__ unsigned short As[3][4096];
    __shared__ unsigned short Bs[3][8192];
    const int tid = threadIdx.x;
    const int lane = tid & 63, wave = tid >> 6;
    const int wr = wave >> 2, wc = wave & 3;
    const int gx = gridDim.x;
    const int nwg = gx * gridDim.y;
    const int bid0 = blockIdx.y * gx + blockIdx.x;
    const int q8 = nwg >> 3, r8 = nwg & 7;
    const int xcd = bid0 & 7, sub = bid0 >> 3;
    const int wgid = ((xcd < r8) ? xcd * (q8 + 1) : r8 * (q8 + 1) + (xcd - r8) * q8) + sub;
    const int bm = wgid / gx, bn = wgid % gx;
    const int l15 = lane & 15, l4 = lane >> 4;
    const int z = blockIdx.z;
    const unsigned short* Az = A + (size_t)z * kspan;
    const unsigned short* Bz = B + (size_t)z * kspan;
    float* C = Cp + (size_t)z * M * N;
    const int nK = kspan >> 5;
    f32x4 acc[4][4] = {};

    const int ra = tid >> 2, ca = (tid & 3) * 8;
    const unsigned short* pa  = Az + (size_t)(bm * 128 + ra) * Kfull + ca;
    const unsigned short* pb0 = Bz + (size_t)(bn * 256 + ra) * Kfull + ca;
    const unsigned short* pb1 = pb0 + (size_t)128 * Kfull;
    const int ea = tid * 8;

#define STG_O(kt, bb)                                      \
    do {                                                   \
        gload_lds16(pa  + (kt) * 32, &As[bb][ea]);         \
        gload_lds16(pb0 + (kt) * 32, &Bs[bb][ea]);         \
        gload_lds16(pb1 + (kt) * 32, &Bs[bb][4096 + ea]);  \
    } while (0)

    STG_O(0, 0);
    STG_O(1, 1);
    int bc = 0, bsl = 2;
    for (int kt = 0; kt < nK; ++kt) {
        if (kt + 1 < nK) bar_vm3(); else bar_vm0();
        if (kt + 2 < nK) STG_O(kt + 2, bsl);
        const unsigned short* as_ = As[bc];
        const unsigned short* bs_ = Bs[bc];
        bf16x8 af[4], bfr[4];
        for (int m = 0; m < 4; ++m)
            af[m] = *(const bf16x8*)&as_[(wr * 64 + m * 16 + l15) * 32 + l4 * 8];
        for (int n = 0; n < 4; ++n)
            bfr[n] = *(const bf16x8*)&bs_[(wc * 64 + n * 16 + l15) * 32 + l4 * 8];
        for (int m = 0; m < 4; ++m)
            for (int n = 0; n < 4; ++n)
                acc[m][n] = MFMA16(af[m], bfr[n], acc[m][n]);
        if (++bc == 3) bc = 0;
        if (++bsl == 3) bsl = 0;
    }
#undef STG_O
    for (int m = 0; m < 4; ++m)
        for (int n = 0; n < 4; ++n)
            for (int j = 0; j < 4; ++j) {
                int row = bm * 128 + wr * 64 + m * 16 + l4 * 4 + j;
                int col = bn * 256 + wc * 64 + n * 16 + l15;
                C[(size_t)row * N + col] = acc[m][n][j];
            }
}

__global__ __launch_bounds__(256) void add_out(const float* __restrict__ p0,
                                               const float* __restrict__ p1,
                                               float* __restrict__ out, int n4) {
    int i = (blockIdx.x * 256 + threadIdx.x) * 4;
    if (i >= n4) return;
    f32x4 a = *(const f32x4*)(p0 + i);
    f32x4 b = *(const f32x4*)(p1 + i);
    a += b;
    *(f32x4*)(out + i) = a;
}

// ---------------------------------------------------------------- QKV GEMM (8-wave) with fused RMSNorm+RoPE epilogue
// A=xb[2048][2048], B=wqkv[3072][2048]; block bn owns heads {2bn, 2bn+1}
__global__ __launch_bounds__(512) void gemm8_qkv(const unsigned short* __restrict__ A,
                                                 const unsigned short* __restrict__ B,
                                                 const float* __restrict__ qw,
                                                 const float* __restrict__ kw,
                                                 const float2* __restrict__ tbl,
                                                 unsigned short* __restrict__ Qb,
                                                 unsigned short* __restrict__ Kb,
                                                 unsigned short* __restrict__ Vb) {
    constexpr int K = 2048;
    constexpr int nK = K >> 5;  // 64
    __shared__ __align__(16) char sm[73728];        // union: As(24K)+Bs(48K) | ybuf(66K)+ssbuf(2K)
    unsigned short* AsB = (unsigned short*)sm;      // As[b] = AsB + b*4096
    unsigned short* BsB = AsB + 12288;              // Bs[b] = BsB + b*8192
    const int tid = threadIdx.x;
    const int lane = tid & 63, wave = tid >> 6;
    const int wr = wave >> 2, wc = wave & 3;
    const int gx = gridDim.x;                       // 12
    const int nwg = gx * gridDim.y;
    const int bid0 = blockIdx.y * gx + blockIdx.x;
    const int q8 = nwg >> 3, r8 = nwg & 7;
    const int xcd = bid0 & 7, sub = bid0 >> 3;
    const int wgid = ((xcd < r8) ? xcd * (q8 + 1) : r8 * (q8 + 1) + (xcd - r8) * q8) + sub;
    const int bm = wgid / gx, bn = wgid % gx;
    const int l15 = lane & 15, l4 = lane >> 4;
    f32x4 acc[4][4] = {};

    const int ra = tid >> 2, ca = (tid & 3) * 8;
    const unsigned short* pa  = A + (size_t)(bm * 128 + ra) * K + ca;
    const unsigned short* pb0 = B + (size_t)(bn * 256 + ra) * K + ca;
    const unsigned short* pb1 = pb0 + (size_t)128 * K;
    const int ea = tid * 8;

#define STG_Q(kt, bb)                                             \
    do {                                                          \
        gload_lds16(pa  + (kt) * 32, AsB + (bb) * 4096 + ea);     \
        gload_lds16(pb0 + (kt) * 32, BsB + (bb) * 8192 + ea);     \
        gload_lds16(pb1 + (kt) * 32, BsB + (bb) * 8192 + 4096 + ea); \
    } while (0)

    STG_Q(0, 0);
    STG_Q(1, 1);
    int bc = 0, bsl = 2;
    for (int kt = 0; kt < nK; ++kt) {
        if (kt + 1 < nK) bar_vm3(); else bar_vm0();
        if (kt + 2 < nK) STG_Q(kt + 2, bsl);
        const unsigned short* as_ = AsB + bc * 4096;
        const unsigned short* bs_ = BsB + bc * 8192;
        bf16x8 af[4], bfr[4];
        for (int m = 0; m < 4; ++m)
            af[m] = *(const bf16x8*)&as_[(wr * 64 + m * 16 + l15) * 32 + l4 * 8];
        for (int n = 0; n < 4; ++n)
            bfr[n] = *(const bf16x8*)&bs_[(wc * 64 + n * 16 + l15) * 32 + l4 * 8];
        for (int m = 0; m < 4; ++m)
            for (int n = 0; n < 4; ++n)
                acc[m][n] = MFMA16(af[m], bfr[n], acc[m][n]);
        if (++bc == 3) bc = 0;
        if (++bsl == 3) bsl = 0;
    }
#undef STG_Q

    // ---------------- fused epilogue (2 heads per block) ----------------
    const int hl = wc >> 1;                 // head-local 0/1
    const int half = wc & 1;                // 0: cols 0..63, 1: cols 64..127 of the head
    __syncthreads();                        // all LDS reads done; union region reusable

    if (bn >= 10) {                         // both heads are V
        const int head_v = 2 * bn - 20 + hl;
        unsigned short* dst = Vb + (size_t)head_v * 2048 * 128;
        for (int m = 0; m < 4; ++m)
            for (int j = 0; j < 4; ++j) {
                int row = bm * 128 + wr * 64 + m * 16 + l4 * 4 + j;
                for (int n = 0; n < 4; ++n)
                    dst[(size_t)row * 128 + half * 64 + n * 16 + l15] = f2bf(acc[m][n][j]);
            }
        return;
    }

    unsigned short* ybuf = (unsigned short*)sm;     // [128][264] bf16 (cols 0..255 = 2 heads)
    float* ssbuf = (float*)(sm + 67584);            // [4][128]
    // per-(row, wc) partial sum of squares over this wave's 64 cols
    for (int m = 0; m < 4; ++m)
        for (int j = 0; j < 4; ++j) {
            float ss = 0.0f;
            for (int n = 0; n < 4; ++n) ss += acc[m][n][j] * acc[m][n][j];
            for (int mk = 8; mk; mk >>= 1) ss += __shfl_xor(ss, mk);
            if (l15 == 0) ssbuf[wc * 128 + wr * 64 + m * 16 + l4 * 4 + j] = ss;
        }
    __syncthreads();
    const float* w = (bn < 8) ? qw : kw;
    float wv4[4];
    for (int n = 0; n < 4; ++n) wv4[n] = w[half * 64 + n * 16 + l15];
    for (int m = 0; m < 4; ++m)
        for (int j = 0; j < 4; ++j) {
            int lrow = wr * 64 + m * 16 + l4 * 4 + j;
            float tot = ssbuf[hl * 256 + lrow] + ssbuf[hl * 256 + 128 + lrow];
            float rr = rsqrtf(tot * (1.0f / 128.0f) + 1e-6f);
            for (int n = 0; n < 4; ++n)
                ybuf[lrow * 264 + wc * 64 + n * 16 + l15] = f2bf(acc[m][n][j] * rr * wv4[n]);
        }
    __syncthreads();
    const int head_g = 2 * bn + hl;
    unsigned short* dstbase = (bn < 8) ? Qb + (size_t)head_g * 2048 * 128
                                       : Kb + (size_t)(head_g - 16) * 2048 * 128;
    for (int m = 0; m < 4; ++m)
        for (int j = 0; j < 4; ++j) {
            int lrow = wr * 64 + m * 16 + l4 * 4 + j;
            int grow = bm * 128 + lrow;
            for (int n = 0; n < 4; ++n) {
                int wcol = wc * 64 + n * 16 + l15;        // 0..255
                float2 cs = tbl[grow * 64 + (wcol & 63)];
                float own = bf2f(ybuf[lrow * 264 + wcol]);
                float par = bf2f(ybuf[lrow * 264 + (wcol ^ 64)]);
                float outv = (half == 0) ? own * cs.x - par * cs.y
                                         : par * cs.y + own * cs.x;
                dstbase[(size_t)grow * 128 + (wcol & 127)] = f2bf(outv);
            }
        }
}

// ---------------------------------------------------------------- V transpose: Vb [4][2048][128] -> VbT [4][128][2048]
__global__ __launch_bounds__(256) void transpose_v(const unsigned short* __restrict__ Vb,
                                                   unsigned short* __restrict__ VbT) {
    const int kt = blockIdx.x;
    const int h  = blockIdx.y;
    __shared__ unsigned short T[64 * 130];
    const int tid = threadIdx.x;
    for (int i = 0; i < 4; ++i) {
        int s = i * 256 + tid;
        int r = s >> 4, c = (s & 15) * 8;
        us8 v = *(const us8*)(Vb + ((size_t)h * 2048 + kt * 64 + r) * 128 + c);
        for (int j = 0; j < 8; ++j) T[r * 130 + c + j] = v[j];
    }
    __syncthreads();
    for (int i = 0; i < 4; ++i) {
        int s = i * 256 + tid;
        int d = s >> 3, ck = (s & 7) * 8;
        us8 v;
        for (int j = 0; j < 8; ++j) v[j] = T[(ck + j) * 130 + d];
        *(us8*)(VbT + (size_t)h * 128 * 2048 + (size_t)d * 2048 + kt * 64 + ck) = v;
    }
}

// ---------------------------------------------------------------- flash attention (windowed causal GQA)
__global__ __launch_bounds__(256) void attn_fwd(const unsigned short* __restrict__ Qb,
                                                const unsigned short* __restrict__ Kb,
                                                const unsigned short* __restrict__ VbT,
                                                unsigned short* __restrict__ Ob) {
    const int qt = blockIdx.x;
    const int h = blockIdx.y;
    const int kvh = h >> 2;
    const int q0 = qt * 64;
    __shared__ unsigned short Ks[2][64 * 128];
    __shared__ unsigned short Vs[2][128 * 64];
    __shared__ unsigned short Ps[4][16 * 72];
    const int tid = threadIdx.x;
    const int lane = tid & 63, wave = tid >> 6;
    const int l15 = lane & 15, l4 = lane >> 4;

    bf16x8 qf[4];
    {
        const unsigned short* qrow =
            Qb + ((size_t)h * 2048 + q0 + wave * 16 + l15) * 128 + l4 * 8;
        for (int kk = 0; kk < 4; ++kk) qf[kk] = *(const bf16x8*)(qrow + kk * 32);
    }
    f32x4 o[8] = {};
    float m2[4], lp[4];
    for (int j = 0; j < 4; ++j) { m2[j] = -1e30f; lp[j] = 0.0f; }
    const float SCALE2 = 0.08838834764831843f * 1.4426950408889634f;
    const int kt_lo = (qt >= 16) ? (qt - 16) : 0;

    const unsigned short* Kh = Kb + (size_t)kvh * 2048 * 128;
    const unsigned short* Vh = VbT + (size_t)kvh * 128 * 2048;

    {   // prologue
        const int kt = kt_lo;
        for (int i = 0; i < 4; ++i) {
            int s = i * 256 + tid;
            int r = s >> 4;
            int cb = ((s & 15) * 16) ^ ((r & 7) << 4);
            gload_lds16(Kh + (size_t)(kt * 64 + r) * 128 + (cb >> 1), &Ks[0][s * 8]);
        }
        for (int i = 0; i < 4; ++i) {
            int s = i * 256 + tid;
            int d = s >> 3;
            int cb = ((s & 7) * 16) ^ ((d & 7) << 4);
            gload_lds16(Vh + (size_t)d * 2048 + kt * 64 + (cb >> 1), &Vs[0][s * 8]);
        }
    }

    int cur = 0;
    for (int kt = kt_lo; kt <= qt; ++kt) {
        __syncthreads();

        if (kt < qt) {
            const int kn = kt + 1;
            for (int i = 0; i < 4; ++i) {
                int s = i * 256 + tid;
                int r = s >> 4;
                int cb = ((s & 15) * 16) ^ ((r & 7) << 4);
                gload_lds16(Kh + (size_t)(kn * 64 + r) * 128 + (cb >> 1), &Ks[cur ^ 1][s * 8]);
            }
            for (int i = 0; i < 4; ++i) {
                int s = i * 256 + tid;
                int d = s >> 3;
                int cb = ((s & 7) * 16) ^ ((d & 7) << 4);
                gload_lds16(Vh + (size_t)d * 2048 + kn * 64 + (cb >> 1), &Vs[cur ^ 1][s * 8]);
            }
        }

        f32x4 s[4] = {};
        __builtin_amdgcn_s_setprio(1);
        for (int nn = 0; nn < 4; ++nn)
            for (int kk = 0; kk < 4; ++kk) {
                int r = nn * 16 + l15;
                int cb = (kk * 64 + l4 * 16) ^ ((r & 7) << 4);
                bf16x8 kf = *(const bf16x8*)((const char*)&Ks[cur][0] + r * 256 + cb);
                s[nn] = MFMA16(qf[kk], kf, s[nn]);
            }
        __builtin_amdgcn_s_setprio(0);

        float p[4][4];
        const bool masked = (kt == qt) || (qt >= 16 && kt == kt_lo);
        if (masked) {
            for (int nn = 0; nn < 4; ++nn) {
                int kc = kt * 64 + nn * 16 + l15;
                for (int j = 0; j < 4; ++j) {
                    int qr = q0 + wave * 16 + l4 * 4 + j;
                    float sv = s[nn][j] * SCALE2;
                    bool ok = (qr >= kc) && (qr - kc < 1024);
                    p[nn][j] = ok ? sv : -1e30f;
                }
            }
        } else {
            for (int nn = 0; nn < 4; ++nn)
                for (int j = 0; j < 4; ++j) p[nn][j] = s[nn][j] * SCALE2;
        }

        float mx4[4];
        bool flag = true;
        for (int j = 0; j < 4; ++j) {
            float mx = fmaxf(fmaxf(p[0][j], p[1][j]), fmaxf(p[2][j], p[3][j]));
            for (int mk = 8; mk; mk >>= 1) mx = fmaxf(mx, __shfl_xor(mx, mk));
            mx4[j] = mx;
            flag = flag && (mx <= m2[j] + 11.0f);
        }
        if (!__all(flag)) {
            for (int j = 0; j < 4; ++j) {
                float mnew = fmaxf(m2[j], mx4[j]);
                float corr = exp2f(m2[j] - mnew);
                m2[j] = mnew;
                lp[j] *= corr;
                for (int dd = 0; dd < 8; ++dd) o[dd][j] *= corr;
            }
        }
        for (int j = 0; j < 4; ++j) {
            float rs = 0.0f;
            for (int nn = 0; nn < 4; ++nn) {
                float pv = exp2f(p[nn][j] - m2[j]);
                p[nn][j] = pv;
                rs += pv;
            }
            lp[j] += rs;
        }

        for (int j = 0; j < 4; ++j)
            for (int nn = 0; nn < 4; ++nn)
                Ps[wave][(l4 * 4 + j) * 72 + nn * 16 + l15] = f2bf(p[nn][j]);

        bf16x8 pa[2];
        for (int kk2 = 0; kk2 < 2; ++kk2)
            pa[kk2] = *(const bf16x8*)&Ps[wave][l15 * 72 + kk2 * 32 + l4 * 8];

        __builtin_amdgcn_s_setprio(1);
        for (int dd = 0; dd < 8; ++dd)
            for (int kk2 = 0; kk2 < 2; ++kk2) {
                int d = dd * 16 + l15;
                int cb = (kk2 * 64 + l4 * 16) ^ ((d & 7) << 4);
                bf16x8 vf = *(const bf16x8*)((const char*)&Vs[cur][0] + d * 128 + cb);
                o[dd] = MFMA16(pa[kk2], vf, o[dd]);
            }
        __builtin_amdgcn_s_setprio(0);
        cur ^= 1;
    }

    for (int j = 0; j < 4; ++j) {
        float lt = lp[j];
        for (int mk = 8; mk; mk >>= 1) lt += __shfl_xor(lt, mk);
        float inv = 1.0f / lt;
        int row = q0 + wave * 16 + l4 * 4 + j;
        unsigned short* orow = Ob + (size_t)row * 2048 + h * 128;
        for (int dd = 0; dd < 8; ++dd) orow[dd * 16 + l15] = f2bf(o[dd][j] * inv);
    }
}

// ---------------------------------------------------------------- launch
extern "C" void kernel_launch(void* const* d_in, const int* in_sizes, int n_in,
                              void* d_out, int out_size, void* d_ws, size_t ws_size,
                              hipStream_t stream) {
    const float* x  = (const float*)d_in[0];
    const float* wq = (const float*)d_in[1];
    const float* wk = (const float*)d_in[2];
    const float* wv = (const float*)d_in[3];
    const float* wo = (const float*)d_in[4];
    const float* qw = (const float*)d_in[5];
    const float* kw = (const float*)d_in[6];
    float* out = (float*)d_out;

    char* ws = (char*)d_ws;
    unsigned short* xb   = (unsigned short*)(ws + 0);          //  8 MB
    unsigned short* wqkv = (unsigned short*)(ws + 8388608);    // 12 MB
    unsigned short* wob  = (unsigned short*)(ws + 20971520);   //  8 MB
    unsigned short* Qb   = (unsigned short*)(ws + 29360128);   //  8 MB
    unsigned short* Kb   = (unsigned short*)(ws + 37748736);   //  2 MB
    unsigned short* Vb   = (unsigned short*)(ws + 39845888);   //  2 MB
    unsigned short* VbT  = (unsigned short*)(ws + 41943040);   //  2 MB
    unsigned short* Ob   = (unsigned short*)(ws + 44040192);   //  8 MB
    float2*         tbl  = (float2*)(ws + 52428800);           //  1 MB
    float*          outP = (float*)(ws + 53477376);            // 32 MB (2x f32 partials)

    prep_all<<<dim3(14848), dim3(256), 0, stream>>>(x, wq, wk, wv, wo, xb, wqkv, wob, tbl);
    gemm8_qkv<<<dim3(12, 16), dim3(512), 0, stream>>>(xb, wqkv, qw, kw, tbl, Qb, Kb, Vb);
    transpose_v<<<dim3(32, 4), dim3(256), 0, stream>>>(Vb, VbT);
    attn_fwd<<<dim3(32, 16), dim3(256), 0, stream>>>(Qb, Kb, VbT, Ob);
    gemm8_out<<<dim3(8, 16, 2), dim3(512), 0, stream>>>(Ob, wob, outP, 2048, 2048, 2048, 1024);
    add_out<<<dim3(4096), dim3(256), 0, stream>>>(outP, outP + 2048 * 2048, out, 2048 * 2048);
}

// Round 7
// 147.740 us; speedup vs baseline: 1.8375x; 1.0815x over previous
//
#include <hip/hip_runtime.h>
#include <hip/hip_bf16.h>
#include <cstdint>
#include <cstddef>

typedef __attribute__((ext_vector_type(4))) float f32x4;
typedef __attribute__((ext_vector_type(8))) short bf16x8;
typedef __attribute__((ext_vector_type(8))) unsigned short us8;

#define MFMA16(a, b, c) __builtin_amdgcn_mfma_f32_16x16x32_bf16(a, b, c, 0, 0, 0)

__device__ inline unsigned short f2bf(float f) {
    unsigned int u = __float_as_uint(f);
    u += 0x7fffu + ((u >> 16) & 1u);
    return (unsigned short)(u >> 16);
}
__device__ inline float bf2f(unsigned short u) {
    return __uint_as_float((unsigned int)u << 16);
}

__device__ inline void gload_lds16(const void* g, void* l) {
    __builtin_amdgcn_global_load_lds(
        (const __attribute__((address_space(1))) void*)g,
        (__attribute__((address_space(3))) void*)l, 16, 0, 0);
}
__device__ inline unsigned lds_addr(const void* p) {
    return (unsigned)(size_t)((__attribute__((address_space(3))) const void*)p);
}

// ---------------------------------------------------------------- fused prep: 5 f32->bf16 converts + RoPE table
__global__ __launch_bounds__(256) void prep_all(const float* __restrict__ x,
                                                const float* __restrict__ wq,
                                                const float* __restrict__ wk,
                                                const float* __restrict__ wv,
                                                const float* __restrict__ wo,
                                                unsigned short* __restrict__ xb,
                                                unsigned short* __restrict__ wqkv,
                                                unsigned short* __restrict__ wob,
                                                float2* __restrict__ tbl) {
    const int b = blockIdx.x;
    if (b < 14336) {
        const float* src; unsigned short* dst; int off4;
        if (b < 4096)       { src = x;  dst = xb;                 off4 = b; }
        else if (b < 8192)  { src = wq; dst = wqkv;               off4 = b - 4096; }
        else if (b < 9216)  { src = wk; dst = wqkv + 2048 * 2048; off4 = b - 8192; }
        else if (b < 10240) { src = wv; dst = wqkv + 2560 * 2048; off4 = b - 9216; }
        else                { src = wo; dst = wob;                off4 = b - 10240; }
        int i = (off4 * 256 + threadIdx.x) * 4;
        float4 v = *(const float4*)(src + i);
        ushort4 o;
        o.x = f2bf(v.x); o.y = f2bf(v.y); o.z = f2bf(v.z); o.w = f2bf(v.w);
        *(ushort4*)(dst + i) = o;
    } else {
        int idx = (b - 14336) * 256 + threadIdx.x;
        int row = idx >> 6, t = idx & 63;
        float inv_freq = exp2f((float)t * (-2.0f / 128.0f) * 13.287712379549449f);
        float s, c;
        sincosf((float)row * inv_freq, &s, &c);
        tbl[idx] = make_float2(c, s);
    }
}

// ---------------------------------------------------------------- gemm256: C[M,N] = A[M,K]*B[N,K]^T (f32 partials, split-K via z)
// 256x256 tile, BK=32, 8 waves (2Mx4N), per-wave 128x64; 3-buffer depth-2;
// single "s_waitcnt vmcnt(4); s_barrier" per iter; asm ds_read_b128; quarter-swizzled LDS.
__global__ __launch_bounds__(512, 2) void gemm256(const unsigned short* __restrict__ A,
                                                  const unsigned short* __restrict__ B,
                                                  float* __restrict__ Cp,
                                                  int M, int N, int Kfull, int kspan) {
    __shared__ unsigned short As[3][8192];
    __shared__ unsigned short Bs[3][8192];
    const int tid = threadIdx.x;
    const int lane = tid & 63, wave = tid >> 6;
    const int wr = wave >> 2, wc = wave & 3;
    const int l15 = lane & 15, l4 = lane >> 4;
    const int gx = gridDim.x;
    const int nwg = gx * gridDim.y;
    const int bid0 = blockIdx.y * gx + blockIdx.x;
    const int q8 = nwg >> 3, r8 = nwg & 7;
    const int xcd = bid0 & 7, sub = bid0 >> 3;
    const int wgid = ((xcd < r8) ? xcd * (q8 + 1) : r8 * (q8 + 1) + (xcd - r8) * q8) + sub;
    const int bm = wgid / gx, bn = wgid % gx;
    const int z = blockIdx.z;
    const unsigned short* Az = A + (size_t)z * kspan;
    const unsigned short* Bz = B + (size_t)z * kspan;
    float* C = Cp + (size_t)z * M * N;
    const int nK = kspan >> 5;

    f32x4 acc[8][4] = {};

    // staging: thread -> row r0 (0..127) & r0+128, quarter qs; source pre-swizzled
    const int r0 = tid >> 2, qs = tid & 3;
    const int qsw = qs ^ ((r0 >> 1) & 3);
    const unsigned short* pa0 = Az + (size_t)(bm * 256 + r0) * Kfull + qsw * 8;
    const unsigned short* pa1 = pa0 + (size_t)128 * Kfull;
    const unsigned short* pb0 = Bz + (size_t)(bn * 256 + r0) * Kfull + qsw * 8;
    const unsigned short* pb1 = pb0 + (size_t)128 * Kfull;

#define STG(kt, bb)                                            \
    do {                                                       \
        gload_lds16(pa0 + (kt) * 32, &As[bb][tid * 8]);        \
        gload_lds16(pa1 + (kt) * 32, &As[bb][4096 + tid * 8]); \
        gload_lds16(pb0 + (kt) * 32, &Bs[bb][tid * 8]);        \
        gload_lds16(pb1 + (kt) * 32, &Bs[bb][4096 + tid * 8]); \
    } while (0)

    // ds_read base addresses (logical quarter l4 -> physical l4 ^ ((row>>1)&3))
    const int q = l4 ^ ((l15 >> 1) & 3);
    const unsigned aB = lds_addr(&As[0][0]) + (unsigned)((wr * 128 + l15) * 64 + q * 16);
    const unsigned bB = lds_addr(&Bs[0][0]) + (unsigned)((wc * 64 + l15) * 64 + q * 16);

#define DSR(dst, addr, off) \
    asm volatile("ds_read_b128 %0, %1 offset:" #off : "=v"(dst) : "v"(addr))

    STG(0, 0);
    STG(1, 1);
    int bc = 0, bs = 2;
    for (int kt = 0; kt < nK; ++kt) {
        if (kt + 1 < nK)
            asm volatile("s_waitcnt vmcnt(4)\ns_barrier" ::: "memory");
        else
            asm volatile("s_waitcnt vmcnt(0)\ns_barrier" ::: "memory");
        __builtin_amdgcn_sched_barrier(0);

        bf16x8 a[8], b[4];
        {
            const unsigned aA = aB + bc * 16384;
            const unsigned bA = bB + bc * 16384;
            DSR(a[0], aA, 0);    DSR(a[1], aA, 1024);
            DSR(a[2], aA, 2048); DSR(a[3], aA, 3072);
            DSR(a[4], aA, 4096); DSR(a[5], aA, 5120);
            DSR(a[6], aA, 6144); DSR(a[7], aA, 7168);
            DSR(b[0], bA, 0);    DSR(b[1], bA, 1024);
            DSR(b[2], bA, 2048); DSR(b[3], bA, 3072);
        }
        if (kt + 2 < nK) STG(kt + 2, bs);
        asm volatile("s_waitcnt lgkmcnt(0)" ::: "memory");
        __builtin_amdgcn_sched_barrier(0);

        __builtin_amdgcn_s_setprio(1);
#pragma unroll
        for (int m = 0; m < 8; ++m)
#pragma unroll
            for (int n = 0; n < 4; ++n)
                acc[m][n] = MFMA16(a[m], b[n], acc[m][n]);
        __builtin_amdgcn_s_setprio(0);

        if (++bc == 3) bc = 0;
        if (++bs == 3) bs = 0;
    }
#undef STG
#undef DSR

    for (int m = 0; m < 8; ++m)
        for (int n = 0; n < 4; ++n)
            for (int j = 0; j < 4; ++j) {
                int row = bm * 256 + wr * 128 + m * 16 + l4 * 4 + j;
                int col = bn * 256 + wc * 64 + n * 16 + l15;
                C[(size_t)row * N + col] = acc[m][n][j];
            }
}

// ---------------------------------------------------------------- combine + RMSNorm + RoPE + repack
// p0,p1 f32 [2048][3072]; heads 0..15 -> Q, 16..19 -> K, 20..23 -> V
__global__ __launch_bounds__(256) void norm_rope(const float* __restrict__ p0,
                                                 const float* __restrict__ p1,
                                                 const float* __restrict__ qw,
                                                 const float* __restrict__ kw,
                                                 const float2* __restrict__ tbl,
                                                 unsigned short* __restrict__ Qb,
                                                 unsigned short* __restrict__ Kb,
                                                 unsigned short* __restrict__ Vb) {
    const int row = blockIdx.x;
    const int head = blockIdx.y * 4 + (threadIdx.x >> 6);
    const int t = threadIdx.x & 63;
    const size_t off = (size_t)row * 3072 + head * 128;
    float x1 = p0[off + t] + p1[off + t];
    float x2 = p0[off + t + 64] + p1[off + t + 64];
    if (head < 20) {
        float ss = x1 * x1 + x2 * x2;
        for (int m = 32; m; m >>= 1) ss += __shfl_xor(ss, m);
        float r = rsqrtf(ss * (1.0f / 128.0f) + 1e-6f);
        const float* w = (head < 16) ? qw : kw;
        float y1 = x1 * r * w[t], y2 = x2 * r * w[t + 64];
        float2 cs = tbl[row * 64 + t];
        x1 = y1 * cs.x - y2 * cs.y;
        x2 = y1 * cs.y + y2 * cs.x;
    }
    unsigned short* dst;
    if (head < 16)      dst = Qb + ((size_t)head * 2048 + row) * 128;
    else if (head < 20) dst = Kb + ((size_t)(head - 16) * 2048 + row) * 128;
    else                dst = Vb + ((size_t)(head - 20) * 2048 + row) * 128;
    dst[t] = f2bf(x1);
    dst[t + 64] = f2bf(x2);
}

// ---------------------------------------------------------------- V transpose: Vb [4][2048][128] -> VbT [4][128][2048]
__global__ __launch_bounds__(256) void transpose_v(const unsigned short* __restrict__ Vb,
                                                   unsigned short* __restrict__ VbT) {
    const int kt = blockIdx.x;
    const int h  = blockIdx.y;
    __shared__ unsigned short T[64 * 130];
    const int tid = threadIdx.x;
    for (int i = 0; i < 4; ++i) {
        int s = i * 256 + tid;
        int r = s >> 4, c = (s & 15) * 8;
        us8 v = *(const us8*)(Vb + ((size_t)h * 2048 + kt * 64 + r) * 128 + c);
        for (int j = 0; j < 8; ++j) T[r * 130 + c + j] = v[j];
    }
    __syncthreads();
    for (int i = 0; i < 4; ++i) {
        int s = i * 256 + tid;
        int d = s >> 3, ck = (s & 7) * 8;
        us8 v;
        for (int j = 0; j < 8; ++j) v[j] = T[(ck + j) * 130 + d];
        *(us8*)(VbT + (size_t)h * 128 * 2048 + (size_t)d * 2048 + kt * 64 + ck) = v;
    }
}

// ---------------------------------------------------------------- flash attention (windowed causal GQA)
__global__ __launch_bounds__(256) void attn_fwd(const unsigned short* __restrict__ Qb,
                                                const unsigned short* __restrict__ Kb,
                                                const unsigned short* __restrict__ VbT,
                                                unsigned short* __restrict__ Ob) {
    const int qt = blockIdx.x;
    const int h = blockIdx.y;
    const int kvh = h >> 2;
    const int q0 = qt * 64;
    __shared__ unsigned short Ks[2][64 * 128];
    __shared__ unsigned short Vs[2][128 * 64];
    __shared__ unsigned short Ps[4][16 * 72];
    const int tid = threadIdx.x;
    const int lane = tid & 63, wave = tid >> 6;
    const int l15 = lane & 15, l4 = lane >> 4;

    bf16x8 qf[4];
    {
        const unsigned short* qrow =
            Qb + ((size_t)h * 2048 + q0 + wave * 16 + l15) * 128 + l4 * 8;
        for (int kk = 0; kk < 4; ++kk) qf[kk] = *(const bf16x8*)(qrow + kk * 32);
    }
    f32x4 o[8] = {};
    float m2[4], lp[4];
    for (int j = 0; j < 4; ++j) { m2[j] = -1e30f; lp[j] = 0.0f; }
    const float SCALE2 = 0.08838834764831843f * 1.4426950408889634f;
    const int kt_lo = (qt >= 16) ? (qt - 16) : 0;

    const unsigned short* Kh = Kb + (size_t)kvh * 2048 * 128;
    const unsigned short* Vh = VbT + (size_t)kvh * 128 * 2048;

    {   // prologue
        const int kt = kt_lo;
        for (int i = 0; i < 4; ++i) {
            int s = i * 256 + tid;
            int r = s >> 4;
            int cb = ((s & 15) * 16) ^ ((r & 7) << 4);
            gload_lds16(Kh + (size_t)(kt * 64 + r) * 128 + (cb >> 1), &Ks[0][s * 8]);
        }
        for (int i = 0; i < 4; ++i) {
            int s = i * 256 + tid;
            int d = s >> 3;
            int cb = ((s & 7) * 16) ^ ((d & 7) << 4);
            gload_lds16(Vh + (size_t)d * 2048 + kt * 64 + (cb >> 1), &Vs[0][s * 8]);
        }
    }

    int cur = 0;
    for (int kt = kt_lo; kt <= qt; ++kt) {
        __syncthreads();

        if (kt < qt) {
            const int kn = kt + 1;
            for (int i = 0; i < 4; ++i) {
                int s = i * 256 + tid;
                int r = s >> 4;
                int cb = ((s & 15) * 16) ^ ((r & 7) << 4);
                gload_lds16(Kh + (size_t)(kn * 64 + r) * 128 + (cb >> 1), &Ks[cur ^ 1][s * 8]);
            }
            for (int i = 0; i < 4; ++i) {
                int s = i * 256 + tid;
                int d = s >> 3;
                int cb = ((s & 7) * 16) ^ ((d & 7) << 4);
                gload_lds16(Vh + (size_t)d * 2048 + kn * 64 + (cb >> 1), &Vs[cur ^ 1][s * 8]);
            }
        }

        f32x4 s[4] = {};
        __builtin_amdgcn_s_setprio(1);
        for (int nn = 0; nn < 4; ++nn)
            for (int kk = 0; kk < 4; ++kk) {
                int r = nn * 16 + l15;
                int cb = (kk * 64 + l4 * 16) ^ ((r & 7) << 4);
                bf16x8 kf = *(const bf16x8*)((const char*)&Ks[cur][0] + r * 256 + cb);
                s[nn] = MFMA16(qf[kk], kf, s[nn]);
            }
        __builtin_amdgcn_s_setprio(0);

        float p[4][4];
        const bool masked = (kt == qt) || (qt >= 16 && kt == kt_lo);
        if (masked) {
            for (int nn = 0; nn < 4; ++nn) {
                int kc = kt * 64 + nn * 16 + l15;
                for (int j = 0; j < 4; ++j) {
                    int qr = q0 + wave * 16 + l4 * 4 + j;
                    float sv = s[nn][j] * SCALE2;
                    bool ok = (qr >= kc) && (qr - kc < 1024);
                    p[nn][j] = ok ? sv : -1e30f;
                }
            }
        } else {
            for (int nn = 0; nn < 4; ++nn)
                for (int j = 0; j < 4; ++j) p[nn][j] = s[nn][j] * SCALE2;
        }

        float mx4[4];
        bool flag = true;
        for (int j = 0; j < 4; ++j) {
            float mx = fmaxf(fmaxf(p[0][j], p[1][j]), fmaxf(p[2][j], p[3][j]));
            for (int mk = 8; mk; mk >>= 1) mx = fmaxf(mx, __shfl_xor(mx, mk));
            mx4[j] = mx;
            flag = flag && (mx <= m2[j] + 11.0f);
        }
        if (!__all(flag)) {
            for (int j = 0; j < 4; ++j) {
                float mnew = fmaxf(m2[j], mx4[j]);
                float corr = exp2f(m2[j] - mnew);
                m2[j] = mnew;
                lp[j] *= corr;
                for (int dd = 0; dd < 8; ++dd) o[dd][j] *= corr;
            }
        }
        for (int j = 0; j < 4; ++j) {
            float rs = 0.0f;
            for (int nn = 0; nn < 4; ++nn) {
                float pv = exp2f(p[nn][j] - m2[j]);
                p[nn][j] = pv;
                rs += pv;
            }
            lp[j] += rs;
        }

        for (int j = 0; j < 4; ++j)
            for (int nn = 0; nn < 4; ++nn)
                Ps[wave][(l4 * 4 + j) * 72 + nn * 16 + l15] = f2bf(p[nn][j]);

        bf16x8 pa[2];
        for (int kk2 = 0; kk2 < 2; ++kk2)
            pa[kk2] = *(const bf16x8*)&Ps[wave][l15 * 72 + kk2 * 32 + l4 * 8];

        __builtin_amdgcn_s_setprio(1);
        for (int dd = 0; dd < 8; ++dd)
            for (int kk2 = 0; kk2 < 2; ++kk2) {
                int d = dd * 16 + l15;
                int cb = (kk2 * 64 + l4 * 16) ^ ((d & 7) << 4);
                bf16x8 vf = *(const bf16x8*)((const char*)&Vs[cur][0] + d * 128 + cb);
                o[dd] = MFMA16(pa[kk2], vf, o[dd]);
            }
        __builtin_amdgcn_s_setprio(0);
        cur ^= 1;
    }

    for (int j = 0; j < 4; ++j) {
        float lt = lp[j];
        for (int mk = 8; mk; mk >>= 1) lt += __shfl_xor(lt, mk);
        float inv = 1.0f / lt;
        int row = q0 + wave * 16 + l4 * 4 + j;
        unsigned short* orow = Ob + (size_t)row * 2048 + h * 128;
        for (int dd = 0; dd < 8; ++dd) orow[dd * 16 + l15] = f2bf(o[dd][j] * inv);
    }
}

// ---------------------------------------------------------------- combine 4 split-K partials
__global__ __launch_bounds__(256) void add4(const float* __restrict__ p,
                                            float* __restrict__ out, int n) {
    int i = (blockIdx.x * 256 + threadIdx.x) * 4;
    if (i >= n) return;
    f32x4 a = *(const f32x4*)(p + i);
    f32x4 b = *(const f32x4*)(p + 4194304 + i);
    f32x4 c = *(const f32x4*)(p + 8388608 + i);
    f32x4 d = *(const f32x4*)(p + 12582912 + i);
    a = (a + b) + (c + d);
    *(f32x4*)(out + i) = a;
}

// ---------------------------------------------------------------- launch
extern "C" void kernel_launch(void* const* d_in, const int* in_sizes, int n_in,
                              void* d_out, int out_size, void* d_ws, size_t ws_size,
                              hipStream_t stream) {
    const float* x  = (const float*)d_in[0];
    const float* wq = (const float*)d_in[1];
    const float* wk = (const float*)d_in[2];
    const float* wv = (const float*)d_in[3];
    const float* wo = (const float*)d_in[4];
    const float* qw = (const float*)d_in[5];
    const float* kw = (const float*)d_in[6];
    float* out = (float*)d_out;

    char* ws = (char*)d_ws;
    unsigned short* xb   = (unsigned short*)(ws + 0);          //  8 MB (dead after gemm-qkv)
    unsigned short* wqkv = (unsigned short*)(ws + 8388608);    // 12 MB (dead after gemm-qkv)
    unsigned short* wob  = (unsigned short*)(ws + 20971520);   //  8 MB (alive till gemm-out)
    float*          qkvP = (float*)(ws + 29360128);            // 48 MB f32 x2 partials (dead after norm_rope)
    unsigned short* Qb   = (unsigned short*)(ws + 79691776);   //  8 MB (dead after attn)
    unsigned short* Kb   = (unsigned short*)(ws + 88080384);   //  2 MB (dead after attn)
    unsigned short* Vb   = (unsigned short*)(ws + 90177536);   //  2 MB (dead after transpose)
    unsigned short* VbT  = (unsigned short*)(ws + 92274688);   //  2 MB (dead after attn)
    float*          outP = (float*)(ws + 29360128);            // 64 MB, overlays dead qkvP/Qb/Kb/Vb/VbT
    unsigned short* Ob   = (unsigned short*)(ws + 96468992);   //  8 MB (outside outP)
    float2*         tbl  = (float2*)(ws + 104857600);          //  1 MB

    prep_all<<<dim3(14848), dim3(256), 0, stream>>>(x, wq, wk, wv, wo, xb, wqkv, wob, tbl);
    gemm256<<<dim3(12, 8, 2), dim3(512), 0, stream>>>(xb, wqkv, qkvP, 2048, 3072, 2048, 1024);
    norm_rope<<<dim3(2048, 6), dim3(256), 0, stream>>>(qkvP, qkvP + 2048 * 3072, qw, kw, tbl, Qb, Kb, Vb);
    transpose_v<<<dim3(32, 4), dim3(256), 0, stream>>>(Vb, VbT);
    attn_fwd<<<dim3(32, 16), dim3(256), 0, stream>>>(Qb, Kb, VbT, Ob);
    gemm256<<<dim3(8, 8, 4), dim3(512), 0, stream>>>(Ob, wob, outP, 2048, 2048, 2048, 512);
    add4<<<dim3(4096), dim3(256), 0, stream>>>(outP, out, 2048 * 2048);
}

// Round 8
// 143.697 us; speedup vs baseline: 1.8892x; 1.0281x over previous
//
#include <hip/hip_runtime.h>
#include <hip/hip_bf16.h>
#include <cstdint>
#include <cstddef>

typedef __attribute__((ext_vector_type(4))) float f32x4;
typedef __attribute__((ext_vector_type(8))) short bf16x8;
typedef __attribute__((ext_vector_type(8))) unsigned short us8;

#define MFMA16(a, b, c) __builtin_amdgcn_mfma_f32_16x16x32_bf16(a, b, c, 0, 0, 0)

__device__ inline unsigned short f2bf(float f) {
    unsigned int u = __float_as_uint(f);
    u += 0x7fffu + ((u >> 16) & 1u);
    return (unsigned short)(u >> 16);
}
// 1-instruction bf16 convert (RTNE) via packed cvt; low 16 bits hold the result
__device__ inline unsigned short f2bf_fast(float f) {
    float r;
    asm("v_cvt_pk_bf16_f32 %0, %1, %2" : "=v"(r) : "v"(f), "v"(f));
    return (unsigned short)__float_as_uint(r);
}

__device__ inline void gload_lds16(const void* g, void* l) {
    __builtin_amdgcn_global_load_lds(
        (const __attribute__((address_space(1))) void*)g,
        (__attribute__((address_space(3))) void*)l, 16, 0, 0);
}
__device__ inline unsigned lds_addr(const void* p) {
    return (unsigned)(size_t)((__attribute__((address_space(3))) const void*)p);
}

// ---------------------------------------------------------------- fused prep: 5 f32->bf16 converts + RoPE table
__global__ __launch_bounds__(256) void prep_all(const float* __restrict__ x,
                                                const float* __restrict__ wq,
                                                const float* __restrict__ wk,
                                                const float* __restrict__ wv,
                                                const float* __restrict__ wo,
                                                unsigned short* __restrict__ xb,
                                                unsigned short* __restrict__ wqkv,
                                                unsigned short* __restrict__ wob,
                                                float2* __restrict__ tbl) {
    const int b = blockIdx.x;
    if (b < 14336) {
        const float* src; unsigned short* dst; int off4;
        if (b < 4096)       { src = x;  dst = xb;                 off4 = b; }
        else if (b < 8192)  { src = wq; dst = wqkv;               off4 = b - 4096; }
        else if (b < 9216)  { src = wk; dst = wqkv + 2048 * 2048; off4 = b - 8192; }
        else if (b < 10240) { src = wv; dst = wqkv + 2560 * 2048; off4 = b - 9216; }
        else                { src = wo; dst = wob;                off4 = b - 10240; }
        int i = (off4 * 256 + threadIdx.x) * 4;
        float4 v = *(const float4*)(src + i);
        ushort4 o;
        o.x = f2bf(v.x); o.y = f2bf(v.y); o.z = f2bf(v.z); o.w = f2bf(v.w);
        *(ushort4*)(dst + i) = o;
    } else {
        int idx = (b - 14336) * 256 + threadIdx.x;
        int row = idx >> 6, t = idx & 63;
        float inv_freq = exp2f((float)t * (-2.0f / 128.0f) * 13.287712379549449f);
        float s, c;
        sincosf((float)row * inv_freq, &s, &c);
        tbl[idx] = make_float2(c, s);
    }
}

// ---------------------------------------------------------------- gemm256 (unchanged from R6)
__global__ __launch_bounds__(512, 2) void gemm256(const unsigned short* __restrict__ A,
                                                  const unsigned short* __restrict__ B,
                                                  float* __restrict__ Cp,
                                                  int M, int N, int Kfull, int kspan) {
    __shared__ unsigned short As[3][8192];
    __shared__ unsigned short Bs[3][8192];
    const int tid = threadIdx.x;
    const int lane = tid & 63, wave = tid >> 6;
    const int wr = wave >> 2, wc = wave & 3;
    const int l15 = lane & 15, l4 = lane >> 4;
    const int gx = gridDim.x;
    const int nwg = gx * gridDim.y;
    const int bid0 = blockIdx.y * gx + blockIdx.x;
    const int q8 = nwg >> 3, r8 = nwg & 7;
    const int xcd = bid0 & 7, sub = bid0 >> 3;
    const int wgid = ((xcd < r8) ? xcd * (q8 + 1) : r8 * (q8 + 1) + (xcd - r8) * q8) + sub;
    const int bm = wgid / gx, bn = wgid % gx;
    const int z = blockIdx.z;
    const unsigned short* Az = A + (size_t)z * kspan;
    const unsigned short* Bz = B + (size_t)z * kspan;
    float* C = Cp + (size_t)z * M * N;
    const int nK = kspan >> 5;

    f32x4 acc[8][4] = {};

    const int r0 = tid >> 2, qs = tid & 3;
    const int qsw = qs ^ ((r0 >> 1) & 3);
    const unsigned short* pa0 = Az + (size_t)(bm * 256 + r0) * Kfull + qsw * 8;
    const unsigned short* pa1 = pa0 + (size_t)128 * Kfull;
    const unsigned short* pb0 = Bz + (size_t)(bn * 256 + r0) * Kfull + qsw * 8;
    const unsigned short* pb1 = pb0 + (size_t)128 * Kfull;

#define STG(kt, bb)                                            \
    do {                                                       \
        gload_lds16(pa0 + (kt) * 32, &As[bb][tid * 8]);        \
        gload_lds16(pa1 + (kt) * 32, &As[bb][4096 + tid * 8]); \
        gload_lds16(pb0 + (kt) * 32, &Bs[bb][tid * 8]);        \
        gload_lds16(pb1 + (kt) * 32, &Bs[bb][4096 + tid * 8]); \
    } while (0)

    const int q = l4 ^ ((l15 >> 1) & 3);
    const unsigned aB = lds_addr(&As[0][0]) + (unsigned)((wr * 128 + l15) * 64 + q * 16);
    const unsigned bB = lds_addr(&Bs[0][0]) + (unsigned)((wc * 64 + l15) * 64 + q * 16);

#define DSR(dst, addr, off) \
    asm volatile("ds_read_b128 %0, %1 offset:" #off : "=v"(dst) : "v"(addr))

    STG(0, 0);
    STG(1, 1);
    int bc = 0, bs = 2;
    for (int kt = 0; kt < nK; ++kt) {
        if (kt + 1 < nK)
            asm volatile("s_waitcnt vmcnt(4)\ns_barrier" ::: "memory");
        else
            asm volatile("s_waitcnt vmcnt(0)\ns_barrier" ::: "memory");
        __builtin_amdgcn_sched_barrier(0);

        bf16x8 a[8], b[4];
        {
            const unsigned aA = aB + bc * 16384;
            const unsigned bA = bB + bc * 16384;
            DSR(a[0], aA, 0);    DSR(a[1], aA, 1024);
            DSR(a[2], aA, 2048); DSR(a[3], aA, 3072);
            DSR(a[4], aA, 4096); DSR(a[5], aA, 5120);
            DSR(a[6], aA, 6144); DSR(a[7], aA, 7168);
            DSR(b[0], bA, 0);    DSR(b[1], bA, 1024);
            DSR(b[2], bA, 2048); DSR(b[3], bA, 3072);
        }
        if (kt + 2 < nK) STG(kt + 2, bs);
        asm volatile("s_waitcnt lgkmcnt(0)" ::: "memory");
        __builtin_amdgcn_sched_barrier(0);

        __builtin_amdgcn_s_setprio(1);
#pragma unroll
        for (int m = 0; m < 8; ++m)
#pragma unroll
            for (int n = 0; n < 4; ++n)
                acc[m][n] = MFMA16(a[m], b[n], acc[m][n]);
        __builtin_amdgcn_s_setprio(0);

        if (++bc == 3) bc = 0;
        if (++bs == 3) bs = 0;
    }
#undef STG
#undef DSR

    for (int m = 0; m < 8; ++m)
        for (int n = 0; n < 4; ++n)
            for (int j = 0; j < 4; ++j) {
                int row = bm * 256 + wr * 128 + m * 16 + l4 * 4 + j;
                int col = bn * 256 + wc * 64 + n * 16 + l15;
                C[(size_t)row * N + col] = acc[m][n][j];
            }
}

// ---------------------------------------------------------------- combine + RMSNorm + RoPE (Q/K heads only; Q pre-scaled)
__global__ __launch_bounds__(256) void norm_rope(const float* __restrict__ p0,
                                                 const float* __restrict__ p1,
                                                 const float* __restrict__ qw,
                                                 const float* __restrict__ kw,
                                                 const float2* __restrict__ tbl,
                                                 unsigned short* __restrict__ Qb,
                                                 unsigned short* __restrict__ Kb) {
    const int row = blockIdx.x;
    const int head = blockIdx.y * 4 + (threadIdx.x >> 6);  // 0..19
    const int t = threadIdx.x & 63;
    const size_t off = (size_t)row * 3072 + head * 128;
    float x1 = p0[off + t] + p1[off + t];
    float x2 = p0[off + t + 64] + p1[off + t + 64];
    float ss = x1 * x1 + x2 * x2;
    for (int m = 32; m; m >>= 1) ss += __shfl_xor(ss, m);
    float r = rsqrtf(ss * (1.0f / 128.0f) + 1e-6f);
    const float* w = (head < 16) ? qw : kw;
    float y1 = x1 * r * w[t], y2 = x2 * r * w[t + 64];
    float2 cs = tbl[row * 64 + t];
    x1 = y1 * cs.x - y2 * cs.y;
    x2 = y1 * cs.y + y2 * cs.x;
    if (head < 16) {                       // fold softmax scale*log2(e) into Q
        const float SCALE2 = 0.12751879526654698f;
        x1 *= SCALE2; x2 *= SCALE2;
    }
    unsigned short* dst = (head < 16) ? Qb + ((size_t)head * 2048 + row) * 128
                                      : Kb + ((size_t)(head - 16) * 2048 + row) * 128;
    dst[t] = f2bf(x1);
    dst[t + 64] = f2bf(x2);
}

// ---------------------------------------------------------------- V: combine partials + transpose -> VbT [4][128][2048]
__global__ __launch_bounds__(256) void transpose_v(const float* __restrict__ p0,
                                                   const float* __restrict__ p1,
                                                   unsigned short* __restrict__ VbT) {
    const int kt = blockIdx.x;  // 0..31
    const int h  = blockIdx.y;  // 0..3
    __shared__ unsigned short T[64 * 132];
    const int tid = threadIdx.x;
    for (int i = 0; i < 8; ++i) {
        int s = i * 256 + tid;
        int r = s >> 5, c = (s & 31) * 4;
        size_t off = (size_t)(kt * 64 + r) * 3072 + (20 + h) * 128 + c;
        float4 a = *(const float4*)(p0 + off);
        float4 b = *(const float4*)(p1 + off);
        ushort4 o;
        o.x = f2bf(a.x + b.x); o.y = f2bf(a.y + b.y);
        o.z = f2bf(a.z + b.z); o.w = f2bf(a.w + b.w);
        *(ushort4*)&T[r * 132 + c] = o;
    }
    __syncthreads();
    for (int i = 0; i < 4; ++i) {
        int s = i * 256 + tid;
        int d = s >> 3, ck = (s & 7) * 8;
        us8 v;
        for (int j = 0; j < 8; ++j) v[j] = T[(ck + j) * 132 + d];
        *(us8*)(VbT + (size_t)h * 128 * 2048 + (size_t)d * 2048 + kt * 64 + ck) = v;
    }
}

// ---------------------------------------------------------------- flash attention (windowed causal GQA)
// 1-D grid, XCD-pinned: bid&7 = dispatch slot -> 2 fixed heads per XCD
__global__ __launch_bounds__(256) void attn_fwd(const unsigned short* __restrict__ Qb,
                                                const unsigned short* __restrict__ Kb,
                                                const unsigned short* __restrict__ VbT,
                                                unsigned short* __restrict__ Ob) {
    const int bid = blockIdx.x;
    const int seq = bid >> 3;
    const int h = (bid & 7) * 2 + (seq >> 5);   // XCD slot owns heads {2s, 2s+1}
    const int qt = seq & 31;
    const int kvh = h >> 2;
    const int q0 = qt * 64;
    __shared__ unsigned short Ks[2][64 * 128];
    __shared__ unsigned short Vs[2][128 * 64];
    __shared__ unsigned short Ps[4][16 * 72];
    const int tid = threadIdx.x;
    const int lane = tid & 63, wave = tid >> 6;
    const int l15 = lane & 15, l4 = lane >> 4;

    bf16x8 qf[4];
    {
        const unsigned short* qrow =
            Qb + ((size_t)h * 2048 + q0 + wave * 16 + l15) * 128 + l4 * 8;
        for (int kk = 0; kk < 4; ++kk) qf[kk] = *(const bf16x8*)(qrow + kk * 32);
    }
    f32x4 o[8] = {};
    float m2[4], lp[4];
    for (int j = 0; j < 4; ++j) { m2[j] = -1e30f; lp[j] = 0.0f; }
    const int kt_lo = (qt >= 16) ? (qt - 16) : 0;

    const unsigned short* Kh = Kb + (size_t)kvh * 2048 * 128;
    const unsigned short* Vh = VbT + (size_t)kvh * 128 * 2048;

    {   // prologue
        const int kt = kt_lo;
        for (int i = 0; i < 4; ++i) {
            int s = i * 256 + tid;
            int r = s >> 4;
            int cb = ((s & 15) * 16) ^ ((r & 7) << 4);
            gload_lds16(Kh + (size_t)(kt * 64 + r) * 128 + (cb >> 1), &Ks[0][s * 8]);
        }
        for (int i = 0; i < 4; ++i) {
            int s = i * 256 + tid;
            int d = s >> 3;
            int cb = ((s & 7) * 16) ^ ((d & 7) << 4);
            gload_lds16(Vh + (size_t)d * 2048 + kt * 64 + (cb >> 1), &Vs[0][s * 8]);
        }
    }

    int cur = 0;
    for (int kt = kt_lo; kt <= qt; ++kt) {
        __syncthreads();

        if (kt < qt) {
            const int kn = kt + 1;
            for (int i = 0; i < 4; ++i) {
                int s = i * 256 + tid;
                int r = s >> 4;
                int cb = ((s & 15) * 16) ^ ((r & 7) << 4);
                gload_lds16(Kh + (size_t)(kn * 64 + r) * 128 + (cb >> 1), &Ks[cur ^ 1][s * 8]);
            }
            for (int i = 0; i < 4; ++i) {
                int s = i * 256 + tid;
                int d = s >> 3;
                int cb = ((s & 7) * 16) ^ ((d & 7) << 4);
                gload_lds16(Vh + (size_t)d * 2048 + kn * 64 + (cb >> 1), &Vs[cur ^ 1][s * 8]);
            }
        }

        // S = Q K^T (Q pre-scaled -> p is already in log2 domain)
        f32x4 s[4] = {};
        __builtin_amdgcn_s_setprio(1);
        for (int nn = 0; nn < 4; ++nn)
            for (int kk = 0; kk < 4; ++kk) {
                int r = nn * 16 + l15;
                int cb = (kk * 64 + l4 * 16) ^ ((r & 7) << 4);
                bf16x8 kf = *(const bf16x8*)((const char*)&Ks[cur][0] + r * 256 + cb);
                s[nn] = MFMA16(qf[kk], kf, s[nn]);
            }
        __builtin_amdgcn_s_setprio(0);

        float p[4][4];
        const bool masked = (kt == qt) || (qt >= 16 && kt == kt_lo);
        if (masked) {
            for (int nn = 0; nn < 4; ++nn) {
                int kc = kt * 64 + nn * 16 + l15;
                for (int j = 0; j < 4; ++j) {
                    int qr = q0 + wave * 16 + l4 * 4 + j;
                    unsigned diff = (unsigned)(qr - kc);
                    p[nn][j] = (diff < 1024u) ? s[nn][j] : -1e30f;
                }
            }
        } else {
            for (int nn = 0; nn < 4; ++nn)
                for (int j = 0; j < 4; ++j) p[nn][j] = s[nn][j];
        }

        // deferred-max: common path needs NO cross-lane reduce
        float mxl[4];
        bool flag = true;
        for (int j = 0; j < 4; ++j) {
            mxl[j] = fmaxf(fmaxf(p[0][j], p[1][j]), fmaxf(p[2][j], p[3][j]));
            flag = flag && (mxl[j] <= m2[j] + 11.0f);
        }
        if (!__all(flag)) {
            for (int j = 0; j < 4; ++j) {
                float mx = mxl[j];
                for (int mk = 8; mk; mk >>= 1) mx = fmaxf(mx, __shfl_xor(mx, mk));
                float mnew = fmaxf(m2[j], mx);
                float corr = exp2f(m2[j] - mnew);
                m2[j] = mnew;
                lp[j] *= corr;
                for (int dd = 0; dd < 8; ++dd) o[dd][j] *= corr;
            }
        }
        for (int j = 0; j < 4; ++j) {
            float rs = 0.0f;
            for (int nn = 0; nn < 4; ++nn) {
                float pv = exp2f(p[nn][j] - m2[j]);
                p[nn][j] = pv;
                rs += pv;
            }
            lp[j] += rs;
        }

        for (int j = 0; j < 4; ++j)
            for (int nn = 0; nn < 4; ++nn)
                Ps[wave][(l4 * 4 + j) * 72 + nn * 16 + l15] = f2bf_fast(p[nn][j]);

        bf16x8 pa[2];
        for (int kk2 = 0; kk2 < 2; ++kk2)
            pa[kk2] = *(const bf16x8*)&Ps[wave][l15 * 72 + kk2 * 32 + l4 * 8];

        __builtin_amdgcn_s_setprio(1);
        for (int dd = 0; dd < 8; ++dd)
            for (int kk2 = 0; kk2 < 2; ++kk2) {
                int d = dd * 16 + l15;
                int cb = (kk2 * 64 + l4 * 16) ^ ((d & 7) << 4);
                bf16x8 vf = *(const bf16x8*)((const char*)&Vs[cur][0] + d * 128 + cb);
                o[dd] = MFMA16(pa[kk2], vf, o[dd]);
            }
        __builtin_amdgcn_s_setprio(0);
        cur ^= 1;
    }

    for (int j = 0; j < 4; ++j) {
        float lt = lp[j];
        for (int mk = 8; mk; mk >>= 1) lt += __shfl_xor(lt, mk);
        float inv = 1.0f / lt;
        int row = q0 + wave * 16 + l4 * 4 + j;
        unsigned short* orow = Ob + (size_t)row * 2048 + h * 128;
        for (int dd = 0; dd < 8; ++dd) orow[dd * 16 + l15] = f2bf_fast(o[dd][j] * inv);
    }
}

// ---------------------------------------------------------------- combine 4 split-K partials
__global__ __launch_bounds__(256) void add4(const float* __restrict__ p,
                                            float* __restrict__ out, int n) {
    int i = (blockIdx.x * 256 + threadIdx.x) * 4;
    if (i >= n) return;
    f32x4 a = *(const f32x4*)(p + i);
    f32x4 b = *(const f32x4*)(p + 4194304 + i);
    f32x4 c = *(const f32x4*)(p + 8388608 + i);
    f32x4 d = *(const f32x4*)(p + 12582912 + i);
    a = (a + b) + (c + d);
    *(f32x4*)(out + i) = a;
}

// ---------------------------------------------------------------- launch
extern "C" void kernel_launch(void* const* d_in, const int* in_sizes, int n_in,
                              void* d_out, int out_size, void* d_ws, size_t ws_size,
                              hipStream_t stream) {
    const float* x  = (const float*)d_in[0];
    const float* wq = (const float*)d_in[1];
    const float* wk = (const float*)d_in[2];
    const float* wv = (const float*)d_in[3];
    const float* wo = (const float*)d_in[4];
    const float* qw = (const float*)d_in[5];
    const float* kw = (const float*)d_in[6];
    float* out = (float*)d_out;

    char* ws = (char*)d_ws;
    unsigned short* xb   = (unsigned short*)(ws + 0);          //  8 MB
    unsigned short* wqkv = (unsigned short*)(ws + 8388608);    // 12 MB
    unsigned short* wob  = (unsigned short*)(ws + 20971520);   //  8 MB
    float*          qkvP = (float*)(ws + 29360128);            // 48 MB f32 x2 partials
    unsigned short* Qb   = (unsigned short*)(ws + 79691776);   //  8 MB
    unsigned short* Kb   = (unsigned short*)(ws + 88080384);   //  2 MB
    unsigned short* VbT  = (unsigned short*)(ws + 92274688);   //  2 MB
    float*          outP = (float*)(ws + 29360128);            // 64 MB overlays dead qkvP/Qb/Kb/VbT
    unsigned short* Ob   = (unsigned short*)(ws + 96468992);   //  8 MB
    float2*         tbl  = (float2*)(ws + 104857600);          //  1 MB

    prep_all<<<dim3(14848), dim3(256), 0, stream>>>(x, wq, wk, wv, wo, xb, wqkv, wob, tbl);
    gemm256<<<dim3(12, 8, 2), dim3(512), 0, stream>>>(xb, wqkv, qkvP, 2048, 3072, 2048, 1024);
    norm_rope<<<dim3(2048, 5), dim3(256), 0, stream>>>(qkvP, qkvP + 2048 * 3072, qw, kw, tbl, Qb, Kb);
    transpose_v<<<dim3(32, 4), dim3(256), 0, stream>>>(qkvP, qkvP + 2048 * 3072, VbT);
    attn_fwd<<<dim3(512), dim3(256), 0, stream>>>(Qb, Kb, VbT, Ob);
    gemm256<<<dim3(8, 8, 4), dim3(512), 0, stream>>>(Ob, wob, outP, 2048, 2048, 2048, 512);
    add4<<<dim3(4096), dim3(256), 0, stream>>>(outP, out, 2048 * 2048);
}

// Round 9
// 133.732 us; speedup vs baseline: 2.0299x; 1.0745x over previous
//
#include <hip/hip_runtime.h>
#include <hip/hip_bf16.h>
#include <cstdint>
#include <cstddef>

typedef __attribute__((ext_vector_type(4))) float f32x4;
typedef __attribute__((ext_vector_type(8))) short bf16x8;
typedef __attribute__((ext_vector_type(8))) unsigned short us8;

#define MFMA16(a, b, c) __builtin_amdgcn_mfma_f32_16x16x32_bf16(a, b, c, 0, 0, 0)

__device__ inline unsigned short f2bf(float f) {
    unsigned int u = __float_as_uint(f);
    u += 0x7fffu + ((u >> 16) & 1u);
    return (unsigned short)(u >> 16);
}
__device__ inline float bf2f(unsigned short u) {
    return __uint_as_float((unsigned int)u << 16);
}
// 1-instruction bf16 convert (RTNE) via packed cvt
__device__ inline unsigned short f2bf_fast(float f) {
    float r;
    asm("v_cvt_pk_bf16_f32 %0, %1, %2" : "=v"(r) : "v"(f), "v"(f));
    return (unsigned short)__float_as_uint(r);
}

__device__ inline void gload_lds16(const void* g, void* l) {
    __builtin_amdgcn_global_load_lds(
        (const __attribute__((address_space(1))) void*)g,
        (__attribute__((address_space(3))) void*)l, 16, 0, 0);
}
__device__ inline unsigned lds_addr(const void* p) {
    return (unsigned)(size_t)((__attribute__((address_space(3))) const void*)p);
}

// ---------------------------------------------------------------- fused prep: 5 f32->bf16 converts + RoPE table
__global__ __launch_bounds__(256) void prep_all(const float* __restrict__ x,
                                                const float* __restrict__ wq,
                                                const float* __restrict__ wk,
                                                const float* __restrict__ wv,
                                                const float* __restrict__ wo,
                                                unsigned short* __restrict__ xb,
                                                unsigned short* __restrict__ wqkv,
                                                unsigned short* __restrict__ wob,
                                                float2* __restrict__ tbl) {
    const int b = blockIdx.x;
    if (b < 14336) {
        const float* src; unsigned short* dst; int off4;
        if (b < 4096)       { src = x;  dst = xb;                 off4 = b; }
        else if (b < 8192)  { src = wq; dst = wqkv;               off4 = b - 4096; }
        else if (b < 9216)  { src = wk; dst = wqkv + 2048 * 2048; off4 = b - 8192; }
        else if (b < 10240) { src = wv; dst = wqkv + 2560 * 2048; off4 = b - 9216; }
        else                { src = wo; dst = wob;                off4 = b - 10240; }
        int i = (off4 * 256 + threadIdx.x) * 4;
        float4 v = *(const float4*)(src + i);
        ushort4 o;
        o.x = f2bf(v.x); o.y = f2bf(v.y); o.z = f2bf(v.z); o.w = f2bf(v.w);
        *(ushort4*)(dst + i) = o;
    } else {
        int idx = (b - 14336) * 256 + threadIdx.x;
        int row = idx >> 6, t = idx & 63;
        float inv_freq = exp2f((float)t * (-2.0f / 128.0f) * 13.287712379549449f);
        float s, c;
        sincosf((float)row * inv_freq, &s, &c);
        tbl[idx] = make_float2(c, s);
    }
}

// ---------------------------------------------------------------- gemm256: bf16 partials out (f32 accum in AGPR)
__global__ __launch_bounds__(512, 2) void gemm256(const unsigned short* __restrict__ A,
                                                  const unsigned short* __restrict__ B,
                                                  unsigned short* __restrict__ Cp,
                                                  int M, int N, int Kfull, int kspan) {
    __shared__ unsigned short As[3][8192];
    __shared__ unsigned short Bs[3][8192];
    const int tid = threadIdx.x;
    const int lane = tid & 63, wave = tid >> 6;
    const int wr = wave >> 2, wc = wave & 3;
    const int l15 = lane & 15, l4 = lane >> 4;
    const int gx = gridDim.x;
    const int nwg = gx * gridDim.y;
    const int bid0 = blockIdx.y * gx + blockIdx.x;
    const int q8 = nwg >> 3, r8 = nwg & 7;
    const int xcd = bid0 & 7, sub = bid0 >> 3;
    const int wgid = ((xcd < r8) ? xcd * (q8 + 1) : r8 * (q8 + 1) + (xcd - r8) * q8) + sub;
    const int bm = wgid / gx, bn = wgid % gx;
    const int z = blockIdx.z;
    const unsigned short* Az = A + (size_t)z * kspan;
    const unsigned short* Bz = B + (size_t)z * kspan;
    unsigned short* C = Cp + (size_t)z * M * N;
    const int nK = kspan >> 5;

    f32x4 acc[8][4] = {};

    const int r0 = tid >> 2, qs = tid & 3;
    const int qsw = qs ^ ((r0 >> 1) & 3);
    const unsigned short* pa0 = Az + (size_t)(bm * 256 + r0) * Kfull + qsw * 8;
    const unsigned short* pa1 = pa0 + (size_t)128 * Kfull;
    const unsigned short* pb0 = Bz + (size_t)(bn * 256 + r0) * Kfull + qsw * 8;
    const unsigned short* pb1 = pb0 + (size_t)128 * Kfull;

#define STG(kt, bb)                                            \
    do {                                                       \
        gload_lds16(pa0 + (kt) * 32, &As[bb][tid * 8]);        \
        gload_lds16(pa1 + (kt) * 32, &As[bb][4096 + tid * 8]); \
        gload_lds16(pb0 + (kt) * 32, &Bs[bb][tid * 8]);        \
        gload_lds16(pb1 + (kt) * 32, &Bs[bb][4096 + tid * 8]); \
    } while (0)

    const int q = l4 ^ ((l15 >> 1) & 3);
    const unsigned aB = lds_addr(&As[0][0]) + (unsigned)((wr * 128 + l15) * 64 + q * 16);
    const unsigned bB = lds_addr(&Bs[0][0]) + (unsigned)((wc * 64 + l15) * 64 + q * 16);

#define DSR(dst, addr, off) \
    asm volatile("ds_read_b128 %0, %1 offset:" #off : "=v"(dst) : "v"(addr))

    STG(0, 0);
    STG(1, 1);
    int bc = 0, bs = 2;
    for (int kt = 0; kt < nK; ++kt) {
        if (kt + 1 < nK)
            asm volatile("s_waitcnt vmcnt(4)\ns_barrier" ::: "memory");
        else
            asm volatile("s_waitcnt vmcnt(0)\ns_barrier" ::: "memory");
        __builtin_amdgcn_sched_barrier(0);

        bf16x8 a[8], b[4];
        {
            const unsigned aA = aB + bc * 16384;
            const unsigned bA = bB + bc * 16384;
            DSR(a[0], aA, 0);    DSR(a[1], aA, 1024);
            DSR(a[2], aA, 2048); DSR(a[3], aA, 3072);
            DSR(a[4], aA, 4096); DSR(a[5], aA, 5120);
            DSR(a[6], aA, 6144); DSR(a[7], aA, 7168);
            DSR(b[0], bA, 0);    DSR(b[1], bA, 1024);
            DSR(b[2], bA, 2048); DSR(b[3], bA, 3072);
        }
        if (kt + 2 < nK) STG(kt + 2, bs);
        asm volatile("s_waitcnt lgkmcnt(0)" ::: "memory");
        __builtin_amdgcn_sched_barrier(0);

        __builtin_amdgcn_s_setprio(1);
#pragma unroll
        for (int m = 0; m < 8; ++m)
#pragma unroll
            for (int n = 0; n < 4; ++n)
                acc[m][n] = MFMA16(a[m], b[n], acc[m][n]);
        __builtin_amdgcn_s_setprio(0);

        if (++bc == 3) bc = 0;
        if (++bs == 3) bs = 0;
    }
#undef STG
#undef DSR

    for (int m = 0; m < 8; ++m)
        for (int n = 0; n < 4; ++n)
            for (int j = 0; j < 4; ++j) {
                int row = bm * 256 + wr * 128 + m * 16 + l4 * 4 + j;
                int col = bn * 256 + wc * 64 + n * 16 + l15;
                C[(size_t)row * N + col] = f2bf_fast(acc[m][n][j]);
            }
}

// ---------------------------------------------------------------- combine + RMSNorm + RoPE (Q/K heads; Q pre-scaled)
__global__ __launch_bounds__(256) void norm_rope(const unsigned short* __restrict__ p0,
                                                 const unsigned short* __restrict__ p1,
                                                 const float* __restrict__ qw,
                                                 const float* __restrict__ kw,
                                                 const float2* __restrict__ tbl,
                                                 unsigned short* __restrict__ Qb,
                                                 unsigned short* __restrict__ Kb) {
    const int row = blockIdx.x;
    const int head = blockIdx.y * 4 + (threadIdx.x >> 6);  // 0..19
    const int t = threadIdx.x & 63;
    const size_t off = (size_t)row * 3072 + head * 128;
    float x1 = bf2f(p0[off + t]) + bf2f(p1[off + t]);
    float x2 = bf2f(p0[off + t + 64]) + bf2f(p1[off + t + 64]);
    float ss = x1 * x1 + x2 * x2;
    for (int m = 32; m; m >>= 1) ss += __shfl_xor(ss, m);
    float r = rsqrtf(ss * (1.0f / 128.0f) + 1e-6f);
    const float* w = (head < 16) ? qw : kw;
    float y1 = x1 * r * w[t], y2 = x2 * r * w[t + 64];
    float2 cs = tbl[row * 64 + t];
    x1 = y1 * cs.x - y2 * cs.y;
    x2 = y1 * cs.y + y2 * cs.x;
    if (head < 16) {                       // fold softmax scale*log2(e) into Q
        const float SCALE2 = 0.12751879526654698f;
        x1 *= SCALE2; x2 *= SCALE2;
    }
    unsigned short* dst = (head < 16) ? Qb + ((size_t)head * 2048 + row) * 128
                                      : Kb + ((size_t)(head - 16) * 2048 + row) * 128;
    dst[t] = f2bf(x1);
    dst[t + 64] = f2bf(x2);
}

// ---------------------------------------------------------------- V: combine bf16 partials + transpose -> VbT [4][128][2048]
__global__ __launch_bounds__(256) void transpose_v(const unsigned short* __restrict__ p0,
                                                   const unsigned short* __restrict__ p1,
                                                   unsigned short* __restrict__ VbT) {
    const int kt = blockIdx.x;  // 0..31
    const int h  = blockIdx.y;  // 0..3
    __shared__ unsigned short T[64 * 132];
    const int tid = threadIdx.x;
    for (int i = 0; i < 8; ++i) {
        int s = i * 256 + tid;
        int r = s >> 5, c = (s & 31) * 4;
        size_t off = (size_t)(kt * 64 + r) * 3072 + (20 + h) * 128 + c;
        ushort4 a = *(const ushort4*)(p0 + off);
        ushort4 b = *(const ushort4*)(p1 + off);
        ushort4 o;
        o.x = f2bf(bf2f(a.x) + bf2f(b.x));
        o.y = f2bf(bf2f(a.y) + bf2f(b.y));
        o.z = f2bf(bf2f(a.z) + bf2f(b.z));
        o.w = f2bf(bf2f(a.w) + bf2f(b.w));
        *(ushort4*)&T[r * 132 + c] = o;
    }
    __syncthreads();
    for (int i = 0; i < 4; ++i) {
        int s = i * 256 + tid;
        int d = s >> 3, ck = (s & 7) * 8;
        us8 v;
        for (int j = 0; j < 8; ++j) v[j] = T[(ck + j) * 132 + d];
        *(us8*)(VbT + (size_t)h * 128 * 2048 + (size_t)d * 2048 + kt * 64 + ck) = v;
    }
}

// ---------------------------------------------------------------- flash attention (windowed causal GQA)
// 2 blocks/CU: K dbuf + single-V async stage; 2 counted barriers/tile
__global__ __launch_bounds__(256) void attn_fwd(const unsigned short* __restrict__ Qb,
                                                const unsigned short* __restrict__ Kb,
                                                const unsigned short* __restrict__ VbT,
                                                unsigned short* __restrict__ Ob) {
    const int bid = blockIdx.x;
    const int seq = bid >> 3;
    const int h = (bid & 7) * 2 + (seq >> 5);   // XCD slot owns heads {2s, 2s+1}
    const int qt = seq & 31;
    const int kvh = h >> 2;
    const int q0 = qt * 64;
    __shared__ unsigned short Ks[2][64 * 128];
    __shared__ unsigned short Vs[128 * 64];
    __shared__ unsigned short Ps[4][16 * 72];
    const int tid = threadIdx.x;
    const int lane = tid & 63, wave = tid >> 6;
    const int l15 = lane & 15, l4 = lane >> 4;

    bf16x8 qf[4];
    {
        const unsigned short* qrow =
            Qb + ((size_t)h * 2048 + q0 + wave * 16 + l15) * 128 + l4 * 8;
        for (int kk = 0; kk < 4; ++kk) qf[kk] = *(const bf16x8*)(qrow + kk * 32);
    }
    f32x4 o[8] = {};
    float m2[4], lp[4];
    for (int j = 0; j < 4; ++j) { m2[j] = -1e30f; lp[j] = 0.0f; }
    const int kt_lo = (qt >= 16) ? (qt - 16) : 0;

    const unsigned short* Kh = Kb + (size_t)kvh * 2048 * 128;
    const unsigned short* Vh = VbT + (size_t)kvh * 128 * 2048;

    // per-thread staging geometry (hoisted)
    int ksr[4], ksc[4], vsr[4], vsc[4];
    for (int i = 0; i < 4; ++i) {
        int s = i * 256 + tid;
        ksr[i] = s >> 4;
        ksc[i] = (((s & 15) * 16) ^ ((ksr[i] & 7) << 4)) >> 1;
        vsr[i] = s >> 3;
        vsc[i] = (((s & 7) * 16) ^ ((vsr[i] & 7) << 4)) >> 1;
    }

    // prologue: K[kt_lo] -> Ks[0]
    for (int i = 0; i < 4; ++i)
        gload_lds16(Kh + (size_t)(kt_lo * 64 + ksr[i]) * 128 + ksc[i], &Ks[0][(i * 256 + tid) * 8]);

    int cur = 0;
    for (int kt = kt_lo; kt <= qt; ++kt) {
        asm volatile("s_waitcnt vmcnt(0)\ns_barrier" ::: "memory");
        __builtin_amdgcn_sched_barrier(0);

        // issue V[kt] (oldest -> certified by vmcnt(4) later), then K[kt+1]
        for (int i = 0; i < 4; ++i)
            gload_lds16(Vh + (size_t)vsr[i] * 2048 + kt * 64 + vsc[i], &Vs[(i * 256 + tid) * 8]);
        if (kt < qt) {
            for (int i = 0; i < 4; ++i)
                gload_lds16(Kh + (size_t)((kt + 1) * 64 + ksr[i]) * 128 + ksc[i],
                            &Ks[cur ^ 1][(i * 256 + tid) * 8]);
        }

        // S = Q K^T (Q pre-scaled -> log2 domain)
        f32x4 s[4] = {};
        __builtin_amdgcn_s_setprio(1);
        for (int nn = 0; nn < 4; ++nn)
            for (int kk = 0; kk < 4; ++kk) {
                int r = nn * 16 + l15;
                int cb = (kk * 64 + l4 * 16) ^ ((r & 7) << 4);
                bf16x8 kf = *(const bf16x8*)((const char*)&Ks[cur][0] + r * 256 + cb);
                s[nn] = MFMA16(qf[kk], kf, s[nn]);
            }
        __builtin_amdgcn_s_setprio(0);

        float p[4][4];
        const bool masked = (kt == qt) || (qt >= 16 && kt == kt_lo);
        if (masked) {
            for (int nn = 0; nn < 4; ++nn) {
                int kc = kt * 64 + nn * 16 + l15;
                for (int j = 0; j < 4; ++j) {
                    int qr = q0 + wave * 16 + l4 * 4 + j;
                    unsigned diff = (unsigned)(qr - kc);
                    p[nn][j] = (diff < 1024u) ? s[nn][j] : -1e30f;
                }
            }
        } else {
            for (int nn = 0; nn < 4; ++nn)
                for (int j = 0; j < 4; ++j) p[nn][j] = s[nn][j];
        }

        // deferred-max: common path has NO cross-lane reduce
        float mxl[4];
        bool flag = true;
        for (int j = 0; j < 4; ++j) {
            mxl[j] = fmaxf(fmaxf(p[0][j], p[1][j]), fmaxf(p[2][j], p[3][j]));
            flag = flag && (mxl[j] <= m2[j] + 11.0f);
        }
        if (!__all(flag)) {
            for (int j = 0; j < 4; ++j) {
                float mx = mxl[j];
                for (int mk = 8; mk; mk >>= 1) mx = fmaxf(mx, __shfl_xor(mx, mk));
                float mnew = fmaxf(m2[j], mx);
                float corr = exp2f(m2[j] - mnew);
                m2[j] = mnew;
                lp[j] *= corr;
                for (int dd = 0; dd < 8; ++dd) o[dd][j] *= corr;
            }
        }
        for (int j = 0; j < 4; ++j) {
            float rs = 0.0f;
            for (int nn = 0; nn < 4; ++nn) {
                float pv = exp2f(p[nn][j] - m2[j]);
                p[nn][j] = pv;
                rs += pv;
            }
            lp[j] += rs;
        }

        for (int j = 0; j < 4; ++j)
            for (int nn = 0; nn < 4; ++nn)
                Ps[wave][(l4 * 4 + j) * 72 + nn * 16 + l15] = f2bf_fast(p[nn][j]);

        bf16x8 pa[2];
        for (int kk2 = 0; kk2 < 2; ++kk2)
            pa[kk2] = *(const bf16x8*)&Ps[wave][l15 * 72 + kk2 * 32 + l4 * 8];

        // V[kt] certified (oldest 4 of <=8 outstanding); K[kt+1] may stay in flight
        if (kt < qt)
            asm volatile("s_waitcnt vmcnt(4)\ns_barrier" ::: "memory");
        else
            asm volatile("s_waitcnt vmcnt(0)\ns_barrier" ::: "memory");
        __builtin_amdgcn_sched_barrier(0);

        __builtin_amdgcn_s_setprio(1);
        for (int dd = 0; dd < 8; ++dd)
            for (int kk2 = 0; kk2 < 2; ++kk2) {
                int d = dd * 16 + l15;
                int cb = (kk2 * 64 + l4 * 16) ^ ((d & 7) << 4);
                bf16x8 vf = *(const bf16x8*)((const char*)&Vs[0] + d * 128 + cb);
                o[dd] = MFMA16(pa[kk2], vf, o[dd]);
            }
        __builtin_amdgcn_s_setprio(0);
        cur ^= 1;
    }

    for (int j = 0; j < 4; ++j) {
        float lt = lp[j];
        for (int mk = 8; mk; mk >>= 1) lt += __shfl_xor(lt, mk);
        float inv = 1.0f / lt;
        int row = q0 + wave * 16 + l4 * 4 + j;
        unsigned short* orow = Ob + (size_t)row * 2048 + h * 128;
        for (int dd = 0; dd < 8; ++dd) orow[dd * 16 + l15] = f2bf_fast(o[dd][j] * inv);
    }
}

// ---------------------------------------------------------------- combine 4 bf16 split-K partials -> f32 out
__global__ __launch_bounds__(256) void add4(const unsigned short* __restrict__ p,
                                            float* __restrict__ out, int n) {
    int i = (blockIdx.x * 256 + threadIdx.x) * 8;
    if (i >= n) return;
    us8 a = *(const us8*)(p + i);
    us8 b = *(const us8*)(p + 4194304 + i);
    us8 c = *(const us8*)(p + 8388608 + i);
    us8 d = *(const us8*)(p + 12582912 + i);
    f32x4 o0, o1;
    for (int j = 0; j < 4; ++j)
        o0[j] = (bf2f(a[j]) + bf2f(b[j])) + (bf2f(c[j]) + bf2f(d[j]));
    for (int j = 0; j < 4; ++j)
        o1[j] = (bf2f(a[j + 4]) + bf2f(b[j + 4])) + (bf2f(c[j + 4]) + bf2f(d[j + 4]));
    *(f32x4*)(out + i) = o0;
    *(f32x4*)(out + i + 4) = o1;
}

// ---------------------------------------------------------------- launch
extern "C" void kernel_launch(void* const* d_in, const int* in_sizes, int n_in,
                              void* d_out, int out_size, void* d_ws, size_t ws_size,
                              hipStream_t stream) {
    const float* x  = (const float*)d_in[0];
    const float* wq = (const float*)d_in[1];
    const float* wk = (const float*)d_in[2];
    const float* wv = (const float*)d_in[3];
    const float* wo = (const float*)d_in[4];
    const float* wo_ = wo; (void)wo_;
    const float* qw = (const float*)d_in[5];
    const float* kw = (const float*)d_in[6];
    float* out = (float*)d_out;

    char* ws = (char*)d_ws;
    unsigned short* xb   = (unsigned short*)(ws + 0);          //  8 MB (dead after gemm-qkv)
    unsigned short* wqkv = (unsigned short*)(ws + 8388608);    // 12 MB (dead after gemm-qkv)
    unsigned short* wob  = (unsigned short*)(ws + 20971520);   //  8 MB (alive till out-gemm)
    unsigned short* qkvP = (unsigned short*)(ws + 29360128);   // 25 MB bf16 x2 partials (dead after norm/transpose)
    unsigned short* Qb   = (unsigned short*)(ws + 54525952);   //  8 MB (dead after attn)
    unsigned short* Kb   = (unsigned short*)(ws + 62914560);   //  2 MB (dead after attn)
    unsigned short* VbT  = (unsigned short*)(ws + 65011712);   //  2 MB (dead after attn)
    unsigned short* Ob   = (unsigned short*)(ws + 67108864);   //  8 MB (alive till out-gemm)
    unsigned short* outP = (unsigned short*)(ws + 29360128);   // 32 MB bf16 x4, overlays dead qkvP/Qb
    float2*         tbl  = (float2*)(ws + 104857600);          //  1 MB

    prep_all<<<dim3(14848), dim3(256), 0, stream>>>(x, wq, wk, wv, wo, xb, wqkv, wob, tbl);
    gemm256<<<dim3(12, 8, 2), dim3(512), 0, stream>>>(xb, wqkv, qkvP, 2048, 3072, 2048, 1024);
    norm_rope<<<dim3(2048, 5), dim3(256), 0, stream>>>(qkvP, qkvP + 2048 * 3072, qw, kw, tbl, Qb, Kb);
    transpose_v<<<dim3(32, 4), dim3(256), 0, stream>>>(qkvP, qkvP + 2048 * 3072, VbT);
    attn_fwd<<<dim3(512), dim3(256), 0, stream>>>(Qb, Kb, VbT, Ob);
    gemm256<<<dim3(8, 8, 4), dim3(512), 0, stream>>>(Ob, wob, outP, 2048, 2048, 2048, 512);
    add4<<<dim3(2048), dim3(256), 0, stream>>>(outP, out, 2048 * 2048);
}

// Round 10
// 126.474 us; speedup vs baseline: 2.1464x; 1.0574x over previous
//
#include <hip/hip_runtime.h>
#include <hip/hip_bf16.h>
#include <cstdint>
#include <cstddef>

typedef __attribute__((ext_vector_type(4))) float f32x4;
typedef __attribute__((ext_vector_type(8))) short bf16x8;
typedef __attribute__((ext_vector_type(8))) unsigned short us8;

#define MFMA16(a, b, c) __builtin_amdgcn_mfma_f32_16x16x32_bf16(a, b, c, 0, 0, 0)

__device__ inline unsigned short f2bf(float f) {
    unsigned int u = __float_as_uint(f);
    u += 0x7fffu + ((u >> 16) & 1u);
    return (unsigned short)(u >> 16);
}
__device__ inline float bf2f(unsigned short u) {
    return __uint_as_float((unsigned int)u << 16);
}
// 1-instruction bf16 convert (RTNE) via packed cvt
__device__ inline unsigned short f2bf_fast(float f) {
    float r;
    asm("v_cvt_pk_bf16_f32 %0, %1, %2" : "=v"(r) : "v"(f), "v"(f));
    return (unsigned short)__float_as_uint(r);
}

__device__ inline void gload_lds16(const void* g, void* l) {
    __builtin_amdgcn_global_load_lds(
        (const __attribute__((address_space(1))) void*)g,
        (__attribute__((address_space(3))) void*)l, 16, 0, 0);
}
__device__ inline unsigned lds_addr(const void* p) {
    return (unsigned)(size_t)((__attribute__((address_space(3))) const void*)p);
}

// ---------------------------------------------------------------- fused prep: 5 f32->bf16 converts + RoPE table
__global__ __launch_bounds__(256) void prep_all(const float* __restrict__ x,
                                                const float* __restrict__ wq,
                                                const float* __restrict__ wk,
                                                const float* __restrict__ wv,
                                                const float* __restrict__ wo,
                                                unsigned short* __restrict__ xb,
                                                unsigned short* __restrict__ wqkv,
                                                unsigned short* __restrict__ wob,
                                                float2* __restrict__ tbl) {
    const int b = blockIdx.x;
    if (b < 14336) {
        const float* src; unsigned short* dst; int off4;
        if (b < 4096)       { src = x;  dst = xb;                 off4 = b; }
        else if (b < 8192)  { src = wq; dst = wqkv;               off4 = b - 4096; }
        else if (b < 9216)  { src = wk; dst = wqkv + 2048 * 2048; off4 = b - 8192; }
        else if (b < 10240) { src = wv; dst = wqkv + 2560 * 2048; off4 = b - 9216; }
        else                { src = wo; dst = wob;                off4 = b - 10240; }
        int i = (off4 * 256 + threadIdx.x) * 4;
        float4 v = *(const float4*)(src + i);
        ushort4 o;
        o.x = f2bf(v.x); o.y = f2bf(v.y); o.z = f2bf(v.z); o.w = f2bf(v.w);
        *(ushort4*)(dst + i) = o;
    } else {
        int idx = (b - 14336) * 256 + threadIdx.x;
        int row = idx >> 6, t = idx & 63;
        float inv_freq = exp2f((float)t * (-2.0f / 128.0f) * 13.287712379549449f);
        float s, c;
        sincosf((float)row * inv_freq, &s, &c);
        tbl[idx] = make_float2(c, s);
    }
}

// ---------------------------------------------------------------- gemm256: bf16 partials out (f32 accum)
__global__ __launch_bounds__(512, 2) void gemm256(const unsigned short* __restrict__ A,
                                                  const unsigned short* __restrict__ B,
                                                  unsigned short* __restrict__ Cp,
                                                  int M, int N, int Kfull, int kspan) {
    __shared__ unsigned short As[3][8192];
    __shared__ unsigned short Bs[3][8192];
    const int tid = threadIdx.x;
    const int lane = tid & 63, wave = tid >> 6;
    const int wr = wave >> 2, wc = wave & 3;
    const int l15 = lane & 15, l4 = lane >> 4;
    const int gx = gridDim.x;
    const int nwg = gx * gridDim.y;
    const int bid0 = blockIdx.y * gx + blockIdx.x;
    const int q8 = nwg >> 3, r8 = nwg & 7;
    const int xcd = bid0 & 7, sub = bid0 >> 3;
    const int wgid = ((xcd < r8) ? xcd * (q8 + 1) : r8 * (q8 + 1) + (xcd - r8) * q8) + sub;
    const int bm = wgid / gx, bn = wgid % gx;
    const int z = blockIdx.z;
    const unsigned short* Az = A + (size_t)z * kspan;
    const unsigned short* Bz = B + (size_t)z * kspan;
    unsigned short* C = Cp + (size_t)z * M * N;
    const int nK = kspan >> 5;

    f32x4 acc[8][4] = {};

    const int r0 = tid >> 2, qs = tid & 3;
    const int qsw = qs ^ ((r0 >> 1) & 3);
    const unsigned short* pa0 = Az + (size_t)(bm * 256 + r0) * Kfull + qsw * 8;
    const unsigned short* pa1 = pa0 + (size_t)128 * Kfull;
    const unsigned short* pb0 = Bz + (size_t)(bn * 256 + r0) * Kfull + qsw * 8;
    const unsigned short* pb1 = pb0 + (size_t)128 * Kfull;

#define STG(kt, bb)                                            \
    do {                                                       \
        gload_lds16(pa0 + (kt) * 32, &As[bb][tid * 8]);        \
        gload_lds16(pa1 + (kt) * 32, &As[bb][4096 + tid * 8]); \
        gload_lds16(pb0 + (kt) * 32, &Bs[bb][tid * 8]);        \
        gload_lds16(pb1 + (kt) * 32, &Bs[bb][4096 + tid * 8]); \
    } while (0)

    const int q = l4 ^ ((l15 >> 1) & 3);
    const unsigned aB = lds_addr(&As[0][0]) + (unsigned)((wr * 128 + l15) * 64 + q * 16);
    const unsigned bB = lds_addr(&Bs[0][0]) + (unsigned)((wc * 64 + l15) * 64 + q * 16);

#define DSR(dst, addr, off) \
    asm volatile("ds_read_b128 %0, %1 offset:" #off : "=v"(dst) : "v"(addr))

    STG(0, 0);
    STG(1, 1);
    int bc = 0, bs = 2;
    for (int kt = 0; kt < nK; ++kt) {
        if (kt + 1 < nK)
            asm volatile("s_waitcnt vmcnt(4)\ns_barrier" ::: "memory");
        else
            asm volatile("s_waitcnt vmcnt(0)\ns_barrier" ::: "memory");
        __builtin_amdgcn_sched_barrier(0);

        bf16x8 a[8], b[4];
        {
            const unsigned aA = aB + bc * 16384;
            const unsigned bA = bB + bc * 16384;
            DSR(a[0], aA, 0);    DSR(a[1], aA, 1024);
            DSR(a[2], aA, 2048); DSR(a[3], aA, 3072);
            DSR(a[4], aA, 4096); DSR(a[5], aA, 5120);
            DSR(a[6], aA, 6144); DSR(a[7], aA, 7168);
            DSR(b[0], bA, 0);    DSR(b[1], bA, 1024);
            DSR(b[2], bA, 2048); DSR(b[3], bA, 3072);
        }
        if (kt + 2 < nK) STG(kt + 2, bs);
        asm volatile("s_waitcnt lgkmcnt(0)" ::: "memory");
        __builtin_amdgcn_sched_barrier(0);

        __builtin_amdgcn_s_setprio(1);
#pragma unroll
        for (int m = 0; m < 8; ++m)
#pragma unroll
            for (int n = 0; n < 4; ++n)
                acc[m][n] = MFMA16(a[m], b[n], acc[m][n]);
        __builtin_amdgcn_s_setprio(0);

        if (++bc == 3) bc = 0;
        if (++bs == 3) bs = 0;
    }
#undef STG
#undef DSR

    for (int m = 0; m < 8; ++m)
        for (int n = 0; n < 4; ++n)
            for (int j = 0; j < 4; ++j) {
                int row = bm * 256 + wr * 128 + m * 16 + l4 * 4 + j;
                int col = bn * 256 + wc * 64 + n * 16 + l15;
                C[(size_t)row * N + col] = f2bf_fast(acc[m][n][j]);
            }
}

// ---------------------------------------------------------------- combine + RMSNorm + RoPE (Q/K heads; Q pre-scaled)
__global__ __launch_bounds__(256) void norm_rope(const unsigned short* __restrict__ p0,
                                                 const unsigned short* __restrict__ p1,
                                                 const float* __restrict__ qw,
                                                 const float* __restrict__ kw,
                                                 const float2* __restrict__ tbl,
                                                 unsigned short* __restrict__ Qb,
                                                 unsigned short* __restrict__ Kb) {
    const int row = blockIdx.x;
    const int head = blockIdx.y * 4 + (threadIdx.x >> 6);  // 0..19
    const int t = threadIdx.x & 63;
    const size_t off = (size_t)row * 3072 + head * 128;
    float x1 = bf2f(p0[off + t]) + bf2f(p1[off + t]);
    float x2 = bf2f(p0[off + t + 64]) + bf2f(p1[off + t + 64]);
    float ss = x1 * x1 + x2 * x2;
    for (int m = 32; m; m >>= 1) ss += __shfl_xor(ss, m);
    float r = rsqrtf(ss * (1.0f / 128.0f) + 1e-6f);
    const float* w = (head < 16) ? qw : kw;
    float y1 = x1 * r * w[t], y2 = x2 * r * w[t + 64];
    float2 cs = tbl[row * 64 + t];
    x1 = y1 * cs.x - y2 * cs.y;
    x2 = y1 * cs.y + y2 * cs.x;
    if (head < 16) {                       // fold softmax scale*log2(e) into Q
        const float SCALE2 = 0.12751879526654698f;
        x1 *= SCALE2; x2 *= SCALE2;
    }
    unsigned short* dst = (head < 16) ? Qb + ((size_t)head * 2048 + row) * 128
                                      : Kb + ((size_t)(head - 16) * 2048 + row) * 128;
    dst[t] = f2bf(x1);
    dst[t + 64] = f2bf(x2);
}

// ---------------------------------------------------------------- V: combine + transpose with k-permuted columns
// VbT[h][d][kt*64 + c'] = V[kt*64 + k(c')][d], k(c') = (c'&3)*16 + (c'>>2)
__global__ __launch_bounds__(256) void transpose_v(const unsigned short* __restrict__ p0,
                                                   const unsigned short* __restrict__ p1,
                                                   unsigned short* __restrict__ VbT) {
    const int kt = blockIdx.x;  // 0..31
    const int h  = blockIdx.y;  // 0..3
    __shared__ unsigned short T[64 * 132];
    const int tid = threadIdx.x;
    for (int i = 0; i < 8; ++i) {
        int s = i * 256 + tid;
        int r = s >> 5, c = (s & 31) * 4;
        size_t off = (size_t)(kt * 64 + r) * 3072 + (20 + h) * 128 + c;
        ushort4 a = *(const ushort4*)(p0 + off);
        ushort4 b = *(const ushort4*)(p1 + off);
        ushort4 o;
        o.x = f2bf(bf2f(a.x) + bf2f(b.x));
        o.y = f2bf(bf2f(a.y) + bf2f(b.y));
        o.z = f2bf(bf2f(a.z) + bf2f(b.z));
        o.w = f2bf(bf2f(a.w) + bf2f(b.w));
        *(ushort4*)&T[r * 132 + c] = o;
    }
    __syncthreads();
    for (int i = 0; i < 4; ++i) {
        int s = i * 256 + tid;
        int d = s >> 3, ck = (s & 7) * 8;
        us8 v;
        for (int j = 0; j < 8; ++j) {
            int c = ck + j;
            int k = (c & 3) * 16 + (c >> 2);
            v[j] = T[k * 132 + d];
        }
        *(us8*)(VbT + (size_t)h * 128 * 2048 + (size_t)d * 2048 + kt * 64 + ck) = v;
    }
}

// ---------------------------------------------------------------- flash attention: 2 heads/block, 8 waves, 128 q-rows/stage
__global__ __launch_bounds__(512) void attn_fwd(const unsigned short* __restrict__ Qb,
                                                const unsigned short* __restrict__ Kb,
                                                const unsigned short* __restrict__ VbT,
                                                unsigned short* __restrict__ Ob) {
    const int bid = blockIdx.x;
    const int p = bid & 7;           // head pair = XCD slot
    const int qt = bid >> 3;         // 0..31
    const int q0 = qt * 64;
    __shared__ unsigned short Ks[2][64 * 128];   // swizzled
    __shared__ unsigned short Vs[128 * 64];      // V^T swizzled, k-permuted columns
    __shared__ unsigned short Ps[8][16 * 68];    // packed P, stride 68 shorts, XOR swizzle
    const int tid = threadIdx.x;
    const int lane = tid & 63, wave = tid >> 6;
    const int l15 = lane & 15, l4 = lane >> 4;
    const int h = 2 * p + (wave >> 2);           // this wave's head
    const int rgrp = wave & 3;                   // 16-row group within the 64-row tile
    const int kvh = p >> 1;

    bf16x8 qf[4];
    {
        const unsigned short* qrow =
            Qb + ((size_t)h * 2048 + q0 + rgrp * 16 + l15) * 128 + l4 * 8;
        for (int kk = 0; kk < 4; ++kk) qf[kk] = *(const bf16x8*)(qrow + kk * 32);
    }
    f32x4 o[8] = {};
    float m2[4], lp[4];
    for (int j = 0; j < 4; ++j) { m2[j] = -1e30f; lp[j] = 0.0f; }
    const int kt_lo = (qt >= 16) ? (qt - 16) : 0;

    const unsigned short* Kh = Kb + (size_t)kvh * 2048 * 128;
    const unsigned short* Vh = VbT + (size_t)kvh * 128 * 2048;

    // per-thread staging geometry (512 threads, 2 chunks each)
    int ksr[2], ksc[2], vsr[2], vsc[2];
    for (int i = 0; i < 2; ++i) {
        int s = i * 512 + tid;
        ksr[i] = s >> 4;
        ksc[i] = (((s & 15) * 16) ^ ((ksr[i] & 7) << 4)) >> 1;
        vsr[i] = s >> 3;
        vsc[i] = (((s & 7) * 16) ^ ((vsr[i] & 7) << 4)) >> 1;
    }

    // prologue: K[kt_lo] -> Ks[0]
    for (int i = 0; i < 2; ++i)
        gload_lds16(Kh + (size_t)(kt_lo * 64 + ksr[i]) * 128 + ksc[i],
                    &Ks[0][(i * 512 + tid) * 8]);

    int cur = 0;
    for (int kt = kt_lo; kt <= qt; ++kt) {
        asm volatile("s_waitcnt vmcnt(0)\ns_barrier" ::: "memory");
        __builtin_amdgcn_sched_barrier(0);

        // issue V[kt] (oldest), then K[kt+1]
        for (int i = 0; i < 2; ++i)
            gload_lds16(Vh + (size_t)vsr[i] * 2048 + kt * 64 + vsc[i],
                        &Vs[(i * 512 + tid) * 8]);
        if (kt < qt) {
            for (int i = 0; i < 2; ++i)
                gload_lds16(Kh + (size_t)((kt + 1) * 64 + ksr[i]) * 128 + ksc[i],
                            &Ks[cur ^ 1][(i * 512 + tid) * 8]);
        }

        // S = Q K^T (Q pre-scaled -> log2 domain)
        f32x4 s[4] = {};
        __builtin_amdgcn_s_setprio(1);
        for (int nn = 0; nn < 4; ++nn)
            for (int kk = 0; kk < 4; ++kk) {
                int r = nn * 16 + l15;
                int cb = (kk * 64 + l4 * 16) ^ ((r & 7) << 4);
                bf16x8 kf = *(const bf16x8*)((const char*)&Ks[cur][0] + r * 256 + cb);
                s[nn] = MFMA16(qf[kk], kf, s[nn]);
            }
        __builtin_amdgcn_s_setprio(0);

        float pv4[4][4];
        const bool masked = (kt == qt) || (qt >= 16 && kt == kt_lo);
        if (masked) {
            for (int nn = 0; nn < 4; ++nn) {
                int kc = kt * 64 + nn * 16 + l15;
                for (int j = 0; j < 4; ++j) {
                    int qr = q0 + rgrp * 16 + l4 * 4 + j;
                    unsigned diff = (unsigned)(qr - kc);
                    pv4[nn][j] = (diff < 1024u) ? s[nn][j] : -1e30f;
                }
            }
        } else {
            for (int nn = 0; nn < 4; ++nn)
                for (int j = 0; j < 4; ++j) pv4[nn][j] = s[nn][j];
        }

        // deferred-max: common path has NO cross-lane reduce
        float mxl[4];
        bool flag = true;
        for (int j = 0; j < 4; ++j) {
            mxl[j] = fmaxf(fmaxf(pv4[0][j], pv4[1][j]), fmaxf(pv4[2][j], pv4[3][j]));
            flag = flag && (mxl[j] <= m2[j] + 11.0f);
        }
        if (!__all(flag)) {
            for (int j = 0; j < 4; ++j) {
                float mx = mxl[j];
                for (int mk = 8; mk; mk >>= 1) mx = fmaxf(mx, __shfl_xor(mx, mk));
                float mnew = fmaxf(m2[j], mx);
                float corr = exp2f(m2[j] - mnew);
                m2[j] = mnew;
                lp[j] *= corr;
                for (int dd = 0; dd < 8; ++dd) o[dd][j] *= corr;
            }
        }
        for (int j = 0; j < 4; ++j) {
            float rs = 0.0f;
            for (int nn = 0; nn < 4; ++nn) {
                float pv = exp2f(pv4[nn][j] - m2[j]);
                pv4[nn][j] = pv;
                rs += pv;
            }
            lp[j] += rs;
        }

        // packed P store: k-permuted cols (c' = l15*4 + nn), 1 b64 write per j
        for (int j = 0; j < 4; ++j) {
            int row = l4 * 4 + j;
            unsigned lo, hi;
            asm("v_cvt_pk_bf16_f32 %0, %1, %2" : "=v"(lo) : "v"(pv4[0][j]), "v"(pv4[1][j]));
            asm("v_cvt_pk_bf16_f32 %0, %1, %2" : "=v"(hi) : "v"(pv4[2][j]), "v"(pv4[3][j]));
            int cb = (l15 * 8) ^ ((row & 7) << 4);
            *(uint2*)((char*)&Ps[wave][0] + row * 136 + cb) = make_uint2(lo, hi);
        }

        bf16x8 pa[2];
        for (int kk2 = 0; kk2 < 2; ++kk2) {
            int cb = (kk2 * 64 + l4 * 16) ^ ((l15 & 7) << 4);
            pa[kk2] = *(const bf16x8*)((const char*)&Ps[wave][0] + l15 * 136 + cb);
        }

        // V[kt] certified (this wave's 2 V-loads are its oldest); barrier collectivizes
        if (kt < qt)
            asm volatile("s_waitcnt vmcnt(2)\ns_barrier" ::: "memory");
        else
            asm volatile("s_waitcnt vmcnt(0)\ns_barrier" ::: "memory");
        __builtin_amdgcn_sched_barrier(0);

        __builtin_amdgcn_s_setprio(1);
        for (int dd = 0; dd < 8; ++dd)
            for (int kk2 = 0; kk2 < 2; ++kk2) {
                int d = dd * 16 + l15;
                int cb = (kk2 * 64 + l4 * 16) ^ ((d & 7) << 4);
                bf16x8 vf = *(const bf16x8*)((const char*)&Vs[0] + d * 128 + cb);
                o[dd] = MFMA16(pa[kk2], vf, o[dd]);
            }
        __builtin_amdgcn_s_setprio(0);
        cur ^= 1;
    }

    for (int j = 0; j < 4; ++j) {
        float lt = lp[j];
        for (int mk = 8; mk; mk >>= 1) lt += __shfl_xor(lt, mk);
        float inv = 1.0f / lt;
        int row = q0 + rgrp * 16 + l4 * 4 + j;
        unsigned short* orow = Ob + (size_t)row * 2048 + h * 128;
        for (int dd = 0; dd < 8; ++dd) orow[dd * 16 + l15] = f2bf_fast(o[dd][j] * inv);
    }
}

// ---------------------------------------------------------------- combine 4 bf16 split-K partials -> f32 out
__global__ __launch_bounds__(256) void add4(const unsigned short* __restrict__ p,
                                            float* __restrict__ out, int n) {
    int i = (blockIdx.x * 256 + threadIdx.x) * 8;
    if (i >= n) return;
    us8 a = *(const us8*)(p + i);
    us8 b = *(const us8*)(p + 4194304 + i);
    us8 c = *(const us8*)(p + 8388608 + i);
    us8 d = *(const us8*)(p + 12582912 + i);
    f32x4 o0, o1;
    for (int j = 0; j < 4; ++j)
        o0[j] = (bf2f(a[j]) + bf2f(b[j])) + (bf2f(c[j]) + bf2f(d[j]));
    for (int j = 0; j < 4; ++j)
        o1[j] = (bf2f(a[j + 4]) + bf2f(b[j + 4])) + (bf2f(c[j + 4]) + bf2f(d[j + 4]));
    *(f32x4*)(out + i) = o0;
    *(f32x4*)(out + i + 4) = o1;
}

// ---------------------------------------------------------------- launch
extern "C" void kernel_launch(void* const* d_in, const int* in_sizes, int n_in,
                              void* d_out, int out_size, void* d_ws, size_t ws_size,
                              hipStream_t stream) {
    const float* x  = (const float*)d_in[0];
    const float* wq = (const float*)d_in[1];
    const float* wk = (const float*)d_in[2];
    const float* wv = (const float*)d_in[3];
    const float* wo = (const float*)d_in[4];
    const float* qw = (const float*)d_in[5];
    const float* kw = (const float*)d_in[6];
    float* out = (float*)d_out;

    char* ws = (char*)d_ws;
    unsigned short* xb   = (unsigned short*)(ws + 0);          //  8 MB
    unsigned short* wqkv = (unsigned short*)(ws + 8388608);    // 12 MB
    unsigned short* wob  = (unsigned short*)(ws + 20971520);   //  8 MB
    unsigned short* qkvP = (unsigned short*)(ws + 29360128);   // 25 MB bf16 x2 partials
    unsigned short* Qb   = (unsigned short*)(ws + 54525952);   //  8 MB
    unsigned short* Kb   = (unsigned short*)(ws + 62914560);   //  2 MB
    unsigned short* VbT  = (unsigned short*)(ws + 65011712);   //  2 MB
    unsigned short* Ob   = (unsigned short*)(ws + 67108864);   //  8 MB
    unsigned short* outP = (unsigned short*)(ws + 29360128);   // 32 MB bf16 x4, overlays dead qkvP/Qb
    float2*         tbl  = (float2*)(ws + 104857600);          //  1 MB

    prep_all<<<dim3(14848), dim3(256), 0, stream>>>(x, wq, wk, wv, wo, xb, wqkv, wob, tbl);
    gemm256<<<dim3(12, 8, 2), dim3(512), 0, stream>>>(xb, wqkv, qkvP, 2048, 3072, 2048, 1024);
    norm_rope<<<dim3(2048, 5), dim3(256), 0, stream>>>(qkvP, qkvP + 2048 * 3072, qw, kw, tbl, Qb, Kb);
    transpose_v<<<dim3(32, 4), dim3(256), 0, stream>>>(qkvP, qkvP + 2048 * 3072, VbT);
    attn_fwd<<<dim3(256), dim3(512), 0, stream>>>(Qb, Kb, VbT, Ob);
    gemm256<<<dim3(8, 8, 4), dim3(512), 0, stream>>>(Ob, wob, outP, 2048, 2048, 2048, 512);
    add4<<<dim3(2048), dim3(256), 0, stream>>>(outP, out, 2048 * 2048);
}